// Round 18
// baseline (179.889 us; speedup 1.0000x reference)
//
#include <hip/hip_runtime.h>
#include <hip/hip_fp16.h>
#include <math.h>

// Problem constants (from reference)
constexpr int Nn  = 50000;   // nodes
constexpr int FIN = 128;     // input features
constexpr int NH  = 8;       // heads
constexpr int FO  = 16;      // features per head
constexpr int HF  = 128;     // NH*FO
constexpr int NWR = 272;     // Wh rows: Wp(128) | Wskip(128) | Va_src(8) | Va_trg(8)
constexpr int NPREP = NWR / 2;                  // 136 prep blocks (2 rows each)
constexpr int NBLK64 = (Nn + 63) / 64;          // 782 node blocks (64 nodes ea)
constexpr int NSCAN = (Nn + 255) / 256;         // 196 scan blocks
constexpr int NPW = 10;                         // gather: nodes per wave
constexpr int NGB = Nn / (NPW * 4);             // 1250 gather blocks per group

typedef _Float16 f16x8 __attribute__((ext_vector_type(8)));
typedef float    f32x4 __attribute__((ext_vector_type(4)));

// ---------------------------------------------------------------------------
// Fused prep + count-with-rank.
//   blocks [0, NPREP)   : Wh[272][128] f16 (2 rows/block) + ctp (block 0)
//   blocks [NPREP, ...) : rank[e] = atomicAdd(deg[trg[e]], 1)  (1 edge/thread)
// ---------------------------------------------------------------------------
__global__ __launch_bounds__(256) void k_pc(
    const float* __restrict__ Wp, const float* __restrict__ Wskip,
    const float* __restrict__ a_src, const float* __restrict__ a_trg,
    const float* __restrict__ Wt, const float* __restrict__ a_tp,
    _Float16* __restrict__ Wh, float* __restrict__ ctp,
    const int* __restrict__ trg, int* __restrict__ deg,
    int* __restrict__ rank, int E)
{
    const int bid = blockIdx.x;
    if (bid < NPREP) {
        if (bid == 0 && threadIdx.x < NH) {
            int h = threadIdx.x;
            float s = 0.f;
            #pragma unroll
            for (int f = 0; f < FO; ++f) s += Wt[h * FO + f] * a_tp[h * FO + f];
            ctp[h] = s;
        }
        const int o = bid * 2 + (threadIdx.x >> 7);  // 0..271
        const int k = threadIdx.x & 127;
        float v;
        if (o < 128)      v = Wp[o * FIN + k];
        else if (o < 256) v = Wskip[(o - 128) * FIN + k];
        else if (o < 264) {
            const int h = o - 256;
            float s = 0.f;
            #pragma unroll
            for (int f = 0; f < FO; ++f)
                s += a_src[h * FO + f] * Wp[(h * FO + f) * FIN + k];
            v = s;
        } else {
            const int h = o - 264;
            float s = 0.f;
            #pragma unroll
            for (int f = 0; f < FO; ++f)
                s += a_trg[h * FO + f] * Wp[(h * FO + f) * FIN + k];
            v = s;
        }
        Wh[o * FIN + k] = (_Float16)v;
        return;
    }

    int e = (bid - NPREP) * 256 + threadIdx.x;
    if (e < E) rank[e] = atomicAdd(&deg[trg[e]], 1);
}

// ---------------------------------------------------------------------------
// Scan pair. pos stays EXCLUSIVE; row n spans [pos[n], n+1<Nn?pos[n+1]:E).
// ---------------------------------------------------------------------------
__global__ __launch_bounds__(256) void k_scan1(const int* __restrict__ deg,
                                               int* __restrict__ partial)
{
    __shared__ int lds[256];
    int t = threadIdx.x, i = blockIdx.x * 256 + t;
    lds[t] = (i < Nn) ? deg[i] : 0;
    __syncthreads();
    for (int off = 128; off > 0; off >>= 1) {
        if (t < off) lds[t] += lds[t + off];
        __syncthreads();
    }
    if (t == 0) partial[blockIdx.x] = lds[0];
}

__global__ __launch_bounds__(256) void k_scan3(const int* __restrict__ deg,
                                               const int* __restrict__ partial,
                                               int* __restrict__ pos)
{
    __shared__ int lds[256], lds2[256];
    const int t = threadIdx.x;
    const int i = blockIdx.x * 256 + t;
    lds2[t] = (t < NSCAN) ? partial[t] : 0;
    __syncthreads();
    for (int off = 1; off < 256; off <<= 1) {
        int u = (t >= off) ? lds2[t - off] : 0;
        __syncthreads();
        lds2[t] += u;
        __syncthreads();
    }
    const int base = (blockIdx.x == 0) ? 0 : lds2[blockIdx.x - 1];
    int v = (i < Nn) ? deg[i] : 0;
    lds[t] = v;
    __syncthreads();
    for (int off = 1; off < 256; off <<= 1) {
        int u = (t >= off) ? lds[t - off] : 0;
        __syncthreads();
        lds[t] += u;
        __syncthreads();
    }
    if (i < Nn) pos[i] = base + lds[t] - v;
}

// ---------------------------------------------------------------------------
// Fused fill + node GEMM.
//   blocks [0, nbFill)   : fill — slot = pos[trg]+rank (NO atomics);
//                          spk = src(16b) | f16(prob)(16b), 4 edges/thread.
//   blocks [nbFill, ...) : node GEMM, 64 nodes/block, B-frags in registers,
//                          software-pipelined A-loads. Epilogue writes
//                          GROUP-major projG[g][n][hh][16] f16 and
//                          group-packed scores ssg/stg[g][n][hh] for the
//                          XCD-pinned gather.
// ---------------------------------------------------------------------------
__global__ __launch_bounds__(256) void k_fn(
    const int* __restrict__ src, const int* __restrict__ trg,
    const float* __restrict__ prob, const int* __restrict__ rank,
    const int* __restrict__ pos, unsigned int* __restrict__ spk,
    const float* __restrict__ x, const _Float16* __restrict__ Wh,
    const float* __restrict__ bias,
    __half* __restrict__ projG, float* __restrict__ out,
    float* __restrict__ ssg, float* __restrict__ stg, int E, int nbFill)
{
    const int bid = blockIdx.x;

    if (bid < nbFill) {
        int e4 = bid * 256 + threadIdx.x;
        if (e4 * 4 < E) {
            int4   s4 = reinterpret_cast<const int4*>(src)[e4];
            int4   t4 = reinterpret_cast<const int4*>(trg)[e4];
            float4 p4 = reinterpret_cast<const float4*>(prob)[e4];
            int4   r4 = reinterpret_cast<const int4*>(rank)[e4];
            int    sv[4] = {s4.x, s4.y, s4.z, s4.w};
            int    tv[4] = {t4.x, t4.y, t4.z, t4.w};
            int    rv[4] = {r4.x, r4.y, r4.z, r4.w};
            float  pv[4] = {p4.x, p4.y, p4.z, p4.w};
            #pragma unroll
            for (int i = 0; i < 4; ++i) {
                int slot = pos[tv[i]] + rv[i];
                spk[slot] = (unsigned int)sv[i] |
                    ((unsigned int)__half_as_ushort(__float2half_rn(pv[i])) << 16);
            }
        }
        return;
    }

    // ---- node GEMM ----
    const int g0 = (bid - nbFill) * 64;
    const int w  = threadIdx.x >> 6;           // wave 0..3 (uniform per wave)
    const int l  = threadIdx.x & 63;
    const int lr = l & 15;
    const int kb = l >> 4;                     // k-block 0..3
    const int t0 = w * 4;                      // first tile of this wave

    // B fragments: loaded ONCE, reused across all node groups
    f16x8 b[4][4];
    const _Float16* wb = Wh + (size_t)lr * FIN + kb * 8;
    #pragma unroll
    for (int i = 0; i < 4; ++i) {
        #pragma unroll
        for (int ks = 0; ks < 4; ++ks)
            b[i][ks] = *reinterpret_cast<const f16x8*>(
                wb + (size_t)(t0 + i) * 16 * FIN + ks * 32);
    }
    f16x8 b16[4];
    if (w == 3) {
        #pragma unroll
        for (int ks = 0; ks < 4; ++ks)
            b16[ks] = *reinterpret_cast<const f16x8*>(
                wb + (size_t)16 * 16 * FIN + ks * 32);
    }

    const float* xr0 = x + (size_t)(g0 + lr) * FIN + kb * 8;

    if (g0 + 64 <= Nn) {
        // ---- full block: 4 groups, 2-stage pipeline ----
        float4 ucur[8];
        #pragma unroll
        for (int q = 0; q < 8; ++q)
            ucur[q] = *reinterpret_cast<const float4*>(
                xr0 + (q >> 1) * 32 + (q & 1) * 4);

        #pragma unroll
        for (int ng = 0; ng < 4; ++ng) {
            float4 unx[8];
            if (ng < 3) {
                const float* xrn = xr0 + (size_t)(ng + 1) * 16 * FIN;
                #pragma unroll
                for (int q = 0; q < 8; ++q)
                    unx[q] = *reinterpret_cast<const float4*>(
                        xrn + (q >> 1) * 32 + (q & 1) * 4);
            }

            f16x8 a[4];
            #pragma unroll
            for (int ks = 0; ks < 4; ++ks) {
                float4 lo = ucur[ks * 2], hi = ucur[ks * 2 + 1];
                a[ks][0] = (_Float16)lo.x; a[ks][1] = (_Float16)lo.y;
                a[ks][2] = (_Float16)lo.z; a[ks][3] = (_Float16)lo.w;
                a[ks][4] = (_Float16)hi.x; a[ks][5] = (_Float16)hi.y;
                a[ks][6] = (_Float16)hi.z; a[ks][7] = (_Float16)hi.w;
            }

            f32x4 acc[4];
            #pragma unroll
            for (int i = 0; i < 4; ++i) acc[i] = (f32x4){0.f, 0.f, 0.f, 0.f};
            f32x4 acc16 = (f32x4){0.f, 0.f, 0.f, 0.f};

            #pragma unroll
            for (int i = 0; i < 4; ++i) {
                #pragma unroll
                for (int ks = 0; ks < 4; ++ks)
                    acc[i] = __builtin_amdgcn_mfma_f32_16x16x32_f16(
                        a[ks], b[i][ks], acc[i], 0, 0, 0);
            }
            if (w == 3) {
                #pragma unroll
                for (int ks = 0; ks < 4; ++ks)
                    acc16 = __builtin_amdgcn_mfma_f32_16x16x32_f16(
                        a[ks], b16[ks], acc16, 0, 0, 0);
            }

            const int n0 = g0 + ng * 16;
            #pragma unroll
            for (int r = 0; r < 4; ++r) {
                const int n = n0 + kb * 4 + r;
                if (t0 < 8) {
                    // proj heads: group g = t>>1, head-in-group hh = t&1
                    #pragma unroll
                    for (int i = 0; i < 4; ++i) {
                        const int t = t0 + i;
                        projG[(size_t)(t >> 1) * Nn * 32 + (size_t)n * 32 +
                              (t & 1) * 16 + lr] = __float2half_rn(acc[i][r]);
                    }
                } else {
                    #pragma unroll
                    for (int i = 0; i < 4; ++i) {
                        const int o = (t0 + i - 8) * 16 + lr;
                        out[(size_t)n * HF + o] = acc[i][r] + bias[o];
                    }
                }
                if (w == 3) {
                    if (lr < 8)
                        ssg[(size_t)(lr >> 1) * 2 * Nn + n * 2 + (lr & 1)] = acc16[r];
                    else {
                        const int hq = lr - 8;
                        stg[(size_t)(hq >> 1) * 2 * Nn + n * 2 + (hq & 1)] = acc16[r];
                    }
                }
            }

            #pragma unroll
            for (int q = 0; q < 8; ++q) ucur[q] = unx[q];
        }
    } else {
        // ---- partial last block (one 16-node group at 49984) ----
        f16x8 a[4];
        #pragma unroll
        for (int ks = 0; ks < 4; ++ks) {
            float4 u0 = *reinterpret_cast<const float4*>(xr0 + ks * 32);
            float4 u1 = *reinterpret_cast<const float4*>(xr0 + ks * 32 + 4);
            a[ks][0] = (_Float16)u0.x; a[ks][1] = (_Float16)u0.y;
            a[ks][2] = (_Float16)u0.z; a[ks][3] = (_Float16)u0.w;
            a[ks][4] = (_Float16)u1.x; a[ks][5] = (_Float16)u1.y;
            a[ks][6] = (_Float16)u1.z; a[ks][7] = (_Float16)u1.w;
        }

        f32x4 acc[4];
        #pragma unroll
        for (int i = 0; i < 4; ++i) acc[i] = (f32x4){0.f, 0.f, 0.f, 0.f};
        f32x4 acc16 = (f32x4){0.f, 0.f, 0.f, 0.f};

        #pragma unroll
        for (int i = 0; i < 4; ++i) {
            #pragma unroll
            for (int ks = 0; ks < 4; ++ks)
                acc[i] = __builtin_amdgcn_mfma_f32_16x16x32_f16(
                    a[ks], b[i][ks], acc[i], 0, 0, 0);
        }
        if (w == 3) {
            #pragma unroll
            for (int ks = 0; ks < 4; ++ks)
                acc16 = __builtin_amdgcn_mfma_f32_16x16x32_f16(
                    a[ks], b16[ks], acc16, 0, 0, 0);
        }

        #pragma unroll
        for (int r = 0; r < 4; ++r) {
            const int n = g0 + kb * 4 + r;
            if (t0 < 8) {
                #pragma unroll
                for (int i = 0; i < 4; ++i) {
                    const int t = t0 + i;
                    projG[(size_t)(t >> 1) * Nn * 32 + (size_t)n * 32 +
                          (t & 1) * 16 + lr] = __float2half_rn(acc[i][r]);
                }
            } else {
                #pragma unroll
                for (int i = 0; i < 4; ++i) {
                    const int o = (t0 + i - 8) * 16 + lr;
                    out[(size_t)n * HF + o] = acc[i][r] + bias[o];
                }
            }
            if (w == 3) {
                if (lr < 8)
                    ssg[(size_t)(lr >> 1) * 2 * Nn + n * 2 + (lr & 1)] = acc16[r];
                else {
                    const int hq = lr - 8;
                    stg[(size_t)(hq >> 1) * 2 * Nn + n * 2 + (hq & 1)] = acc16[r];
                }
            }
        }
    }
}

// ---------------------------------------------------------------------------
// Gather, XCD-pinned 2-head groups with node-looping waves.
//   g = bid & 3 -> group g runs on XCDs {g, g+4}; per-XCD random-access set
//   = projG slice 3.2MB + ssg slice 0.4MB < 4MB L2.
//   One wave handles NPW=10 nodes for its group; lanes = 4 edge-slots x
//   2 heads x 8 f-pairs. Node loop amortizes prologue/reduce overhead
//   (the missing piece in R9's failed head-grouping).
// ---------------------------------------------------------------------------
__global__ __launch_bounds__(256) void k_gather(
    const unsigned int* __restrict__ spk, const int* __restrict__ pos,
    const float* __restrict__ ssg, const float* __restrict__ stg,
    const float* __restrict__ ctp,
    const __half2* __restrict__ projG2, float* __restrict__ out, int E)
{
    const int bid = blockIdx.x;
    const int g   = bid & 3;                   // head-group, XCD-pinned
    const int nb  = bid >> 2;                  // 0..NGB-1
    const int wv   = threadIdx.x >> 6;
    const int lane = threadIdx.x & 63;
    const int slot = lane >> 4;                // edge slot 0..3
    const int hh   = (lane >> 3) & 1;          // head within group
    const int f2   = lane & 7;                 // feature pair 0..7

    const float cth = ctp[g * 2 + hh];
    const float* __restrict__ ssl = ssg + (size_t)g * 2 * Nn + hh;  // [s*2]
    const float* __restrict__ stl = stg + (size_t)g * 2 * Nn + hh;  // [n*2]
    const __half2* __restrict__ pG = projG2 + (size_t)g * Nn * 16 + hh * 8 + f2; // [s*16]

    const int nbase = (nb * 4 + wv) * NPW;

    for (int nn = 0; nn < NPW; ++nn) {
        const int n = nbase + nn;              // always < Nn (exact partition)
        const int jb = pos[n];
        const int je = (n + 1 < Nn) ? pos[n + 1] : E;
        const float st = stl[n * 2];

        float num0 = 0.f, num1 = 0.f, den = 0.f;
        int j = jb + slot;
        for (; j + 4 < je; j += 8) {           // 2 independent chains
            const unsigned int pk0 = spk[j];
            const unsigned int pk1 = spk[j + 4];
            const int s0 = pk0 & 0xFFFF;
            const int s1 = pk1 & 0xFFFF;
            const float ss0 = ssl[s0 * 2];
            const float ss1 = ssl[s1 * 2];
            const __half2 g0 = pG[s0 * 16];
            const __half2 g1 = pG[s1 * 16];
            const float p0 = __half2float(__ushort_as_half((unsigned short)(pk0 >> 16)));
            const float p1 = __half2float(__ushort_as_half((unsigned short)(pk1 >> 16)));
            float sc0 = ss0 + st + cth * p0;
            float sc1 = ss1 + st + cth * p1;
            sc0 = fmaxf(sc0, 0.2f * sc0);      // leaky_relu(0.2)
            sc1 = fmaxf(sc1, 0.2f * sc1);
            const float ev0 = __expf(sc0);
            const float ev1 = __expf(sc1);
            const float2 G0 = __half22float2(g0);
            const float2 G1 = __half22float2(g1);
            den  += ev0 + ev1;
            num0 += ev0 * G0.x + ev1 * G1.x;
            num1 += ev0 * G0.y + ev1 * G1.y;
        }
        if (j < je) {
            const unsigned int pk = spk[j];
            const int s = pk & 0xFFFF;
            const float p = __half2float(__ushort_as_half((unsigned short)(pk >> 16)));
            float sc = ssl[s * 2] + st + cth * p;
            sc = fmaxf(sc, 0.2f * sc);
            const float ev = __expf(sc);
            const float2 G = __half22float2(pG[s * 16]);
            den  += ev;
            num0 += ev * G.x;
            num1 += ev * G.y;
        }

        // reduce across the 4 edge slots (lane bits 4,5)
        num0 += __shfl_xor(num0, 16, 64);
        num1 += __shfl_xor(num1, 16, 64);
        den  += __shfl_xor(den,  16, 64);
        num0 += __shfl_xor(num0, 32, 64);
        num1 += __shfl_xor(num1, 32, 64);
        den  += __shfl_xor(den,  32, 64);

        if (slot == 0) {
            const int h = g * 2 + hh;
            const int idx = n * HF + h * FO + f2 * 2;
            const float inv = 1.f / (den + 1e-16f);
            float2 o = *reinterpret_cast<const float2*>(&out[idx]);  // skip+bias
            float v0 = o.x + num0 * inv;
            float v1 = o.y + num1 * inv;
            v0 = v0 > 0.f ? v0 : expm1f(v0);
            v1 = v1 > 0.f ? v1 : expm1f(v1);
            *reinterpret_cast<float2*>(&out[idx]) = make_float2(v0, v1);
        }
    }
}

// ---------------------------------------------------------------------------
extern "C" void kernel_launch(void* const* d_in, const int* in_sizes, int n_in,
                              void* d_out, int out_size, void* d_ws, size_t ws_size,
                              hipStream_t stream)
{
    const float* x     = (const float*)d_in[0];
    const int*   ei    = (const int*)d_in[1];
    const float* prob  = (const float*)d_in[2];
    const float* Wp    = (const float*)d_in[3];
    const float* Wt    = (const float*)d_in[4];
    const float* a_src = (const float*)d_in[5];
    const float* a_trg = (const float*)d_in[6];
    const float* a_tp  = (const float*)d_in[7];
    const float* Wskip = (const float*)d_in[8];
    const float* bias  = (const float*)d_in[9];
    float* out = (float*)d_out;

    const int E = in_sizes[2];        // edge_prob element count = E
    const int* src = ei;              // edge_index row 0
    const int* trg = ei + E;          // edge_index row 1

    // Workspace layout (~27 MB); all blocks 16B-aligned by construction
    char* wsb = (char*)d_ws;
    __half* projG  = (__half*)wsb;                      // Nn*HF f16 (12.8 MB)
    float* ssg     = (float*)(wsb + (size_t)Nn*HF*2);   // 4*Nn*2    (1.6 MB)
    float* stg     = ssg + (size_t)4 * Nn * 2;          // 4*Nn*2    (1.6 MB)
    float* ctp     = stg + (size_t)4 * Nn * 2;          // 16 floats
    _Float16* Wh   = (_Float16*)(ctp + 16);             // 272*128   (68 KB)
    unsigned int* spk = (unsigned int*)(Wh + (size_t)NWR * FIN); // E (3.2 MB)
    int*   rank    = (int*)(spk + E);                   // E         (3.2 MB)
    int*   deg     = rank + E;                          // Nn
    int*   pos     = deg + Nn;                          // Nn
    int*   partial = pos + Nn;                          // NSCAN (pad 256)

    const int nbCount = (E + 255) / 256;                // 3125 (1 edge/thread)
    const int nbFill  = (E + 1023) / 1024;              // 782  (4 edges/thread)

    hipMemsetAsync(deg, 0, (size_t)Nn * sizeof(int), stream);
    k_pc<<<NPREP + nbCount, 256, 0, stream>>>(Wp, Wskip, a_src, a_trg, Wt,
                                              a_tp, Wh, ctp, trg, deg, rank, E);
    k_scan1<<<NSCAN, 256, 0, stream>>>(deg, partial);
    k_scan3<<<NSCAN, 256, 0, stream>>>(deg, partial, pos);
    k_fn<<<nbFill + NBLK64, 256, 0, stream>>>(src, trg, prob, rank, pos, spk,
                                              x, Wh, bias, projG, out,
                                              ssg, stg, E, nbFill);
    k_gather<<<4 * NGB, 256, 0, stream>>>(spk, pos, ssg, stg, ctp,
                                          (const __half2*)projG, out, E);
}

// Round 19
// 143.266 us; speedup vs baseline: 1.2556x; 1.2556x over previous
//
#include <hip/hip_runtime.h>
#include <hip/hip_fp16.h>
#include <math.h>

// Problem constants (from reference)
constexpr int Nn  = 50000;   // nodes
constexpr int FIN = 128;     // input features
constexpr int NH  = 8;       // heads
constexpr int FO  = 16;      // features per head
constexpr int HF  = 128;     // NH*FO
constexpr int NWR = 272;     // Wh rows: Wp(128) | Wskip(128) | Va_src(8) | Va_trg(8)
constexpr int NPREP = NWR / 2;                  // 136 prep blocks (2 rows each)
constexpr int NBLK32 = (Nn + 31) / 32;          // 1563 node blocks (32 nodes ea)
constexpr int NSCAN = (Nn + 255) / 256;         // 196 scan blocks

typedef _Float16 f16x8 __attribute__((ext_vector_type(8)));
typedef float    f32x4 __attribute__((ext_vector_type(4)));

// ---------------------------------------------------------------------------
// Fused prep + count-with-rank.
//   blocks [0, NPREP)   : Wh[272][128] f16 (2 rows/block) + ctp (block 0)
//   blocks [NPREP, ...) : rank[e] = atomicAdd(deg[trg[e]], 1)  (1 edge/thread)
// ---------------------------------------------------------------------------
__global__ __launch_bounds__(256) void k_pc(
    const float* __restrict__ Wp, const float* __restrict__ Wskip,
    const float* __restrict__ a_src, const float* __restrict__ a_trg,
    const float* __restrict__ Wt, const float* __restrict__ a_tp,
    _Float16* __restrict__ Wh, float* __restrict__ ctp,
    const int* __restrict__ trg, int* __restrict__ deg,
    int* __restrict__ rank, int E)
{
    const int bid = blockIdx.x;
    if (bid < NPREP) {
        if (bid == 0 && threadIdx.x < NH) {
            int h = threadIdx.x;
            float s = 0.f;
            #pragma unroll
            for (int f = 0; f < FO; ++f) s += Wt[h * FO + f] * a_tp[h * FO + f];
            ctp[h] = s;
        }
        const int o = bid * 2 + (threadIdx.x >> 7);  // 0..271
        const int k = threadIdx.x & 127;
        float v;
        if (o < 128)      v = Wp[o * FIN + k];
        else if (o < 256) v = Wskip[(o - 128) * FIN + k];
        else if (o < 264) {
            const int h = o - 256;
            float s = 0.f;
            #pragma unroll
            for (int f = 0; f < FO; ++f)
                s += a_src[h * FO + f] * Wp[(h * FO + f) * FIN + k];
            v = s;
        } else {
            const int h = o - 264;
            float s = 0.f;
            #pragma unroll
            for (int f = 0; f < FO; ++f)
                s += a_trg[h * FO + f] * Wp[(h * FO + f) * FIN + k];
            v = s;
        }
        Wh[o * FIN + k] = (_Float16)v;
        return;
    }

    int e = (bid - NPREP) * 256 + threadIdx.x;
    if (e < E) rank[e] = atomicAdd(&deg[trg[e]], 1);
}

// ---------------------------------------------------------------------------
// Scan pair. pos stays EXCLUSIVE; row n spans [pos[n], n+1<Nn?pos[n+1]:E).
// ---------------------------------------------------------------------------
__global__ __launch_bounds__(256) void k_scan1(const int* __restrict__ deg,
                                               int* __restrict__ partial)
{
    __shared__ int lds[256];
    int t = threadIdx.x, i = blockIdx.x * 256 + t;
    lds[t] = (i < Nn) ? deg[i] : 0;
    __syncthreads();
    for (int off = 128; off > 0; off >>= 1) {
        if (t < off) lds[t] += lds[t + off];
        __syncthreads();
    }
    if (t == 0) partial[blockIdx.x] = lds[0];
}

__global__ __launch_bounds__(256) void k_scan3(const int* __restrict__ deg,
                                               const int* __restrict__ partial,
                                               int* __restrict__ pos)
{
    __shared__ int lds[256], lds2[256];
    const int t = threadIdx.x;
    const int i = blockIdx.x * 256 + t;
    lds2[t] = (t < NSCAN) ? partial[t] : 0;
    __syncthreads();
    for (int off = 1; off < 256; off <<= 1) {
        int u = (t >= off) ? lds2[t - off] : 0;
        __syncthreads();
        lds2[t] += u;
        __syncthreads();
    }
    const int base = (blockIdx.x == 0) ? 0 : lds2[blockIdx.x - 1];
    int v = (i < Nn) ? deg[i] : 0;
    lds[t] = v;
    __syncthreads();
    for (int off = 1; off < 256; off <<= 1) {
        int u = (t >= off) ? lds[t - off] : 0;
        __syncthreads();
        lds[t] += u;
        __syncthreads();
    }
    if (i < Nn) pos[i] = base + lds[t] - v;
}

// ---------------------------------------------------------------------------
// Fused fill + node GEMM.
//   blocks [0, nbFill)   : fill — slot = pos[trg]+rank (NO atomics);
//                          spk = src(16b) | f16(prob)(16b), 4 edges/thread.
//   blocks [nbFill, ...) : node GEMM, 32 nodes/block (1563 blocks -> 6
//                          waves/SIMD, double R17's grid-limited 3),
//                          B-frags in registers (2x reuse), software-
//                          pipelined A-loads.
// ---------------------------------------------------------------------------
__global__ __launch_bounds__(256) void k_fn(
    const int* __restrict__ src, const int* __restrict__ trg,
    const float* __restrict__ prob, const int* __restrict__ rank,
    const int* __restrict__ pos, unsigned int* __restrict__ spk,
    const float* __restrict__ x, const _Float16* __restrict__ Wh,
    const float* __restrict__ bias,
    __half* __restrict__ projA, float* __restrict__ out,
    float* __restrict__ ssrc, float* __restrict__ strg_s, int E, int nbFill)
{
    const int bid = blockIdx.x;

    if (bid < nbFill) {
        int e4 = bid * 256 + threadIdx.x;
        if (e4 * 4 < E) {
            int4   s4 = reinterpret_cast<const int4*>(src)[e4];
            int4   t4 = reinterpret_cast<const int4*>(trg)[e4];
            float4 p4 = reinterpret_cast<const float4*>(prob)[e4];
            int4   r4 = reinterpret_cast<const int4*>(rank)[e4];
            int    sv[4] = {s4.x, s4.y, s4.z, s4.w};
            int    tv[4] = {t4.x, t4.y, t4.z, t4.w};
            int    rv[4] = {r4.x, r4.y, r4.z, r4.w};
            float  pv[4] = {p4.x, p4.y, p4.z, p4.w};
            #pragma unroll
            for (int i = 0; i < 4; ++i) {
                int slot = pos[tv[i]] + rv[i];
                spk[slot] = (unsigned int)sv[i] |
                    ((unsigned int)__half_as_ushort(__float2half_rn(pv[i])) << 16);
            }
        }
        return;
    }

    // ---- node GEMM ----
    const int g0 = (bid - nbFill) * 32;
    const int w  = threadIdx.x >> 6;           // wave 0..3 (uniform per wave)
    const int l  = threadIdx.x & 63;
    const int lr = l & 15;
    const int kb = l >> 4;                     // k-block 0..3
    const int t0 = w * 4;                      // first tile of this wave

    // B fragments: loaded ONCE, reused across the block's node groups
    f16x8 b[4][4];
    const _Float16* wb = Wh + (size_t)lr * FIN + kb * 8;
    #pragma unroll
    for (int i = 0; i < 4; ++i) {
        #pragma unroll
        for (int ks = 0; ks < 4; ++ks)
            b[i][ks] = *reinterpret_cast<const f16x8*>(
                wb + (size_t)(t0 + i) * 16 * FIN + ks * 32);
    }
    f16x8 b16[4];
    if (w == 3) {
        #pragma unroll
        for (int ks = 0; ks < 4; ++ks)
            b16[ks] = *reinterpret_cast<const f16x8*>(
                wb + (size_t)16 * 16 * FIN + ks * 32);
    }

    const float* xr0 = x + (size_t)(g0 + lr) * FIN + kb * 8;

    if (g0 + 32 <= Nn) {
        // ---- full block: 2 groups, 2-stage pipeline ----
        float4 ucur[8];
        #pragma unroll
        for (int q = 0; q < 8; ++q)
            ucur[q] = *reinterpret_cast<const float4*>(
                xr0 + (q >> 1) * 32 + (q & 1) * 4);

        #pragma unroll
        for (int ng = 0; ng < 2; ++ng) {
            float4 unx[8];
            if (ng < 1) {
                const float* xrn = xr0 + (size_t)16 * FIN;
                #pragma unroll
                for (int q = 0; q < 8; ++q)
                    unx[q] = *reinterpret_cast<const float4*>(
                        xrn + (q >> 1) * 32 + (q & 1) * 4);
            }

            f16x8 a[4];
            #pragma unroll
            for (int ks = 0; ks < 4; ++ks) {
                float4 lo = ucur[ks * 2], hi = ucur[ks * 2 + 1];
                a[ks][0] = (_Float16)lo.x; a[ks][1] = (_Float16)lo.y;
                a[ks][2] = (_Float16)lo.z; a[ks][3] = (_Float16)lo.w;
                a[ks][4] = (_Float16)hi.x; a[ks][5] = (_Float16)hi.y;
                a[ks][6] = (_Float16)hi.z; a[ks][7] = (_Float16)hi.w;
            }

            f32x4 acc[4];
            #pragma unroll
            for (int i = 0; i < 4; ++i) acc[i] = (f32x4){0.f, 0.f, 0.f, 0.f};
            f32x4 acc16 = (f32x4){0.f, 0.f, 0.f, 0.f};

            #pragma unroll
            for (int i = 0; i < 4; ++i) {
                #pragma unroll
                for (int ks = 0; ks < 4; ++ks)
                    acc[i] = __builtin_amdgcn_mfma_f32_16x16x32_f16(
                        a[ks], b[i][ks], acc[i], 0, 0, 0);
            }
            if (w == 3) {
                #pragma unroll
                for (int ks = 0; ks < 4; ++ks)
                    acc16 = __builtin_amdgcn_mfma_f32_16x16x32_f16(
                        a[ks], b16[ks], acc16, 0, 0, 0);
            }

            const int n0 = g0 + ng * 16;
            #pragma unroll
            for (int r = 0; r < 4; ++r) {
                const int n = n0 + kb * 4 + r;
                if (t0 < 8) {
                    #pragma unroll
                    for (int i = 0; i < 4; ++i)
                        projA[(size_t)n * HF + (t0 + i) * FO + lr] =
                            __float2half_rn(acc[i][r]);
                } else {
                    #pragma unroll
                    for (int i = 0; i < 4; ++i) {
                        const int o = (t0 + i - 8) * 16 + lr;
                        out[(size_t)n * HF + o] = acc[i][r] + bias[o];
                    }
                }
                if (w == 3) {
                    if (lr < 8) ssrc[n * 8 + lr] = acc16[r];
                    else        strg_s[n * 8 + (lr - 8)] = acc16[r];
                }
            }

            #pragma unroll
            for (int q = 0; q < 8; ++q) ucur[q] = unx[q];
        }
    } else {
        // ---- partial last block (one 16-node group at 49984) ----
        f16x8 a[4];
        #pragma unroll
        for (int ks = 0; ks < 4; ++ks) {
            float4 u0 = *reinterpret_cast<const float4*>(xr0 + ks * 32);
            float4 u1 = *reinterpret_cast<const float4*>(xr0 + ks * 32 + 4);
            a[ks][0] = (_Float16)u0.x; a[ks][1] = (_Float16)u0.y;
            a[ks][2] = (_Float16)u0.z; a[ks][3] = (_Float16)u0.w;
            a[ks][4] = (_Float16)u1.x; a[ks][5] = (_Float16)u1.y;
            a[ks][6] = (_Float16)u1.z; a[ks][7] = (_Float16)u1.w;
        }

        f32x4 acc[4];
        #pragma unroll
        for (int i = 0; i < 4; ++i) acc[i] = (f32x4){0.f, 0.f, 0.f, 0.f};
        f32x4 acc16 = (f32x4){0.f, 0.f, 0.f, 0.f};

        #pragma unroll
        for (int i = 0; i < 4; ++i) {
            #pragma unroll
            for (int ks = 0; ks < 4; ++ks)
                acc[i] = __builtin_amdgcn_mfma_f32_16x16x32_f16(
                    a[ks], b[i][ks], acc[i], 0, 0, 0);
        }
        if (w == 3) {
            #pragma unroll
            for (int ks = 0; ks < 4; ++ks)
                acc16 = __builtin_amdgcn_mfma_f32_16x16x32_f16(
                    a[ks], b16[ks], acc16, 0, 0, 0);
        }

        #pragma unroll
        for (int r = 0; r < 4; ++r) {
            const int n = g0 + kb * 4 + r;
            if (t0 < 8) {
                #pragma unroll
                for (int i = 0; i < 4; ++i)
                    projA[(size_t)n * HF + (t0 + i) * FO + lr] =
                        __float2half_rn(acc[i][r]);
            } else {
                #pragma unroll
                for (int i = 0; i < 4; ++i) {
                    const int o = (t0 + i - 8) * 16 + lr;
                    out[(size_t)n * HF + o] = acc[i][r] + bias[o];
                }
            }
            if (w == 3) {
                if (lr < 8) ssrc[n * 8 + lr] = acc16[r];
                else        strg_s[n * 8 + (lr - 8)] = acc16[r];
            }
        }
    }
}

// ---------------------------------------------------------------------------
// Fused gather (R17 structure — best measured): one wave per node; lanes =
// 8 heads x 8 feature-pairs. All lanes share the node's edge range (zero
// divergence, zero shuffles). Per edge: spk dword (broadcast) + ssrc[s]
// 32B-segment gather + projA[s] 256B contiguous wave-read; score+exp
// inline. 4 independent chains for memory-level parallelism.
// ---------------------------------------------------------------------------
__global__ __launch_bounds__(256) void k_gather(
    const unsigned int* __restrict__ spk, const int* __restrict__ pos,
    const float* __restrict__ ssrc, const float* __restrict__ strg_s,
    const float* __restrict__ ctp,
    const __half2* __restrict__ projA, float* __restrict__ out, int E)
{
    const int wv   = threadIdx.x >> 6;
    const int n    = blockIdx.x * 4 + wv;      // 12500*4 = 50000 exactly
    const int lane = threadIdx.x & 63;
    const int h    = lane >> 3;                // head 0..7
    const int f2   = lane & 7;                 // feature pair 0..7

    const int jb = pos[n];                     // exclusive prefix
    const int je = (n + 1 < Nn) ? pos[n + 1] : E;
    const float st  = strg_s[n * 8 + h];
    const float cth = ctp[h];
    const float* __restrict__ ssl = ssrc + h;            // [s*8]
    const __half2* __restrict__ pA = projA + h * 8 + f2; // [s*64]

    float num0 = 0.f, num1 = 0.f, den = 0.f;
    int j = jb;
    for (; j + 3 < je; j += 4) {               // 4 independent chains
        const unsigned int pk0 = spk[j];
        const unsigned int pk1 = spk[j + 1];
        const unsigned int pk2 = spk[j + 2];
        const unsigned int pk3 = spk[j + 3];
        const int s0 = pk0 & 0xFFFF, s1 = pk1 & 0xFFFF;
        const int s2 = pk2 & 0xFFFF, s3 = pk3 & 0xFFFF;
        const float ss0 = ssl[s0 * 8], ss1 = ssl[s1 * 8];
        const float ss2 = ssl[s2 * 8], ss3 = ssl[s3 * 8];
        const __half2 g0 = pA[s0 * 64], g1 = pA[s1 * 64];
        const __half2 g2 = pA[s2 * 64], g3 = pA[s3 * 64];
        const float p0 = __half2float(__ushort_as_half((unsigned short)(pk0 >> 16)));
        const float p1 = __half2float(__ushort_as_half((unsigned short)(pk1 >> 16)));
        const float p2 = __half2float(__ushort_as_half((unsigned short)(pk2 >> 16)));
        const float p3 = __half2float(__ushort_as_half((unsigned short)(pk3 >> 16)));
        float sc0 = ss0 + st + cth * p0;
        float sc1 = ss1 + st + cth * p1;
        float sc2 = ss2 + st + cth * p2;
        float sc3 = ss3 + st + cth * p3;
        sc0 = fmaxf(sc0, 0.2f * sc0);          // leaky_relu(0.2)
        sc1 = fmaxf(sc1, 0.2f * sc1);
        sc2 = fmaxf(sc2, 0.2f * sc2);
        sc3 = fmaxf(sc3, 0.2f * sc3);
        const float ev0 = __expf(sc0), ev1 = __expf(sc1);
        const float ev2 = __expf(sc2), ev3 = __expf(sc3);
        const float2 G0 = __half22float2(g0), G1 = __half22float2(g1);
        const float2 G2 = __half22float2(g2), G3 = __half22float2(g3);
        den  += (ev0 + ev1) + (ev2 + ev3);
        num0 += ev0 * G0.x + ev1 * G1.x + ev2 * G2.x + ev3 * G3.x;
        num1 += ev0 * G0.y + ev1 * G1.y + ev2 * G2.y + ev3 * G3.y;
    }
    for (; j < je; ++j) {
        const unsigned int pk = spk[j];
        const int s = pk & 0xFFFF;
        const float p = __half2float(__ushort_as_half((unsigned short)(pk >> 16)));
        float sc = ssl[s * 8] + st + cth * p;
        sc = fmaxf(sc, 0.2f * sc);
        const float ev = __expf(sc);
        const float2 G = __half22float2(pA[s * 64]);
        den  += ev;
        num0 += ev * G.x;
        num1 += ev * G.y;
    }

    const float inv = 1.f / (den + 1e-16f);
    const int idx = n * HF + h * FO + f2 * 2;
    float2 o = *reinterpret_cast<const float2*>(&out[idx]);  // skip+bias
    float v0 = o.x + num0 * inv;
    float v1 = o.y + num1 * inv;
    v0 = v0 > 0.f ? v0 : expm1f(v0);
    v1 = v1 > 0.f ? v1 : expm1f(v1);
    *reinterpret_cast<float2*>(&out[idx]) = make_float2(v0, v1);
}

// ---------------------------------------------------------------------------
extern "C" void kernel_launch(void* const* d_in, const int* in_sizes, int n_in,
                              void* d_out, int out_size, void* d_ws, size_t ws_size,
                              hipStream_t stream)
{
    const float* x     = (const float*)d_in[0];
    const int*   ei    = (const int*)d_in[1];
    const float* prob  = (const float*)d_in[2];
    const float* Wp    = (const float*)d_in[3];
    const float* Wt    = (const float*)d_in[4];
    const float* a_src = (const float*)d_in[5];
    const float* a_trg = (const float*)d_in[6];
    const float* a_tp  = (const float*)d_in[7];
    const float* Wskip = (const float*)d_in[8];
    const float* bias  = (const float*)d_in[9];
    float* out = (float*)d_out;

    const int E = in_sizes[2];        // edge_prob element count = E
    const int* src = ei;              // edge_index row 0
    const int* trg = ei + E;          // edge_index row 1

    // Workspace layout (~27 MB); all blocks 16B-aligned by construction
    char* wsb = (char*)d_ws;
    __half* projA  = (__half*)wsb;                      // Nn*HF f16 (12.8 MB)
    float* ssrc    = (float*)(wsb + (size_t)Nn*HF*2);   // Nn*8      (1.6 MB)
    float* strg_s  = ssrc + (size_t)Nn * 8;             // Nn*8      (1.6 MB)
    float* ctp     = strg_s + (size_t)Nn * 8;           // 16 floats
    _Float16* Wh   = (_Float16*)(ctp + 16);             // 272*128   (68 KB)
    unsigned int* spk = (unsigned int*)(Wh + (size_t)NWR * FIN); // E (3.2 MB)
    int*   rank    = (int*)(spk + E);                   // E         (3.2 MB)
    int*   deg     = rank + E;                          // Nn
    int*   pos     = deg + Nn;                          // Nn
    int*   partial = pos + Nn;                          // NSCAN (pad 256)

    const int nbCount = (E + 255) / 256;                // 3125 (1 edge/thread)
    const int nbFill  = (E + 1023) / 1024;              // 782  (4 edges/thread)

    hipMemsetAsync(deg, 0, (size_t)Nn * sizeof(int), stream);
    k_pc<<<NPREP + nbCount, 256, 0, stream>>>(Wp, Wskip, a_src, a_trg, Wt,
                                              a_tp, Wh, ctp, trg, deg, rank, E);
    k_scan1<<<NSCAN, 256, 0, stream>>>(deg, partial);
    k_scan3<<<NSCAN, 256, 0, stream>>>(deg, partial, pos);
    k_fn<<<nbFill + NBLK32, 256, 0, stream>>>(src, trg, prob, rank, pos, spk,
                                              x, Wh, bias, projA, out,
                                              ssrc, strg_s, E, nbFill);
    k_gather<<<Nn / 4, 256, 0, stream>>>(spk, pos, ssrc, strg_s, ctp,
                                         (const __half2*)projA, out, E);
}

// Round 20
// 133.799 us; speedup vs baseline: 1.3445x; 1.0708x over previous
//
#include <hip/hip_runtime.h>
#include <hip/hip_fp16.h>
#include <math.h>

// Problem constants (from reference)
constexpr int Nn  = 50000;   // nodes
constexpr int FIN = 128;     // input features
constexpr int NH  = 8;       // heads
constexpr int FO  = 16;      // features per head
constexpr int HF  = 128;     // NH*FO
constexpr int NWR = 272;     // Wh rows: Wp(128) | Wskip(128) | Va_src(8) | Va_trg(8)
constexpr int NPREP = NWR / 2;                  // 136 prep blocks (2 rows each)
constexpr int NBLK64 = (Nn + 63) / 64;          // 782 node blocks (64 nodes ea)
constexpr int NSCAN = (Nn + 255) / 256;         // 196 scan blocks

typedef _Float16 f16x8 __attribute__((ext_vector_type(8)));
typedef float    f32x4 __attribute__((ext_vector_type(4)));

// ---------------------------------------------------------------------------
// Fused prep + count-with-rank.
//   blocks [0, NPREP)   : Wh[272][128] f16 (2 rows/block) + ctp (block 0)
//   blocks [NPREP, ...) : rank[e] = atomicAdd(deg[trg[e]], 1)  (1 edge/thread)
// ---------------------------------------------------------------------------
__global__ __launch_bounds__(256) void k_pc(
    const float* __restrict__ Wp, const float* __restrict__ Wskip,
    const float* __restrict__ a_src, const float* __restrict__ a_trg,
    const float* __restrict__ Wt, const float* __restrict__ a_tp,
    _Float16* __restrict__ Wh, float* __restrict__ ctp,
    const int* __restrict__ trg, int* __restrict__ deg,
    int* __restrict__ rank, int E)
{
    const int bid = blockIdx.x;
    if (bid < NPREP) {
        if (bid == 0 && threadIdx.x < NH) {
            int h = threadIdx.x;
            float s = 0.f;
            #pragma unroll
            for (int f = 0; f < FO; ++f) s += Wt[h * FO + f] * a_tp[h * FO + f];
            ctp[h] = s;
        }
        const int o = bid * 2 + (threadIdx.x >> 7);  // 0..271
        const int k = threadIdx.x & 127;
        float v;
        if (o < 128)      v = Wp[o * FIN + k];
        else if (o < 256) v = Wskip[(o - 128) * FIN + k];
        else if (o < 264) {
            const int h = o - 256;
            float s = 0.f;
            #pragma unroll
            for (int f = 0; f < FO; ++f)
                s += a_src[h * FO + f] * Wp[(h * FO + f) * FIN + k];
            v = s;
        } else {
            const int h = o - 264;
            float s = 0.f;
            #pragma unroll
            for (int f = 0; f < FO; ++f)
                s += a_trg[h * FO + f] * Wp[(h * FO + f) * FIN + k];
            v = s;
        }
        Wh[o * FIN + k] = (_Float16)v;
        return;
    }

    int e = (bid - NPREP) * 256 + threadIdx.x;
    if (e < E) rank[e] = atomicAdd(&deg[trg[e]], 1);
}

// ---------------------------------------------------------------------------
// Scan pair. pos stays EXCLUSIVE; row n spans [pos[n], n+1<Nn?pos[n+1]:E).
// ---------------------------------------------------------------------------
__global__ __launch_bounds__(256) void k_scan1(const int* __restrict__ deg,
                                               int* __restrict__ partial)
{
    __shared__ int lds[256];
    int t = threadIdx.x, i = blockIdx.x * 256 + t;
    lds[t] = (i < Nn) ? deg[i] : 0;
    __syncthreads();
    for (int off = 128; off > 0; off >>= 1) {
        if (t < off) lds[t] += lds[t + off];
        __syncthreads();
    }
    if (t == 0) partial[blockIdx.x] = lds[0];
}

__global__ __launch_bounds__(256) void k_scan3(const int* __restrict__ deg,
                                               const int* __restrict__ partial,
                                               int* __restrict__ pos)
{
    __shared__ int lds[256], lds2[256];
    const int t = threadIdx.x;
    const int i = blockIdx.x * 256 + t;
    lds2[t] = (t < NSCAN) ? partial[t] : 0;
    __syncthreads();
    for (int off = 1; off < 256; off <<= 1) {
        int u = (t >= off) ? lds2[t - off] : 0;
        __syncthreads();
        lds2[t] += u;
        __syncthreads();
    }
    const int base = (blockIdx.x == 0) ? 0 : lds2[blockIdx.x - 1];
    int v = (i < Nn) ? deg[i] : 0;
    lds[t] = v;
    __syncthreads();
    for (int off = 1; off < 256; off <<= 1) {
        int u = (t >= off) ? lds[t - off] : 0;
        __syncthreads();
        lds[t] += u;
        __syncthreads();
    }
    if (i < Nn) pos[i] = base + lds[t] - v;
}

// ---------------------------------------------------------------------------
// Fused fill + node GEMM (R17 configuration — best measured family).
//   blocks [0, nbFill)   : fill — slot = pos[trg]+rank (NO atomics);
//                          spk = src(16b) | f16(prob)(16b), 4 edges/thread.
//   blocks [nbFill, ...) : node GEMM, 64 nodes/block, B-frags in registers,
//                          software-pipelined A-loads.
// ---------------------------------------------------------------------------
__global__ __launch_bounds__(256) void k_fn(
    const int* __restrict__ src, const int* __restrict__ trg,
    const float* __restrict__ prob, const int* __restrict__ rank,
    const int* __restrict__ pos, unsigned int* __restrict__ spk,
    const float* __restrict__ x, const _Float16* __restrict__ Wh,
    const float* __restrict__ bias,
    __half* __restrict__ projA, float* __restrict__ out,
    float* __restrict__ ssrc, float* __restrict__ strg_s, int E, int nbFill)
{
    const int bid = blockIdx.x;

    if (bid < nbFill) {
        int e4 = bid * 256 + threadIdx.x;
        if (e4 * 4 < E) {
            int4   s4 = reinterpret_cast<const int4*>(src)[e4];
            int4   t4 = reinterpret_cast<const int4*>(trg)[e4];
            float4 p4 = reinterpret_cast<const float4*>(prob)[e4];
            int4   r4 = reinterpret_cast<const int4*>(rank)[e4];
            int    sv[4] = {s4.x, s4.y, s4.z, s4.w};
            int    tv[4] = {t4.x, t4.y, t4.z, t4.w};
            int    rv[4] = {r4.x, r4.y, r4.z, r4.w};
            float  pv[4] = {p4.x, p4.y, p4.z, p4.w};
            #pragma unroll
            for (int i = 0; i < 4; ++i) {
                int slot = pos[tv[i]] + rv[i];
                spk[slot] = (unsigned int)sv[i] |
                    ((unsigned int)__half_as_ushort(__float2half_rn(pv[i])) << 16);
            }
        }
        return;
    }

    // ---- node GEMM ----
    const int g0 = (bid - nbFill) * 64;
    const int w  = threadIdx.x >> 6;           // wave 0..3 (uniform per wave)
    const int l  = threadIdx.x & 63;
    const int lr = l & 15;
    const int kb = l >> 4;                     // k-block 0..3
    const int t0 = w * 4;                      // first tile of this wave

    // B fragments: loaded ONCE, reused across all node groups
    f16x8 b[4][4];
    const _Float16* wb = Wh + (size_t)lr * FIN + kb * 8;
    #pragma unroll
    for (int i = 0; i < 4; ++i) {
        #pragma unroll
        for (int ks = 0; ks < 4; ++ks)
            b[i][ks] = *reinterpret_cast<const f16x8*>(
                wb + (size_t)(t0 + i) * 16 * FIN + ks * 32);
    }
    f16x8 b16[4];
    if (w == 3) {
        #pragma unroll
        for (int ks = 0; ks < 4; ++ks)
            b16[ks] = *reinterpret_cast<const f16x8*>(
                wb + (size_t)16 * 16 * FIN + ks * 32);
    }

    const float* xr0 = x + (size_t)(g0 + lr) * FIN + kb * 8;

    if (g0 + 64 <= Nn) {
        // ---- full block: 4 groups, 2-stage pipeline ----
        float4 ucur[8];
        #pragma unroll
        for (int q = 0; q < 8; ++q)
            ucur[q] = *reinterpret_cast<const float4*>(
                xr0 + (q >> 1) * 32 + (q & 1) * 4);

        #pragma unroll
        for (int ng = 0; ng < 4; ++ng) {
            float4 unx[8];
            if (ng < 3) {
                const float* xrn = xr0 + (size_t)(ng + 1) * 16 * FIN;
                #pragma unroll
                for (int q = 0; q < 8; ++q)
                    unx[q] = *reinterpret_cast<const float4*>(
                        xrn + (q >> 1) * 32 + (q & 1) * 4);
            }

            f16x8 a[4];
            #pragma unroll
            for (int ks = 0; ks < 4; ++ks) {
                float4 lo = ucur[ks * 2], hi = ucur[ks * 2 + 1];
                a[ks][0] = (_Float16)lo.x; a[ks][1] = (_Float16)lo.y;
                a[ks][2] = (_Float16)lo.z; a[ks][3] = (_Float16)lo.w;
                a[ks][4] = (_Float16)hi.x; a[ks][5] = (_Float16)hi.y;
                a[ks][6] = (_Float16)hi.z; a[ks][7] = (_Float16)hi.w;
            }

            f32x4 acc[4];
            #pragma unroll
            for (int i = 0; i < 4; ++i) acc[i] = (f32x4){0.f, 0.f, 0.f, 0.f};
            f32x4 acc16 = (f32x4){0.f, 0.f, 0.f, 0.f};

            #pragma unroll
            for (int i = 0; i < 4; ++i) {
                #pragma unroll
                for (int ks = 0; ks < 4; ++ks)
                    acc[i] = __builtin_amdgcn_mfma_f32_16x16x32_f16(
                        a[ks], b[i][ks], acc[i], 0, 0, 0);
            }
            if (w == 3) {
                #pragma unroll
                for (int ks = 0; ks < 4; ++ks)
                    acc16 = __builtin_amdgcn_mfma_f32_16x16x32_f16(
                        a[ks], b16[ks], acc16, 0, 0, 0);
            }

            const int n0 = g0 + ng * 16;
            #pragma unroll
            for (int r = 0; r < 4; ++r) {
                const int n = n0 + kb * 4 + r;
                if (t0 < 8) {
                    #pragma unroll
                    for (int i = 0; i < 4; ++i)
                        projA[(size_t)n * HF + (t0 + i) * FO + lr] =
                            __float2half_rn(acc[i][r]);
                } else {
                    #pragma unroll
                    for (int i = 0; i < 4; ++i) {
                        const int o = (t0 + i - 8) * 16 + lr;
                        out[(size_t)n * HF + o] = acc[i][r] + bias[o];
                    }
                }
                if (w == 3) {
                    if (lr < 8) ssrc[n * 8 + lr] = acc16[r];
                    else        strg_s[n * 8 + (lr - 8)] = acc16[r];
                }
            }

            #pragma unroll
            for (int q = 0; q < 8; ++q) ucur[q] = unx[q];
        }
    } else {
        // ---- partial last block (one 16-node group at 49984) ----
        f16x8 a[4];
        #pragma unroll
        for (int ks = 0; ks < 4; ++ks) {
            float4 u0 = *reinterpret_cast<const float4*>(xr0 + ks * 32);
            float4 u1 = *reinterpret_cast<const float4*>(xr0 + ks * 32 + 4);
            a[ks][0] = (_Float16)u0.x; a[ks][1] = (_Float16)u0.y;
            a[ks][2] = (_Float16)u0.z; a[ks][3] = (_Float16)u0.w;
            a[ks][4] = (_Float16)u1.x; a[ks][5] = (_Float16)u1.y;
            a[ks][6] = (_Float16)u1.z; a[ks][7] = (_Float16)u1.w;
        }

        f32x4 acc[4];
        #pragma unroll
        for (int i = 0; i < 4; ++i) acc[i] = (f32x4){0.f, 0.f, 0.f, 0.f};
        f32x4 acc16 = (f32x4){0.f, 0.f, 0.f, 0.f};

        #pragma unroll
        for (int i = 0; i < 4; ++i) {
            #pragma unroll
            for (int ks = 0; ks < 4; ++ks)
                acc[i] = __builtin_amdgcn_mfma_f32_16x16x32_f16(
                    a[ks], b[i][ks], acc[i], 0, 0, 0);
        }
        if (w == 3) {
            #pragma unroll
            for (int ks = 0; ks < 4; ++ks)
                acc16 = __builtin_amdgcn_mfma_f32_16x16x32_f16(
                    a[ks], b16[ks], acc16, 0, 0, 0);
        }

        #pragma unroll
        for (int r = 0; r < 4; ++r) {
            const int n = g0 + kb * 4 + r;
            if (t0 < 8) {
                #pragma unroll
                for (int i = 0; i < 4; ++i)
                    projA[(size_t)n * HF + (t0 + i) * FO + lr] =
                        __float2half_rn(acc[i][r]);
            } else {
                #pragma unroll
                for (int i = 0; i < 4; ++i) {
                    const int o = (t0 + i - 8) * 16 + lr;
                    out[(size_t)n * HF + o] = acc[i][r] + bias[o];
                }
            }
            if (w == 3) {
                if (lr < 8) ssrc[n * 8 + lr] = acc16[r];
                else        strg_s[n * 8 + (lr - 8)] = acc16[r];
            }
        }
    }
}

// ---------------------------------------------------------------------------
// Fused gather with SCALARIZED edge walk: one wave per node. n, jb, je and
// every spk[j] / ssrc[s] address are wave-uniform — readfirstlane forces
// them into SGPRs so the edge stream moves to the scalar pipe (s_load +
// SALU), leaving the VALU only the genuinely per-lane work (score add,
// leaky, exp, half2 unpack, 2 FMAs). Lanes = 8 heads x 8 feature-pairs.
// ---------------------------------------------------------------------------
__global__ __launch_bounds__(256) void k_gather(
    const unsigned int* __restrict__ spk, const int* __restrict__ pos,
    const float* __restrict__ ssrc, const float* __restrict__ strg_s,
    const float* __restrict__ ctp,
    const __half2* __restrict__ projA, float* __restrict__ out, int E)
{
    const int lane = threadIdx.x & 63;
    const int h    = lane >> 3;                // head 0..7
    const int f2   = lane & 7;                 // feature pair 0..7

    // wave-uniform node id, forced scalar
    const int n = __builtin_amdgcn_readfirstlane(
        blockIdx.x * 4 + (threadIdx.x >> 6));  // 12500*4 = 50000 exactly

    const int jb = __builtin_amdgcn_readfirstlane(pos[n]);
    const int je = __builtin_amdgcn_readfirstlane((n + 1 < Nn) ? pos[n + 1] : E);

    const float st  = strg_s[n * 8 + h];
    const float cth = ctp[h];
    const float* __restrict__ ssl = ssrc + h;            // [s*8]
    const __half2* __restrict__ pA = projA + h * 8 + f2; // [s*64]

    float num0 = 0.f, num1 = 0.f, den = 0.f;
    int j = jb;
    for (; j + 3 < je; j += 4) {               // 4 independent chains
        const unsigned int pk0 = __builtin_amdgcn_readfirstlane(spk[j]);
        const unsigned int pk1 = __builtin_amdgcn_readfirstlane(spk[j + 1]);
        const unsigned int pk2 = __builtin_amdgcn_readfirstlane(spk[j + 2]);
        const unsigned int pk3 = __builtin_amdgcn_readfirstlane(spk[j + 3]);
        const int s0 = pk0 & 0xFFFF, s1 = pk1 & 0xFFFF;
        const int s2 = pk2 & 0xFFFF, s3 = pk3 & 0xFFFF;
        const float ss0 = ssl[s0 * 8], ss1 = ssl[s1 * 8];
        const float ss2 = ssl[s2 * 8], ss3 = ssl[s3 * 8];
        const __half2 g0 = pA[s0 * 64], g1 = pA[s1 * 64];
        const __half2 g2 = pA[s2 * 64], g3 = pA[s3 * 64];
        const float p0 = __half2float(__ushort_as_half((unsigned short)(pk0 >> 16)));
        const float p1 = __half2float(__ushort_as_half((unsigned short)(pk1 >> 16)));
        const float p2 = __half2float(__ushort_as_half((unsigned short)(pk2 >> 16)));
        const float p3 = __half2float(__ushort_as_half((unsigned short)(pk3 >> 16)));
        float sc0 = ss0 + st + cth * p0;
        float sc1 = ss1 + st + cth * p1;
        float sc2 = ss2 + st + cth * p2;
        float sc3 = ss3 + st + cth * p3;
        sc0 = fmaxf(sc0, 0.2f * sc0);          // leaky_relu(0.2)
        sc1 = fmaxf(sc1, 0.2f * sc1);
        sc2 = fmaxf(sc2, 0.2f * sc2);
        sc3 = fmaxf(sc3, 0.2f * sc3);
        const float ev0 = __expf(sc0), ev1 = __expf(sc1);
        const float ev2 = __expf(sc2), ev3 = __expf(sc3);
        const float2 G0 = __half22float2(g0), G1 = __half22float2(g1);
        const float2 G2 = __half22float2(g2), G3 = __half22float2(g3);
        den  += (ev0 + ev1) + (ev2 + ev3);
        num0 += ev0 * G0.x + ev1 * G1.x + ev2 * G2.x + ev3 * G3.x;
        num1 += ev0 * G0.y + ev1 * G1.y + ev2 * G2.y + ev3 * G3.y;
    }
    for (; j < je; ++j) {
        const unsigned int pk = __builtin_amdgcn_readfirstlane(spk[j]);
        const int s = pk & 0xFFFF;
        const float p = __half2float(__ushort_as_half((unsigned short)(pk >> 16)));
        float sc = ssl[s * 8] + st + cth * p;
        sc = fmaxf(sc, 0.2f * sc);
        const float ev = __expf(sc);
        const float2 G = __half22float2(pA[s * 64]);
        den  += ev;
        num0 += ev * G.x;
        num1 += ev * G.y;
    }

    const float inv = 1.f / (den + 1e-16f);
    const int idx = n * HF + h * FO + f2 * 2;
    float2 o = *reinterpret_cast<const float2*>(&out[idx]);  // skip+bias
    float v0 = o.x + num0 * inv;
    float v1 = o.y + num1 * inv;
    v0 = v0 > 0.f ? v0 : expm1f(v0);
    v1 = v1 > 0.f ? v1 : expm1f(v1);
    *reinterpret_cast<float2*>(&out[idx]) = make_float2(v0, v1);
}

// ---------------------------------------------------------------------------
extern "C" void kernel_launch(void* const* d_in, const int* in_sizes, int n_in,
                              void* d_out, int out_size, void* d_ws, size_t ws_size,
                              hipStream_t stream)
{
    const float* x     = (const float*)d_in[0];
    const int*   ei    = (const int*)d_in[1];
    const float* prob  = (const float*)d_in[2];
    const float* Wp    = (const float*)d_in[3];
    const float* Wt    = (const float*)d_in[4];
    const float* a_src = (const float*)d_in[5];
    const float* a_trg = (const float*)d_in[6];
    const float* a_tp  = (const float*)d_in[7];
    const float* Wskip = (const float*)d_in[8];
    const float* bias  = (const float*)d_in[9];
    float* out = (float*)d_out;

    const int E = in_sizes[2];        // edge_prob element count = E
    const int* src = ei;              // edge_index row 0
    const int* trg = ei + E;          // edge_index row 1

    // Workspace layout (~27 MB); all blocks 16B-aligned by construction
    char* wsb = (char*)d_ws;
    __half* projA  = (__half*)wsb;                      // Nn*HF f16 (12.8 MB)
    float* ssrc    = (float*)(wsb + (size_t)Nn*HF*2);   // Nn*8      (1.6 MB)
    float* strg_s  = ssrc + (size_t)Nn * 8;             // Nn*8      (1.6 MB)
    float* ctp     = strg_s + (size_t)Nn * 8;           // 16 floats
    _Float16* Wh   = (_Float16*)(ctp + 16);             // 272*128   (68 KB)
    unsigned int* spk = (unsigned int*)(Wh + (size_t)NWR * FIN); // E (3.2 MB)
    int*   rank    = (int*)(spk + E);                   // E         (3.2 MB)
    int*   deg     = rank + E;                          // Nn
    int*   pos     = deg + Nn;                          // Nn
    int*   partial = pos + Nn;                          // NSCAN (pad 256)

    const int nbCount = (E + 255) / 256;                // 3125 (1 edge/thread)
    const int nbFill  = (E + 1023) / 1024;              // 782  (4 edges/thread)

    hipMemsetAsync(deg, 0, (size_t)Nn * sizeof(int), stream);
    k_pc<<<NPREP + nbCount, 256, 0, stream>>>(Wp, Wskip, a_src, a_trg, Wt,
                                              a_tp, Wh, ctp, trg, deg, rank, E);
    k_scan1<<<NSCAN, 256, 0, stream>>>(deg, partial);
    k_scan3<<<NSCAN, 256, 0, stream>>>(deg, partial, pos);
    k_fn<<<nbFill + NBLK64, 256, 0, stream>>>(src, trg, prob, rank, pos, spk,
                                              x, Wh, bias, projA, out,
                                              ssrc, strg_s, E, nbFill);
    k_gather<<<Nn / 4, 256, 0, stream>>>(spk, pos, ssrc, strg_s, ctp,
                                         (const __half2*)projA, out, E);
}

// Round 21
// 131.167 us; speedup vs baseline: 1.3714x; 1.0201x over previous
//
#include <hip/hip_runtime.h>
#include <hip/hip_fp16.h>
#include <math.h>

// Problem constants (from reference)
constexpr int Nn  = 50000;   // nodes
constexpr int FIN = 128;     // input features
constexpr int NH  = 8;       // heads
constexpr int FO  = 16;      // features per head
constexpr int HF  = 128;     // NH*FO
constexpr int NWR = 272;     // Wh rows: Wp(128) | Wskip(128) | Va_src(8) | Va_trg(8)
constexpr int NPREP = NWR / 2;                  // 136 prep blocks (2 rows each)
constexpr int NBLK64 = (Nn + 63) / 64;          // 782 node blocks (64 nodes ea)
constexpr int NSCAN = (Nn + 255) / 256;         // 196 scan blocks

typedef _Float16 f16x8 __attribute__((ext_vector_type(8)));
typedef float    f32x4 __attribute__((ext_vector_type(4)));

// ---------------------------------------------------------------------------
// Fused prep + count-with-rank.
//   blocks [0, NPREP)   : Wh[272][128] f16 (2 rows/block) + ctp (block 0)
//   blocks [NPREP, ...) : rank[e] = atomicAdd(deg[trg[e]], 1)  (1 edge/thread)
// ---------------------------------------------------------------------------
__global__ __launch_bounds__(256) void k_pc(
    const float* __restrict__ Wp, const float* __restrict__ Wskip,
    const float* __restrict__ a_src, const float* __restrict__ a_trg,
    const float* __restrict__ Wt, const float* __restrict__ a_tp,
    _Float16* __restrict__ Wh, float* __restrict__ ctp,
    const int* __restrict__ trg, int* __restrict__ deg,
    int* __restrict__ rank, int E)
{
    const int bid = blockIdx.x;
    if (bid < NPREP) {
        if (bid == 0 && threadIdx.x < NH) {
            int h = threadIdx.x;
            float s = 0.f;
            #pragma unroll
            for (int f = 0; f < FO; ++f) s += Wt[h * FO + f] * a_tp[h * FO + f];
            ctp[h] = s;
        }
        const int o = bid * 2 + (threadIdx.x >> 7);  // 0..271
        const int k = threadIdx.x & 127;
        float v;
        if (o < 128)      v = Wp[o * FIN + k];
        else if (o < 256) v = Wskip[(o - 128) * FIN + k];
        else if (o < 264) {
            const int h = o - 256;
            float s = 0.f;
            #pragma unroll
            for (int f = 0; f < FO; ++f)
                s += a_src[h * FO + f] * Wp[(h * FO + f) * FIN + k];
            v = s;
        } else {
            const int h = o - 264;
            float s = 0.f;
            #pragma unroll
            for (int f = 0; f < FO; ++f)
                s += a_trg[h * FO + f] * Wp[(h * FO + f) * FIN + k];
            v = s;
        }
        Wh[o * FIN + k] = (_Float16)v;
        return;
    }

    int e = (bid - NPREP) * 256 + threadIdx.x;
    if (e < E) rank[e] = atomicAdd(&deg[trg[e]], 1);
}

// ---------------------------------------------------------------------------
// Scan pair. pos stays EXCLUSIVE; row n spans [pos[n], n+1<Nn?pos[n+1]:E).
// ---------------------------------------------------------------------------
__global__ __launch_bounds__(256) void k_scan1(const int* __restrict__ deg,
                                               int* __restrict__ partial)
{
    __shared__ int lds[256];
    int t = threadIdx.x, i = blockIdx.x * 256 + t;
    lds[t] = (i < Nn) ? deg[i] : 0;
    __syncthreads();
    for (int off = 128; off > 0; off >>= 1) {
        if (t < off) lds[t] += lds[t + off];
        __syncthreads();
    }
    if (t == 0) partial[blockIdx.x] = lds[0];
}

__global__ __launch_bounds__(256) void k_scan3(const int* __restrict__ deg,
                                               const int* __restrict__ partial,
                                               int* __restrict__ pos)
{
    __shared__ int lds[256], lds2[256];
    const int t = threadIdx.x;
    const int i = blockIdx.x * 256 + t;
    lds2[t] = (t < NSCAN) ? partial[t] : 0;
    __syncthreads();
    for (int off = 1; off < 256; off <<= 1) {
        int u = (t >= off) ? lds2[t - off] : 0;
        __syncthreads();
        lds2[t] += u;
        __syncthreads();
    }
    const int base = (blockIdx.x == 0) ? 0 : lds2[blockIdx.x - 1];
    int v = (i < Nn) ? deg[i] : 0;
    lds[t] = v;
    __syncthreads();
    for (int off = 1; off < 256; off <<= 1) {
        int u = (t >= off) ? lds[t - off] : 0;
        __syncthreads();
        lds[t] += u;
        __syncthreads();
    }
    if (i < Nn) pos[i] = base + lds[t] - v;
}

// ---------------------------------------------------------------------------
// Node GEMM with INTRA-BLOCK fill overlap: every block does its 64-node
// GEMM AND fills a 1024-edge chunk. Fill's raw edge loads issue BEFORE the
// GEMM body (latency hides under 80 MFMAs + pipelined A-loads); the
// pos-gather + spk scatter-writes run after the epilogue (T14-style
// async-stage at block scope). Resources disjoint; no atomics in fill.
// ---------------------------------------------------------------------------
__global__ __launch_bounds__(256) void k_fn(
    const int* __restrict__ src, const int* __restrict__ trg,
    const float* __restrict__ prob, const int* __restrict__ rank,
    const int* __restrict__ pos, unsigned int* __restrict__ spk,
    const float* __restrict__ x, const _Float16* __restrict__ Wh,
    const float* __restrict__ bias,
    __half* __restrict__ projA, float* __restrict__ out,
    float* __restrict__ ssrc, float* __restrict__ strg_s, int E)
{
    const int bid = blockIdx.x;

    // ---- fill stage A: issue raw edge loads (consumed at the end) ----
    const int e4 = bid * 256 + threadIdx.x;    // edge quad index
    const bool doFill = (e4 * 4 < E);
    int4 s4, t4, r4; float4 p4;
    if (doFill) {
        s4 = reinterpret_cast<const int4*>(src)[e4];
        t4 = reinterpret_cast<const int4*>(trg)[e4];
        p4 = reinterpret_cast<const float4*>(prob)[e4];
        r4 = reinterpret_cast<const int4*>(rank)[e4];
    }

    // ---- node GEMM ----
    const int g0 = bid * 64;
    const int w  = threadIdx.x >> 6;           // wave 0..3 (uniform per wave)
    const int l  = threadIdx.x & 63;
    const int lr = l & 15;
    const int kb = l >> 4;                     // k-block 0..3
    const int t0 = w * 4;                      // first tile of this wave

    // B fragments: loaded ONCE, reused across all node groups
    f16x8 b[4][4];
    const _Float16* wb = Wh + (size_t)lr * FIN + kb * 8;
    #pragma unroll
    for (int i = 0; i < 4; ++i) {
        #pragma unroll
        for (int ks = 0; ks < 4; ++ks)
            b[i][ks] = *reinterpret_cast<const f16x8*>(
                wb + (size_t)(t0 + i) * 16 * FIN + ks * 32);
    }
    f16x8 b16[4];
    if (w == 3) {
        #pragma unroll
        for (int ks = 0; ks < 4; ++ks)
            b16[ks] = *reinterpret_cast<const f16x8*>(
                wb + (size_t)16 * 16 * FIN + ks * 32);
    }

    const float* xr0 = x + (size_t)(g0 + lr) * FIN + kb * 8;

    if (g0 + 64 <= Nn) {
        // ---- full block: 4 groups, 2-stage pipeline ----
        float4 ucur[8];
        #pragma unroll
        for (int q = 0; q < 8; ++q)
            ucur[q] = *reinterpret_cast<const float4*>(
                xr0 + (q >> 1) * 32 + (q & 1) * 4);

        #pragma unroll
        for (int ng = 0; ng < 4; ++ng) {
            float4 unx[8];
            if (ng < 3) {
                const float* xrn = xr0 + (size_t)(ng + 1) * 16 * FIN;
                #pragma unroll
                for (int q = 0; q < 8; ++q)
                    unx[q] = *reinterpret_cast<const float4*>(
                        xrn + (q >> 1) * 32 + (q & 1) * 4);
            }

            f16x8 a[4];
            #pragma unroll
            for (int ks = 0; ks < 4; ++ks) {
                float4 lo = ucur[ks * 2], hi = ucur[ks * 2 + 1];
                a[ks][0] = (_Float16)lo.x; a[ks][1] = (_Float16)lo.y;
                a[ks][2] = (_Float16)lo.z; a[ks][3] = (_Float16)lo.w;
                a[ks][4] = (_Float16)hi.x; a[ks][5] = (_Float16)hi.y;
                a[ks][6] = (_Float16)hi.z; a[ks][7] = (_Float16)hi.w;
            }

            f32x4 acc[4];
            #pragma unroll
            for (int i = 0; i < 4; ++i) acc[i] = (f32x4){0.f, 0.f, 0.f, 0.f};
            f32x4 acc16 = (f32x4){0.f, 0.f, 0.f, 0.f};

            #pragma unroll
            for (int i = 0; i < 4; ++i) {
                #pragma unroll
                for (int ks = 0; ks < 4; ++ks)
                    acc[i] = __builtin_amdgcn_mfma_f32_16x16x32_f16(
                        a[ks], b[i][ks], acc[i], 0, 0, 0);
            }
            if (w == 3) {
                #pragma unroll
                for (int ks = 0; ks < 4; ++ks)
                    acc16 = __builtin_amdgcn_mfma_f32_16x16x32_f16(
                        a[ks], b16[ks], acc16, 0, 0, 0);
            }

            const int n0 = g0 + ng * 16;
            #pragma unroll
            for (int r = 0; r < 4; ++r) {
                const int n = n0 + kb * 4 + r;
                if (t0 < 8) {
                    #pragma unroll
                    for (int i = 0; i < 4; ++i)
                        projA[(size_t)n * HF + (t0 + i) * FO + lr] =
                            __float2half_rn(acc[i][r]);
                } else {
                    #pragma unroll
                    for (int i = 0; i < 4; ++i) {
                        const int o = (t0 + i - 8) * 16 + lr;
                        out[(size_t)n * HF + o] = acc[i][r] + bias[o];
                    }
                }
                if (w == 3) {
                    if (lr < 8) ssrc[n * 8 + lr] = acc16[r];
                    else        strg_s[n * 8 + (lr - 8)] = acc16[r];
                }
            }

            #pragma unroll
            for (int q = 0; q < 8; ++q) ucur[q] = unx[q];
        }
    } else {
        // ---- partial last block (one 16-node group at 49984) ----
        f16x8 a[4];
        #pragma unroll
        for (int ks = 0; ks < 4; ++ks) {
            float4 u0 = *reinterpret_cast<const float4*>(xr0 + ks * 32);
            float4 u1 = *reinterpret_cast<const float4*>(xr0 + ks * 32 + 4);
            a[ks][0] = (_Float16)u0.x; a[ks][1] = (_Float16)u0.y;
            a[ks][2] = (_Float16)u0.z; a[ks][3] = (_Float16)u0.w;
            a[ks][4] = (_Float16)u1.x; a[ks][5] = (_Float16)u1.y;
            a[ks][6] = (_Float16)u1.z; a[ks][7] = (_Float16)u1.w;
        }

        f32x4 acc[4];
        #pragma unroll
        for (int i = 0; i < 4; ++i) acc[i] = (f32x4){0.f, 0.f, 0.f, 0.f};
        f32x4 acc16 = (f32x4){0.f, 0.f, 0.f, 0.f};

        #pragma unroll
        for (int i = 0; i < 4; ++i) {
            #pragma unroll
            for (int ks = 0; ks < 4; ++ks)
                acc[i] = __builtin_amdgcn_mfma_f32_16x16x32_f16(
                    a[ks], b[i][ks], acc[i], 0, 0, 0);
        }
        if (w == 3) {
            #pragma unroll
            for (int ks = 0; ks < 4; ++ks)
                acc16 = __builtin_amdgcn_mfma_f32_16x16x32_f16(
                    a[ks], b16[ks], acc16, 0, 0, 0);
        }

        #pragma unroll
        for (int r = 0; r < 4; ++r) {
            const int n = g0 + kb * 4 + r;
            if (t0 < 8) {
                #pragma unroll
                for (int i = 0; i < 4; ++i)
                    projA[(size_t)n * HF + (t0 + i) * FO + lr] =
                        __float2half_rn(acc[i][r]);
            } else {
                #pragma unroll
                for (int i = 0; i < 4; ++i) {
                    const int o = (t0 + i - 8) * 16 + lr;
                    out[(size_t)n * HF + o] = acc[i][r] + bias[o];
                }
            }
            if (w == 3) {
                if (lr < 8) ssrc[n * 8 + lr] = acc16[r];
                else        strg_s[n * 8 + (lr - 8)] = acc16[r];
            }
        }
    }

    // ---- fill stage B: pos-gather + packed scatter-writes ----
    if (doFill) {
        int  tv[4] = {t4.x, t4.y, t4.z, t4.w};
        int  sv[4] = {s4.x, s4.y, s4.z, s4.w};
        int  rv[4] = {r4.x, r4.y, r4.z, r4.w};
        float pv[4] = {p4.x, p4.y, p4.z, p4.w};
        int slot[4];
        #pragma unroll
        for (int i = 0; i < 4; ++i) slot[i] = pos[tv[i]] + rv[i];
        #pragma unroll
        for (int i = 0; i < 4; ++i) {
            spk[slot[i]] = (unsigned int)sv[i] |
                ((unsigned int)__half_as_ushort(__float2half_rn(pv[i])) << 16);
        }
    }
}

// ---------------------------------------------------------------------------
// Fused gather with SCALARIZED edge walk (R20 winner): one wave per node.
// n, jb, je and every spk[j] are wave-uniform — readfirstlane forces them
// into SGPRs so the edge stream moves to the scalar pipe, leaving the VALU
// only the per-lane work. Lanes = 8 heads x 8 feature-pairs.
// ---------------------------------------------------------------------------
__global__ __launch_bounds__(256) void k_gather(
    const unsigned int* __restrict__ spk, const int* __restrict__ pos,
    const float* __restrict__ ssrc, const float* __restrict__ strg_s,
    const float* __restrict__ ctp,
    const __half2* __restrict__ projA, float* __restrict__ out, int E)
{
    const int lane = threadIdx.x & 63;
    const int h    = lane >> 3;                // head 0..7
    const int f2   = lane & 7;                 // feature pair 0..7

    // wave-uniform node id, forced scalar
    const int n = __builtin_amdgcn_readfirstlane(
        blockIdx.x * 4 + (threadIdx.x >> 6));  // 12500*4 = 50000 exactly

    const int jb = __builtin_amdgcn_readfirstlane(pos[n]);
    const int je = __builtin_amdgcn_readfirstlane((n + 1 < Nn) ? pos[n + 1] : E);

    const float st  = strg_s[n * 8 + h];
    const float cth = ctp[h];
    const float* __restrict__ ssl = ssrc + h;            // [s*8]
    const __half2* __restrict__ pA = projA + h * 8 + f2; // [s*64]

    float num0 = 0.f, num1 = 0.f, den = 0.f;
    int j = jb;
    for (; j + 3 < je; j += 4) {               // 4 independent chains
        const unsigned int pk0 = __builtin_amdgcn_readfirstlane(spk[j]);
        const unsigned int pk1 = __builtin_amdgcn_readfirstlane(spk[j + 1]);
        const unsigned int pk2 = __builtin_amdgcn_readfirstlane(spk[j + 2]);
        const unsigned int pk3 = __builtin_amdgcn_readfirstlane(spk[j + 3]);
        const int s0 = pk0 & 0xFFFF, s1 = pk1 & 0xFFFF;
        const int s2 = pk2 & 0xFFFF, s3 = pk3 & 0xFFFF;
        const float ss0 = ssl[s0 * 8], ss1 = ssl[s1 * 8];
        const float ss2 = ssl[s2 * 8], ss3 = ssl[s3 * 8];
        const __half2 g0 = pA[s0 * 64], g1 = pA[s1 * 64];
        const __half2 g2 = pA[s2 * 64], g3 = pA[s3 * 64];
        const float p0 = __half2float(__ushort_as_half((unsigned short)(pk0 >> 16)));
        const float p1 = __half2float(__ushort_as_half((unsigned short)(pk1 >> 16)));
        const float p2 = __half2float(__ushort_as_half((unsigned short)(pk2 >> 16)));
        const float p3 = __half2float(__ushort_as_half((unsigned short)(pk3 >> 16)));
        float sc0 = ss0 + st + cth * p0;
        float sc1 = ss1 + st + cth * p1;
        float sc2 = ss2 + st + cth * p2;
        float sc3 = ss3 + st + cth * p3;
        sc0 = fmaxf(sc0, 0.2f * sc0);          // leaky_relu(0.2)
        sc1 = fmaxf(sc1, 0.2f * sc1);
        sc2 = fmaxf(sc2, 0.2f * sc2);
        sc3 = fmaxf(sc3, 0.2f * sc3);
        const float ev0 = __expf(sc0), ev1 = __expf(sc1);
        const float ev2 = __expf(sc2), ev3 = __expf(sc3);
        const float2 G0 = __half22float2(g0), G1 = __half22float2(g1);
        const float2 G2 = __half22float2(g2), G3 = __half22float2(g3);
        den  += (ev0 + ev1) + (ev2 + ev3);
        num0 += ev0 * G0.x + ev1 * G1.x + ev2 * G2.x + ev3 * G3.x;
        num1 += ev0 * G0.y + ev1 * G1.y + ev2 * G2.y + ev3 * G3.y;
    }
    for (; j < je; ++j) {
        const unsigned int pk = __builtin_amdgcn_readfirstlane(spk[j]);
        const int s = pk & 0xFFFF;
        const float p = __half2float(__ushort_as_half((unsigned short)(pk >> 16)));
        float sc = ssl[s * 8] + st + cth * p;
        sc = fmaxf(sc, 0.2f * sc);
        const float ev = __expf(sc);
        const float2 G = __half22float2(pA[s * 64]);
        den  += ev;
        num0 += ev * G.x;
        num1 += ev * G.y;
    }

    const float inv = 1.f / (den + 1e-16f);
    const int idx = n * HF + h * FO + f2 * 2;
    float2 o = *reinterpret_cast<const float2*>(&out[idx]);  // skip+bias
    float v0 = o.x + num0 * inv;
    float v1 = o.y + num1 * inv;
    v0 = v0 > 0.f ? v0 : expm1f(v0);
    v1 = v1 > 0.f ? v1 : expm1f(v1);
    *reinterpret_cast<float2*>(&out[idx]) = make_float2(v0, v1);
}

// ---------------------------------------------------------------------------
extern "C" void kernel_launch(void* const* d_in, const int* in_sizes, int n_in,
                              void* d_out, int out_size, void* d_ws, size_t ws_size,
                              hipStream_t stream)
{
    const float* x     = (const float*)d_in[0];
    const int*   ei    = (const int*)d_in[1];
    const float* prob  = (const float*)d_in[2];
    const float* Wp    = (const float*)d_in[3];
    const float* Wt    = (const float*)d_in[4];
    const float* a_src = (const float*)d_in[5];
    const float* a_trg = (const float*)d_in[6];
    const float* a_tp  = (const float*)d_in[7];
    const float* Wskip = (const float*)d_in[8];
    const float* bias  = (const float*)d_in[9];
    float* out = (float*)d_out;

    const int E = in_sizes[2];        // edge_prob element count = E
    const int* src = ei;              // edge_index row 0
    const int* trg = ei + E;          // edge_index row 1

    // Workspace layout (~27 MB); all blocks 16B-aligned by construction
    char* wsb = (char*)d_ws;
    __half* projA  = (__half*)wsb;                      // Nn*HF f16 (12.8 MB)
    float* ssrc    = (float*)(wsb + (size_t)Nn*HF*2);   // Nn*8      (1.6 MB)
    float* strg_s  = ssrc + (size_t)Nn * 8;             // Nn*8      (1.6 MB)
    float* ctp     = strg_s + (size_t)Nn * 8;           // 16 floats
    _Float16* Wh   = (_Float16*)(ctp + 16);             // 272*128   (68 KB)
    unsigned int* spk = (unsigned int*)(Wh + (size_t)NWR * FIN); // E (3.2 MB)
    int*   rank    = (int*)(spk + E);                   // E         (3.2 MB)
    int*   deg     = rank + E;                          // Nn
    int*   pos     = deg + Nn;                          // Nn
    int*   partial = pos + Nn;                          // NSCAN (pad 256)

    const int nbCount = (E + 255) / 256;                // 3125 (1 edge/thread)

    hipMemsetAsync(deg, 0, (size_t)Nn * sizeof(int), stream);
    k_pc<<<NPREP + nbCount, 256, 0, stream>>>(Wp, Wskip, a_src, a_trg, Wt,
                                              a_tp, Wh, ctp, trg, deg, rank, E);
    k_scan1<<<NSCAN, 256, 0, stream>>>(deg, partial);
    k_scan3<<<NSCAN, 256, 0, stream>>>(deg, partial, pos);
    k_fn<<<NBLK64, 256, 0, stream>>>(src, trg, prob, rank, pos, spk,
                                     x, Wh, bias, projA, out,
                                     ssrc, strg_s, E);
    k_gather<<<Nn / 4, 256, 0, stream>>>(spk, pos, ssrc, strg_s, ctp,
                                         (const __half2*)projA, out, E);
}

// Round 22
// 127.012 us; speedup vs baseline: 1.4163x; 1.0327x over previous
//
#include <hip/hip_runtime.h>
#include <hip/hip_fp16.h>
#include <math.h>

// Problem constants (from reference)
constexpr int Nn  = 50000;   // nodes
constexpr int FIN = 128;     // input features
constexpr int NH  = 8;       // heads
constexpr int FO  = 16;      // features per head
constexpr int HF  = 128;     // NH*FO
constexpr int NWR = 272;     // Wh rows: Wp(128) | Wskip(128) | Va_src(8) | Va_trg(8)
constexpr int NBLK64 = (Nn + 63) / 64;          // 782 node blocks (64 nodes ea)
constexpr int NSCAN = (Nn + 255) / 256;         // 196 scan blocks

typedef _Float16 f16x8 __attribute__((ext_vector_type(8)));
typedef float    f32x4 __attribute__((ext_vector_type(4)));

// ---------------------------------------------------------------------------
// Weight prep (must complete before k_cn's node GEMM): Wh[272][128] f16
// (rows: Wp | Wskip | Va_src | Va_trg); ctp[h] = <Wt[h,:], a_tp[h,:]> (blk 0).
// ---------------------------------------------------------------------------
__global__ __launch_bounds__(256) void k_prep(
    const float* __restrict__ Wp, const float* __restrict__ Wskip,
    const float* __restrict__ a_src, const float* __restrict__ a_trg,
    const float* __restrict__ Wt, const float* __restrict__ a_tp,
    _Float16* __restrict__ Wh, float* __restrict__ ctp)
{
    if (blockIdx.x == 0 && threadIdx.x < NH) {
        int h = threadIdx.x;
        float s = 0.f;
        #pragma unroll
        for (int f = 0; f < FO; ++f) s += Wt[h * FO + f] * a_tp[h * FO + f];
        ctp[h] = s;
    }
    const int o = blockIdx.x * 2 + (threadIdx.x >> 7);  // 0..271
    const int k = threadIdx.x & 127;
    float v;
    if (o < 128)      v = Wp[o * FIN + k];
    else if (o < 256) v = Wskip[(o - 128) * FIN + k];
    else if (o < 264) {
        const int h = o - 256;
        float s = 0.f;
        #pragma unroll
        for (int f = 0; f < FO; ++f)
            s += a_src[h * FO + f] * Wp[(h * FO + f) * FIN + k];
        v = s;
    } else {
        const int h = o - 264;
        float s = 0.f;
        #pragma unroll
        for (int f = 0; f < FO; ++f)
            s += a_trg[h * FO + f] * Wp[(h * FO + f) * FIN + k];
        v = s;
    }
    Wh[o * FIN + k] = (_Float16)v;
}

// ---------------------------------------------------------------------------
// Node GEMM with INTRA-BLOCK count overlap (count and GEMM are independent:
// count reads trg, writes deg/rank; GEMM reads x/Wh, writes projA/out/
// scores). trg loads issue BEFORE the GEMM body; the 4 independent returning
// atomics + rank int4-write run AFTER the epilogue — their ~600cy latency
// hides under the 80 MFMAs + pipelined A-loads.
// ---------------------------------------------------------------------------
__global__ __launch_bounds__(256) void k_cn(
    const int* __restrict__ trg, int* __restrict__ deg, int* __restrict__ rank,
    const float* __restrict__ x, const _Float16* __restrict__ Wh,
    const float* __restrict__ bias,
    __half* __restrict__ projA, float* __restrict__ out,
    float* __restrict__ ssrc, float* __restrict__ strg_s, int E)
{
    const int bid = blockIdx.x;

    // ---- count stage A: issue trg loads ----
    const int e4 = bid * 256 + threadIdx.x;    // edge quad index
    const bool doCnt = (e4 * 4 < E);
    int4 t4;
    if (doCnt) t4 = reinterpret_cast<const int4*>(trg)[e4];

    // ---- node GEMM ----
    const int g0 = bid * 64;
    const int w  = threadIdx.x >> 6;           // wave 0..3 (uniform per wave)
    const int l  = threadIdx.x & 63;
    const int lr = l & 15;
    const int kb = l >> 4;                     // k-block 0..3
    const int t0 = w * 4;                      // first tile of this wave

    // B fragments: loaded ONCE, reused across all node groups
    f16x8 b[4][4];
    const _Float16* wb = Wh + (size_t)lr * FIN + kb * 8;
    #pragma unroll
    for (int i = 0; i < 4; ++i) {
        #pragma unroll
        for (int ks = 0; ks < 4; ++ks)
            b[i][ks] = *reinterpret_cast<const f16x8*>(
                wb + (size_t)(t0 + i) * 16 * FIN + ks * 32);
    }
    f16x8 b16[4];
    if (w == 3) {
        #pragma unroll
        for (int ks = 0; ks < 4; ++ks)
            b16[ks] = *reinterpret_cast<const f16x8*>(
                wb + (size_t)16 * 16 * FIN + ks * 32);
    }

    const float* xr0 = x + (size_t)(g0 + lr) * FIN + kb * 8;

    if (g0 + 64 <= Nn) {
        // ---- full block: 4 groups, 2-stage pipeline ----
        float4 ucur[8];
        #pragma unroll
        for (int q = 0; q < 8; ++q)
            ucur[q] = *reinterpret_cast<const float4*>(
                xr0 + (q >> 1) * 32 + (q & 1) * 4);

        #pragma unroll
        for (int ng = 0; ng < 4; ++ng) {
            float4 unx[8];
            if (ng < 3) {
                const float* xrn = xr0 + (size_t)(ng + 1) * 16 * FIN;
                #pragma unroll
                for (int q = 0; q < 8; ++q)
                    unx[q] = *reinterpret_cast<const float4*>(
                        xrn + (q >> 1) * 32 + (q & 1) * 4);
            }

            f16x8 a[4];
            #pragma unroll
            for (int ks = 0; ks < 4; ++ks) {
                float4 lo = ucur[ks * 2], hi = ucur[ks * 2 + 1];
                a[ks][0] = (_Float16)lo.x; a[ks][1] = (_Float16)lo.y;
                a[ks][2] = (_Float16)lo.z; a[ks][3] = (_Float16)lo.w;
                a[ks][4] = (_Float16)hi.x; a[ks][5] = (_Float16)hi.y;
                a[ks][6] = (_Float16)hi.z; a[ks][7] = (_Float16)hi.w;
            }

            f32x4 acc[4];
            #pragma unroll
            for (int i = 0; i < 4; ++i) acc[i] = (f32x4){0.f, 0.f, 0.f, 0.f};
            f32x4 acc16 = (f32x4){0.f, 0.f, 0.f, 0.f};

            #pragma unroll
            for (int i = 0; i < 4; ++i) {
                #pragma unroll
                for (int ks = 0; ks < 4; ++ks)
                    acc[i] = __builtin_amdgcn_mfma_f32_16x16x32_f16(
                        a[ks], b[i][ks], acc[i], 0, 0, 0);
            }
            if (w == 3) {
                #pragma unroll
                for (int ks = 0; ks < 4; ++ks)
                    acc16 = __builtin_amdgcn_mfma_f32_16x16x32_f16(
                        a[ks], b16[ks], acc16, 0, 0, 0);
            }

            const int n0 = g0 + ng * 16;
            #pragma unroll
            for (int r = 0; r < 4; ++r) {
                const int n = n0 + kb * 4 + r;
                if (t0 < 8) {
                    #pragma unroll
                    for (int i = 0; i < 4; ++i)
                        projA[(size_t)n * HF + (t0 + i) * FO + lr] =
                            __float2half_rn(acc[i][r]);
                } else {
                    #pragma unroll
                    for (int i = 0; i < 4; ++i) {
                        const int o = (t0 + i - 8) * 16 + lr;
                        out[(size_t)n * HF + o] = acc[i][r] + bias[o];
                    }
                }
                if (w == 3) {
                    if (lr < 8) ssrc[n * 8 + lr] = acc16[r];
                    else        strg_s[n * 8 + (lr - 8)] = acc16[r];
                }
            }

            #pragma unroll
            for (int q = 0; q < 8; ++q) ucur[q] = unx[q];
        }
    } else {
        // ---- partial last block (one 16-node group at 49984) ----
        f16x8 a[4];
        #pragma unroll
        for (int ks = 0; ks < 4; ++ks) {
            float4 u0 = *reinterpret_cast<const float4*>(xr0 + ks * 32);
            float4 u1 = *reinterpret_cast<const float4*>(xr0 + ks * 32 + 4);
            a[ks][0] = (_Float16)u0.x; a[ks][1] = (_Float16)u0.y;
            a[ks][2] = (_Float16)u0.z; a[ks][3] = (_Float16)u0.w;
            a[ks][4] = (_Float16)u1.x; a[ks][5] = (_Float16)u1.y;
            a[ks][6] = (_Float16)u1.z; a[ks][7] = (_Float16)u1.w;
        }

        f32x4 acc[4];
        #pragma unroll
        for (int i = 0; i < 4; ++i) acc[i] = (f32x4){0.f, 0.f, 0.f, 0.f};
        f32x4 acc16 = (f32x4){0.f, 0.f, 0.f, 0.f};

        #pragma unroll
        for (int i = 0; i < 4; ++i) {
            #pragma unroll
            for (int ks = 0; ks < 4; ++ks)
                acc[i] = __builtin_amdgcn_mfma_f32_16x16x32_f16(
                    a[ks], b[i][ks], acc[i], 0, 0, 0);
        }
        if (w == 3) {
            #pragma unroll
            for (int ks = 0; ks < 4; ++ks)
                acc16 = __builtin_amdgcn_mfma_f32_16x16x32_f16(
                    a[ks], b16[ks], acc16, 0, 0, 0);
        }

        #pragma unroll
        for (int r = 0; r < 4; ++r) {
            const int n = g0 + kb * 4 + r;
            if (t0 < 8) {
                #pragma unroll
                for (int i = 0; i < 4; ++i)
                    projA[(size_t)n * HF + (t0 + i) * FO + lr] =
                        __float2half_rn(acc[i][r]);
            } else {
                #pragma unroll
                for (int i = 0; i < 4; ++i) {
                    const int o = (t0 + i - 8) * 16 + lr;
                    out[(size_t)n * HF + o] = acc[i][r] + bias[o];
                }
            }
            if (w == 3) {
                if (lr < 8) ssrc[n * 8 + lr] = acc16[r];
                else        strg_s[n * 8 + (lr - 8)] = acc16[r];
            }
        }
    }

    // ---- count stage B: 4 independent returning atomics + rank write ----
    if (doCnt) {
        int4 r;
        r.x = atomicAdd(&deg[t4.x], 1);
        r.y = atomicAdd(&deg[t4.y], 1);
        r.z = atomicAdd(&deg[t4.z], 1);
        r.w = atomicAdd(&deg[t4.w], 1);
        reinterpret_cast<int4*>(rank)[e4] = r;
    }
}

// ---------------------------------------------------------------------------
// Scan pair. pos stays EXCLUSIVE; row n spans [pos[n], n+1<Nn?pos[n+1]:E).
// ---------------------------------------------------------------------------
__global__ __launch_bounds__(256) void k_scan1(const int* __restrict__ deg,
                                               int* __restrict__ partial)
{
    __shared__ int lds[256];
    int t = threadIdx.x, i = blockIdx.x * 256 + t;
    lds[t] = (i < Nn) ? deg[i] : 0;
    __syncthreads();
    for (int off = 128; off > 0; off >>= 1) {
        if (t < off) lds[t] += lds[t + off];
        __syncthreads();
    }
    if (t == 0) partial[blockIdx.x] = lds[0];
}

__global__ __launch_bounds__(256) void k_scan3(const int* __restrict__ deg,
                                               const int* __restrict__ partial,
                                               int* __restrict__ pos)
{
    __shared__ int lds[256], lds2[256];
    const int t = threadIdx.x;
    const int i = blockIdx.x * 256 + t;
    lds2[t] = (t < NSCAN) ? partial[t] : 0;
    __syncthreads();
    for (int off = 1; off < 256; off <<= 1) {
        int u = (t >= off) ? lds2[t - off] : 0;
        __syncthreads();
        lds2[t] += u;
        __syncthreads();
    }
    const int base = (blockIdx.x == 0) ? 0 : lds2[blockIdx.x - 1];
    int v = (i < Nn) ? deg[i] : 0;
    lds[t] = v;
    __syncthreads();
    for (int off = 1; off < 256; off <<= 1) {
        int u = (t >= off) ? lds[t - off] : 0;
        __syncthreads();
        lds[t] += u;
        __syncthreads();
    }
    if (i < Nn) pos[i] = base + lds[t] - v;
}

// ---------------------------------------------------------------------------
// Fill (atomic-free): slot = pos[trg] + rank; spk = src(16b)|f16(prob)(16b).
// 4 edges/thread, 782 blocks.
// ---------------------------------------------------------------------------
__global__ __launch_bounds__(256) void k_fill(
    const int* __restrict__ src, const int* __restrict__ trg,
    const float* __restrict__ prob, const int* __restrict__ rank,
    const int* __restrict__ pos, unsigned int* __restrict__ spk, int E)
{
    int e4 = blockIdx.x * 256 + threadIdx.x;
    if (e4 * 4 >= E) return;
    int4   s4 = reinterpret_cast<const int4*>(src)[e4];
    int4   t4 = reinterpret_cast<const int4*>(trg)[e4];
    float4 p4 = reinterpret_cast<const float4*>(prob)[e4];
    int4   r4 = reinterpret_cast<const int4*>(rank)[e4];
    int    sv[4] = {s4.x, s4.y, s4.z, s4.w};
    int    tv[4] = {t4.x, t4.y, t4.z, t4.w};
    int    rv[4] = {r4.x, r4.y, r4.z, r4.w};
    float  pv[4] = {p4.x, p4.y, p4.z, p4.w};
    #pragma unroll
    for (int i = 0; i < 4; ++i) {
        int slot = pos[tv[i]] + rv[i];
        spk[slot] = (unsigned int)sv[i] |
            ((unsigned int)__half_as_ushort(__float2half_rn(pv[i])) << 16);
    }
}

// ---------------------------------------------------------------------------
// Fused gather with SCALARIZED edge walk (R20 winner): one wave per node.
// n, jb, je and every spk[j] are wave-uniform — readfirstlane forces them
// into SGPRs so the edge stream moves to the scalar pipe, leaving the VALU
// only the per-lane work. Lanes = 8 heads x 8 feature-pairs.
// ---------------------------------------------------------------------------
__global__ __launch_bounds__(256) void k_gather(
    const unsigned int* __restrict__ spk, const int* __restrict__ pos,
    const float* __restrict__ ssrc, const float* __restrict__ strg_s,
    const float* __restrict__ ctp,
    const __half2* __restrict__ projA, float* __restrict__ out, int E)
{
    const int lane = threadIdx.x & 63;
    const int h    = lane >> 3;                // head 0..7
    const int f2   = lane & 7;                 // feature pair 0..7

    // wave-uniform node id, forced scalar
    const int n = __builtin_amdgcn_readfirstlane(
        blockIdx.x * 4 + (threadIdx.x >> 6));  // 12500*4 = 50000 exactly

    const int jb = __builtin_amdgcn_readfirstlane(pos[n]);
    const int je = __builtin_amdgcn_readfirstlane((n + 1 < Nn) ? pos[n + 1] : E);

    const float st  = strg_s[n * 8 + h];
    const float cth = ctp[h];
    const float* __restrict__ ssl = ssrc + h;            // [s*8]
    const __half2* __restrict__ pA = projA + h * 8 + f2; // [s*64]

    float num0 = 0.f, num1 = 0.f, den = 0.f;
    int j = jb;
    for (; j + 3 < je; j += 4) {               // 4 independent chains
        const unsigned int pk0 = __builtin_amdgcn_readfirstlane(spk[j]);
        const unsigned int pk1 = __builtin_amdgcn_readfirstlane(spk[j + 1]);
        const unsigned int pk2 = __builtin_amdgcn_readfirstlane(spk[j + 2]);
        const unsigned int pk3 = __builtin_amdgcn_readfirstlane(spk[j + 3]);
        const int s0 = pk0 & 0xFFFF, s1 = pk1 & 0xFFFF;
        const int s2 = pk2 & 0xFFFF, s3 = pk3 & 0xFFFF;
        const float ss0 = ssl[s0 * 8], ss1 = ssl[s1 * 8];
        const float ss2 = ssl[s2 * 8], ss3 = ssl[s3 * 8];
        const __half2 g0 = pA[s0 * 64], g1 = pA[s1 * 64];
        const __half2 g2 = pA[s2 * 64], g3 = pA[s3 * 64];
        const float p0 = __half2float(__ushort_as_half((unsigned short)(pk0 >> 16)));
        const float p1 = __half2float(__ushort_as_half((unsigned short)(pk1 >> 16)));
        const float p2 = __half2float(__ushort_as_half((unsigned short)(pk2 >> 16)));
        const float p3 = __half2float(__ushort_as_half((unsigned short)(pk3 >> 16)));
        float sc0 = ss0 + st + cth * p0;
        float sc1 = ss1 + st + cth * p1;
        float sc2 = ss2 + st + cth * p2;
        float sc3 = ss3 + st + cth * p3;
        sc0 = fmaxf(sc0, 0.2f * sc0);          // leaky_relu(0.2)
        sc1 = fmaxf(sc1, 0.2f * sc1);
        sc2 = fmaxf(sc2, 0.2f * sc2);
        sc3 = fmaxf(sc3, 0.2f * sc3);
        const float ev0 = __expf(sc0), ev1 = __expf(sc1);
        const float ev2 = __expf(sc2), ev3 = __expf(sc3);
        const float2 G0 = __half22float2(g0), G1 = __half22float2(g1);
        const float2 G2 = __half22float2(g2), G3 = __half22float2(g3);
        den  += (ev0 + ev1) + (ev2 + ev3);
        num0 += ev0 * G0.x + ev1 * G1.x + ev2 * G2.x + ev3 * G3.x;
        num1 += ev0 * G0.y + ev1 * G1.y + ev2 * G2.y + ev3 * G3.y;
    }
    for (; j < je; ++j) {
        const unsigned int pk = __builtin_amdgcn_readfirstlane(spk[j]);
        const int s = pk & 0xFFFF;
        const float p = __half2float(__ushort_as_half((unsigned short)(pk >> 16)));
        float sc = ssl[s * 8] + st + cth * p;
        sc = fmaxf(sc, 0.2f * sc);
        const float ev = __expf(sc);
        const float2 G = __half22float2(pA[s * 64]);
        den  += ev;
        num0 += ev * G.x;
        num1 += ev * G.y;
    }

    const float inv = 1.f / (den + 1e-16f);
    const int idx = n * HF + h * FO + f2 * 2;
    float2 o = *reinterpret_cast<const float2*>(&out[idx]);  // skip+bias
    float v0 = o.x + num0 * inv;
    float v1 = o.y + num1 * inv;
    v0 = v0 > 0.f ? v0 : expm1f(v0);
    v1 = v1 > 0.f ? v1 : expm1f(v1);
    *reinterpret_cast<float2*>(&out[idx]) = make_float2(v0, v1);
}

// ---------------------------------------------------------------------------
extern "C" void kernel_launch(void* const* d_in, const int* in_sizes, int n_in,
                              void* d_out, int out_size, void* d_ws, size_t ws_size,
                              hipStream_t stream)
{
    const float* x     = (const float*)d_in[0];
    const int*   ei    = (const int*)d_in[1];
    const float* prob  = (const float*)d_in[2];
    const float* Wp    = (const float*)d_in[3];
    const float* Wt    = (const float*)d_in[4];
    const float* a_src = (const float*)d_in[5];
    const float* a_trg = (const float*)d_in[6];
    const float* a_tp  = (const float*)d_in[7];
    const float* Wskip = (const float*)d_in[8];
    const float* bias  = (const float*)d_in[9];
    float* out = (float*)d_out;

    const int E = in_sizes[2];        // edge_prob element count = E
    const int* src = ei;              // edge_index row 0
    const int* trg = ei + E;          // edge_index row 1

    // Workspace layout (~27 MB); all blocks 16B-aligned by construction
    char* wsb = (char*)d_ws;
    __half* projA  = (__half*)wsb;                      // Nn*HF f16 (12.8 MB)
    float* ssrc    = (float*)(wsb + (size_t)Nn*HF*2);   // Nn*8      (1.6 MB)
    float* strg_s  = ssrc + (size_t)Nn * 8;             // Nn*8      (1.6 MB)
    float* ctp     = strg_s + (size_t)Nn * 8;           // 16 floats
    _Float16* Wh   = (_Float16*)(ctp + 16);             // 272*128   (68 KB)
    unsigned int* spk = (unsigned int*)(Wh + (size_t)NWR * FIN); // E (3.2 MB)
    int*   rank    = (int*)(spk + E);                   // E         (3.2 MB)
    int*   deg     = rank + E;                          // Nn
    int*   pos     = deg + Nn;                          // Nn
    int*   partial = pos + Nn;                          // NSCAN (pad 256)

    hipMemsetAsync(deg, 0, (size_t)Nn * sizeof(int), stream);
    k_prep<<<NWR / 2, 256, 0, stream>>>(Wp, Wskip, a_src, a_trg, Wt, a_tp,
                                        Wh, ctp);
    k_cn<<<NBLK64, 256, 0, stream>>>(trg, deg, rank, x, Wh, bias,
                                     projA, out, ssrc, strg_s, E);
    k_scan1<<<NSCAN, 256, 0, stream>>>(deg, partial);
    k_scan3<<<NSCAN, 256, 0, stream>>>(deg, partial, pos);
    k_fill<<<NBLK64, 256, 0, stream>>>(src, trg, prob, rank, pos, spk, E);
    k_gather<<<Nn / 4, 256, 0, stream>>>(spk, pos, ssrc, strg_s, ctp,
                                         (const __half2*)projA, out, E);
}

// Round 23
// 122.888 us; speedup vs baseline: 1.4638x; 1.0336x over previous
//
#include <hip/hip_runtime.h>
#include <hip/hip_fp16.h>
#include <math.h>

// Problem constants (from reference)
constexpr int Nn  = 50000;   // nodes
constexpr int FIN = 128;     // input features
constexpr int NH  = 8;       // heads
constexpr int FO  = 16;      // features per head
constexpr int HF  = 128;     // NH*FO
constexpr int NWR = 272;     // Wh rows: Wp(128) | Wskip(128) | Va_src(8) | Va_trg(8)
constexpr int NBLK64 = (Nn + 63) / 64;          // 782 node blocks (64 nodes ea)
constexpr int NSCAN = (Nn + 255) / 256;         // 196 scan blocks

typedef _Float16 f16x8 __attribute__((ext_vector_type(8)));
typedef float    f32x4 __attribute__((ext_vector_type(4)));

// ---------------------------------------------------------------------------
// Weight prep (must complete before k_cn's node GEMM): Wh[272][128] f16
// (rows: Wp | Wskip | Va_src | Va_trg); ctp[h] = <Wt[h,:], a_tp[h,:]> (blk 0).
// ---------------------------------------------------------------------------
__global__ __launch_bounds__(256) void k_prep(
    const float* __restrict__ Wp, const float* __restrict__ Wskip,
    const float* __restrict__ a_src, const float* __restrict__ a_trg,
    const float* __restrict__ Wt, const float* __restrict__ a_tp,
    _Float16* __restrict__ Wh, float* __restrict__ ctp)
{
    if (blockIdx.x == 0 && threadIdx.x < NH) {
        int h = threadIdx.x;
        float s = 0.f;
        #pragma unroll
        for (int f = 0; f < FO; ++f) s += Wt[h * FO + f] * a_tp[h * FO + f];
        ctp[h] = s;
    }
    const int o = blockIdx.x * 2 + (threadIdx.x >> 7);  // 0..271
    const int k = threadIdx.x & 127;
    float v;
    if (o < 128)      v = Wp[o * FIN + k];
    else if (o < 256) v = Wskip[(o - 128) * FIN + k];
    else if (o < 264) {
        const int h = o - 256;
        float s = 0.f;
        #pragma unroll
        for (int f = 0; f < FO; ++f)
            s += a_src[h * FO + f] * Wp[(h * FO + f) * FIN + k];
        v = s;
    } else {
        const int h = o - 264;
        float s = 0.f;
        #pragma unroll
        for (int f = 0; f < FO; ++f)
            s += a_trg[h * FO + f] * Wp[(h * FO + f) * FIN + k];
        v = s;
    }
    Wh[o * FIN + k] = (_Float16)v;
}

// ---------------------------------------------------------------------------
// Node GEMM with intra-block count overlap. Outputs are all f16 now:
//   projA[n][h][f]   f16 (12.8 MB)
//   skipA[n][o]      f16 = skip + bias (12.8 MB)  [gather adds attn, writes out]
//   ssh/sth[n][h]    f16 score arrays (0.8 MB each)
// count: trg loads issue first; returning atomics + rank write after epilogue.
// ---------------------------------------------------------------------------
__global__ __launch_bounds__(256) void k_cn(
    const int* __restrict__ trg, int* __restrict__ deg, int* __restrict__ rank,
    const float* __restrict__ x, const _Float16* __restrict__ Wh,
    const float* __restrict__ bias,
    __half* __restrict__ projA, __half* __restrict__ skipA,
    __half* __restrict__ ssh, __half* __restrict__ sth, int E)
{
    const int bid = blockIdx.x;

    // ---- count stage A: issue trg loads ----
    const int e4 = bid * 256 + threadIdx.x;    // edge quad index
    const bool doCnt = (e4 * 4 < E);
    int4 t4;
    if (doCnt) t4 = reinterpret_cast<const int4*>(trg)[e4];

    // ---- node GEMM ----
    const int g0 = bid * 64;
    const int w  = threadIdx.x >> 6;           // wave 0..3 (uniform per wave)
    const int l  = threadIdx.x & 63;
    const int lr = l & 15;
    const int kb = l >> 4;                     // k-block 0..3
    const int t0 = w * 4;                      // first tile of this wave

    // B fragments: loaded ONCE, reused across all node groups
    f16x8 b[4][4];
    const _Float16* wb = Wh + (size_t)lr * FIN + kb * 8;
    #pragma unroll
    for (int i = 0; i < 4; ++i) {
        #pragma unroll
        for (int ks = 0; ks < 4; ++ks)
            b[i][ks] = *reinterpret_cast<const f16x8*>(
                wb + (size_t)(t0 + i) * 16 * FIN + ks * 32);
    }
    f16x8 b16[4];
    if (w == 3) {
        #pragma unroll
        for (int ks = 0; ks < 4; ++ks)
            b16[ks] = *reinterpret_cast<const f16x8*>(
                wb + (size_t)16 * 16 * FIN + ks * 32);
    }

    const float* xr0 = x + (size_t)(g0 + lr) * FIN + kb * 8;

    if (g0 + 64 <= Nn) {
        // ---- full block: 4 groups, 2-stage pipeline ----
        float4 ucur[8];
        #pragma unroll
        for (int q = 0; q < 8; ++q)
            ucur[q] = *reinterpret_cast<const float4*>(
                xr0 + (q >> 1) * 32 + (q & 1) * 4);

        #pragma unroll
        for (int ng = 0; ng < 4; ++ng) {
            float4 unx[8];
            if (ng < 3) {
                const float* xrn = xr0 + (size_t)(ng + 1) * 16 * FIN;
                #pragma unroll
                for (int q = 0; q < 8; ++q)
                    unx[q] = *reinterpret_cast<const float4*>(
                        xrn + (q >> 1) * 32 + (q & 1) * 4);
            }

            f16x8 a[4];
            #pragma unroll
            for (int ks = 0; ks < 4; ++ks) {
                float4 lo = ucur[ks * 2], hi = ucur[ks * 2 + 1];
                a[ks][0] = (_Float16)lo.x; a[ks][1] = (_Float16)lo.y;
                a[ks][2] = (_Float16)lo.z; a[ks][3] = (_Float16)lo.w;
                a[ks][4] = (_Float16)hi.x; a[ks][5] = (_Float16)hi.y;
                a[ks][6] = (_Float16)hi.z; a[ks][7] = (_Float16)hi.w;
            }

            f32x4 acc[4];
            #pragma unroll
            for (int i = 0; i < 4; ++i) acc[i] = (f32x4){0.f, 0.f, 0.f, 0.f};
            f32x4 acc16 = (f32x4){0.f, 0.f, 0.f, 0.f};

            #pragma unroll
            for (int i = 0; i < 4; ++i) {
                #pragma unroll
                for (int ks = 0; ks < 4; ++ks)
                    acc[i] = __builtin_amdgcn_mfma_f32_16x16x32_f16(
                        a[ks], b[i][ks], acc[i], 0, 0, 0);
            }
            if (w == 3) {
                #pragma unroll
                for (int ks = 0; ks < 4; ++ks)
                    acc16 = __builtin_amdgcn_mfma_f32_16x16x32_f16(
                        a[ks], b16[ks], acc16, 0, 0, 0);
            }

            const int n0 = g0 + ng * 16;
            #pragma unroll
            for (int r = 0; r < 4; ++r) {
                const int n = n0 + kb * 4 + r;
                if (t0 < 8) {
                    #pragma unroll
                    for (int i = 0; i < 4; ++i)
                        projA[(size_t)n * HF + (t0 + i) * FO + lr] =
                            __float2half_rn(acc[i][r]);
                } else {
                    #pragma unroll
                    for (int i = 0; i < 4; ++i) {
                        const int o = (t0 + i - 8) * 16 + lr;
                        skipA[(size_t)n * HF + o] =
                            __float2half_rn(acc[i][r] + bias[o]);
                    }
                }
                if (w == 3) {
                    if (lr < 8) ssh[n * 8 + lr] = __float2half_rn(acc16[r]);
                    else        sth[n * 8 + (lr - 8)] = __float2half_rn(acc16[r]);
                }
            }

            #pragma unroll
            for (int q = 0; q < 8; ++q) ucur[q] = unx[q];
        }
    } else {
        // ---- partial last block (one 16-node group at 49984) ----
        f16x8 a[4];
        #pragma unroll
        for (int ks = 0; ks < 4; ++ks) {
            float4 u0 = *reinterpret_cast<const float4*>(xr0 + ks * 32);
            float4 u1 = *reinterpret_cast<const float4*>(xr0 + ks * 32 + 4);
            a[ks][0] = (_Float16)u0.x; a[ks][1] = (_Float16)u0.y;
            a[ks][2] = (_Float16)u0.z; a[ks][3] = (_Float16)u0.w;
            a[ks][4] = (_Float16)u1.x; a[ks][5] = (_Float16)u1.y;
            a[ks][6] = (_Float16)u1.z; a[ks][7] = (_Float16)u1.w;
        }

        f32x4 acc[4];
        #pragma unroll
        for (int i = 0; i < 4; ++i) acc[i] = (f32x4){0.f, 0.f, 0.f, 0.f};
        f32x4 acc16 = (f32x4){0.f, 0.f, 0.f, 0.f};

        #pragma unroll
        for (int i = 0; i < 4; ++i) {
            #pragma unroll
            for (int ks = 0; ks < 4; ++ks)
                acc[i] = __builtin_amdgcn_mfma_f32_16x16x32_f16(
                    a[ks], b[i][ks], acc[i], 0, 0, 0);
        }
        if (w == 3) {
            #pragma unroll
            for (int ks = 0; ks < 4; ++ks)
                acc16 = __builtin_amdgcn_mfma_f32_16x16x32_f16(
                    a[ks], b16[ks], acc16, 0, 0, 0);
        }

        #pragma unroll
        for (int r = 0; r < 4; ++r) {
            const int n = g0 + kb * 4 + r;
            if (t0 < 8) {
                #pragma unroll
                for (int i = 0; i < 4; ++i)
                    projA[(size_t)n * HF + (t0 + i) * FO + lr] =
                        __float2half_rn(acc[i][r]);
            } else {
                #pragma unroll
                for (int i = 0; i < 4; ++i) {
                    const int o = (t0 + i - 8) * 16 + lr;
                    skipA[(size_t)n * HF + o] =
                        __float2half_rn(acc[i][r] + bias[o]);
                }
            }
            if (w == 3) {
                if (lr < 8) ssh[n * 8 + lr] = __float2half_rn(acc16[r]);
                else        sth[n * 8 + (lr - 8)] = __float2half_rn(acc16[r]);
            }
        }
    }

    // ---- count stage B: 4 independent returning atomics + rank write ----
    if (doCnt) {
        int4 r;
        r.x = atomicAdd(&deg[t4.x], 1);
        r.y = atomicAdd(&deg[t4.y], 1);
        r.z = atomicAdd(&deg[t4.z], 1);
        r.w = atomicAdd(&deg[t4.w], 1);
        reinterpret_cast<int4*>(rank)[e4] = r;
    }
}

// ---------------------------------------------------------------------------
// Scan pair. pos stays EXCLUSIVE; row n spans [pos[n], n+1<Nn?pos[n+1]:E).
// ---------------------------------------------------------------------------
__global__ __launch_bounds__(256) void k_scan1(const int* __restrict__ deg,
                                               int* __restrict__ partial)
{
    __shared__ int lds[256];
    int t = threadIdx.x, i = blockIdx.x * 256 + t;
    lds[t] = (i < Nn) ? deg[i] : 0;
    __syncthreads();
    for (int off = 128; off > 0; off >>= 1) {
        if (t < off) lds[t] += lds[t + off];
        __syncthreads();
    }
    if (t == 0) partial[blockIdx.x] = lds[0];
}

__global__ __launch_bounds__(256) void k_scan3(const int* __restrict__ deg,
                                               const int* __restrict__ partial,
                                               int* __restrict__ pos)
{
    __shared__ int lds[256], lds2[256];
    const int t = threadIdx.x;
    const int i = blockIdx.x * 256 + t;
    lds2[t] = (t < NSCAN) ? partial[t] : 0;
    __syncthreads();
    for (int off = 1; off < 256; off <<= 1) {
        int u = (t >= off) ? lds2[t - off] : 0;
        __syncthreads();
        lds2[t] += u;
        __syncthreads();
    }
    const int base = (blockIdx.x == 0) ? 0 : lds2[blockIdx.x - 1];
    int v = (i < Nn) ? deg[i] : 0;
    lds[t] = v;
    __syncthreads();
    for (int off = 1; off < 256; off <<= 1) {
        int u = (t >= off) ? lds[t - off] : 0;
        __syncthreads();
        lds[t] += u;
        __syncthreads();
    }
    if (i < Nn) pos[i] = base + lds[t] - v;
}

// ---------------------------------------------------------------------------
// Fill (atomic-free): slot = pos[trg] + rank; spk = src(16b)|f16(prob)(16b).
// ---------------------------------------------------------------------------
__global__ __launch_bounds__(256) void k_fill(
    const int* __restrict__ src, const int* __restrict__ trg,
    const float* __restrict__ prob, const int* __restrict__ rank,
    const int* __restrict__ pos, unsigned int* __restrict__ spk, int E)
{
    int e4 = blockIdx.x * 256 + threadIdx.x;
    if (e4 * 4 >= E) return;
    int4   s4 = reinterpret_cast<const int4*>(src)[e4];
    int4   t4 = reinterpret_cast<const int4*>(trg)[e4];
    float4 p4 = reinterpret_cast<const float4*>(prob)[e4];
    int4   r4 = reinterpret_cast<const int4*>(rank)[e4];
    int    sv[4] = {s4.x, s4.y, s4.z, s4.w};
    int    tv[4] = {t4.x, t4.y, t4.z, t4.w};
    int    rv[4] = {r4.x, r4.y, r4.z, r4.w};
    float  pv[4] = {p4.x, p4.y, p4.z, p4.w};
    #pragma unroll
    for (int i = 0; i < 4; ++i) {
        int slot = pos[tv[i]] + rv[i];
        spk[slot] = (unsigned int)sv[i] |
            ((unsigned int)__half_as_ushort(__float2half_rn(pv[i])) << 16);
    }
}

// ---------------------------------------------------------------------------
// Fused gather with scalarized edge walk: one wave per node; lanes = 8 heads
// x 8 feature-pairs. spk stream via readfirstlane (scalar pipe); per-edge
// vector work = f16 score gather + 256B projA wave-read + exp + 2 FMA.
// Epilogue reads f16 skipA and writes f32 out exactly once (no RMW).
// ---------------------------------------------------------------------------
__global__ __launch_bounds__(256) void k_gather(
    const unsigned int* __restrict__ spk, const int* __restrict__ pos,
    const __half* __restrict__ ssh, const __half* __restrict__ sth,
    const float* __restrict__ ctp, const __half* __restrict__ skipA,
    const __half2* __restrict__ projA, float* __restrict__ out, int E)
{
    const int lane = threadIdx.x & 63;
    const int h    = lane >> 3;                // head 0..7
    const int f2   = lane & 7;                 // feature pair 0..7

    // wave-uniform node id, forced scalar
    const int n = __builtin_amdgcn_readfirstlane(
        blockIdx.x * 4 + (threadIdx.x >> 6));  // 12500*4 = 50000 exactly

    const int jb = __builtin_amdgcn_readfirstlane(pos[n]);
    const int je = __builtin_amdgcn_readfirstlane((n + 1 < Nn) ? pos[n + 1] : E);

    const float st  = __half2float(sth[n * 8 + h]);
    const float cth = ctp[h];
    const __half* __restrict__ ssl = ssh + h;            // [s*8]
    const __half2* __restrict__ pA = projA + h * 8 + f2; // [s*64]

    float num0 = 0.f, num1 = 0.f, den = 0.f;
    int j = jb;
    for (; j + 3 < je; j += 4) {               // 4 independent chains
        const unsigned int pk0 = __builtin_amdgcn_readfirstlane(spk[j]);
        const unsigned int pk1 = __builtin_amdgcn_readfirstlane(spk[j + 1]);
        const unsigned int pk2 = __builtin_amdgcn_readfirstlane(spk[j + 2]);
        const unsigned int pk3 = __builtin_amdgcn_readfirstlane(spk[j + 3]);
        const int s0 = pk0 & 0xFFFF, s1 = pk1 & 0xFFFF;
        const int s2 = pk2 & 0xFFFF, s3 = pk3 & 0xFFFF;
        const float ss0 = __half2float(ssl[s0 * 8]);
        const float ss1 = __half2float(ssl[s1 * 8]);
        const float ss2 = __half2float(ssl[s2 * 8]);
        const float ss3 = __half2float(ssl[s3 * 8]);
        const __half2 g0 = pA[s0 * 64], g1 = pA[s1 * 64];
        const __half2 g2 = pA[s2 * 64], g3 = pA[s3 * 64];
        const float p0 = __half2float(__ushort_as_half((unsigned short)(pk0 >> 16)));
        const float p1 = __half2float(__ushort_as_half((unsigned short)(pk1 >> 16)));
        const float p2 = __half2float(__ushort_as_half((unsigned short)(pk2 >> 16)));
        const float p3 = __half2float(__ushort_as_half((unsigned short)(pk3 >> 16)));
        float sc0 = ss0 + st + cth * p0;
        float sc1 = ss1 + st + cth * p1;
        float sc2 = ss2 + st + cth * p2;
        float sc3 = ss3 + st + cth * p3;
        sc0 = fmaxf(sc0, 0.2f * sc0);          // leaky_relu(0.2)
        sc1 = fmaxf(sc1, 0.2f * sc1);
        sc2 = fmaxf(sc2, 0.2f * sc2);
        sc3 = fmaxf(sc3, 0.2f * sc3);
        const float ev0 = __expf(sc0), ev1 = __expf(sc1);
        const float ev2 = __expf(sc2), ev3 = __expf(sc3);
        const float2 G0 = __half22float2(g0), G1 = __half22float2(g1);
        const float2 G2 = __half22float2(g2), G3 = __half22float2(g3);
        den  += (ev0 + ev1) + (ev2 + ev3);
        num0 += ev0 * G0.x + ev1 * G1.x + ev2 * G2.x + ev3 * G3.x;
        num1 += ev0 * G0.y + ev1 * G1.y + ev2 * G2.y + ev3 * G3.y;
    }
    for (; j < je; ++j) {
        const unsigned int pk = __builtin_amdgcn_readfirstlane(spk[j]);
        const int s = pk & 0xFFFF;
        const float p = __half2float(__ushort_as_half((unsigned short)(pk >> 16)));
        float sc = __half2float(ssl[s * 8]) + st + cth * p;
        sc = fmaxf(sc, 0.2f * sc);
        const float ev = __expf(sc);
        const float2 G = __half22float2(pA[s * 64]);
        den  += ev;
        num0 += ev * G.x;
        num1 += ev * G.y;
    }

    const float inv = 1.f / (den + 1e-16f);
    const int idx = n * HF + h * FO + f2 * 2;
    const float2 sk = __half22float2(
        *reinterpret_cast<const __half2*>(&skipA[idx]));   // skip + bias (f16)
    float v0 = sk.x + num0 * inv;
    float v1 = sk.y + num1 * inv;
    v0 = v0 > 0.f ? v0 : expm1f(v0);
    v1 = v1 > 0.f ? v1 : expm1f(v1);
    *reinterpret_cast<float2*>(&out[idx]) = make_float2(v0, v1);
}

// ---------------------------------------------------------------------------
extern "C" void kernel_launch(void* const* d_in, const int* in_sizes, int n_in,
                              void* d_out, int out_size, void* d_ws, size_t ws_size,
                              hipStream_t stream)
{
    const float* x     = (const float*)d_in[0];
    const int*   ei    = (const int*)d_in[1];
    const float* prob  = (const float*)d_in[2];
    const float* Wp    = (const float*)d_in[3];
    const float* Wt    = (const float*)d_in[4];
    const float* a_src = (const float*)d_in[5];
    const float* a_trg = (const float*)d_in[6];
    const float* a_tp  = (const float*)d_in[7];
    const float* Wskip = (const float*)d_in[8];
    const float* bias  = (const float*)d_in[9];
    float* out = (float*)d_out;

    const int E = in_sizes[2];        // edge_prob element count = E
    const int* src = ei;              // edge_index row 0
    const int* trg = ei + E;          // edge_index row 1

    // Workspace layout (~34 MB); all blocks 16B-aligned by construction
    char* wsb = (char*)d_ws;
    __half* projA  = (__half*)wsb;                      // Nn*HF f16 (12.8 MB)
    __half* skipA  = projA + (size_t)Nn * HF;           // Nn*HF f16 (12.8 MB)
    __half* ssh    = skipA + (size_t)Nn * HF;           // Nn*8  f16 (0.8 MB)
    __half* sth    = ssh + (size_t)Nn * 8;              // Nn*8  f16 (0.8 MB)
    float* ctp     = (float*)(sth + (size_t)Nn * 8);    // 16 floats
    _Float16* Wh   = (_Float16*)(ctp + 16);             // 272*128   (68 KB)
    unsigned int* spk = (unsigned int*)(Wh + (size_t)NWR * FIN); // E (3.2 MB)
    int*   rank    = (int*)(spk + E);                   // E         (3.2 MB)
    int*   deg     = rank + E;                          // Nn
    int*   pos     = deg + Nn;                          // Nn
    int*   partial = pos + Nn;                          // NSCAN (pad 256)

    hipMemsetAsync(deg, 0, (size_t)Nn * sizeof(int), stream);
    k_prep<<<NWR / 2, 256, 0, stream>>>(Wp, Wskip, a_src, a_trg, Wt, a_tp,
                                        Wh, ctp);
    k_cn<<<NBLK64, 256, 0, stream>>>(trg, deg, rank, x, Wh, bias,
                                     projA, skipA, ssh, sth, E);
    k_scan1<<<NSCAN, 256, 0, stream>>>(deg, partial);
    k_scan3<<<NSCAN, 256, 0, stream>>>(deg, partial, pos);
    k_fill<<<NBLK64, 256, 0, stream>>>(src, trg, prob, rank, pos, spk, E);
    k_gather<<<Nn / 4, 256, 0, stream>>>(spk, pos, ssh, sth, ctp, skipA,
                                         (const __half2*)projA, out, E);
}

// Round 24
// 122.702 us; speedup vs baseline: 1.4661x; 1.0015x over previous
//
#include <hip/hip_runtime.h>
#include <hip/hip_fp16.h>
#include <math.h>

// Problem constants (from reference)
constexpr int Nn  = 50000;   // nodes
constexpr int FIN = 128;     // input features
constexpr int NH  = 8;       // heads
constexpr int FO  = 16;      // features per head
constexpr int HF  = 128;     // NH*FO
constexpr int NWR = 272;     // Wh rows: Wp(128) | Wskip(128) | Va_src(8) | Va_trg(8)
constexpr int NBLK64 = (Nn + 63) / 64;          // 782 node blocks (64 nodes ea)
constexpr int NSCAN = (Nn + 255) / 256;         // 196 scan blocks

typedef _Float16 f16x8 __attribute__((ext_vector_type(8)));
typedef float    f32x4 __attribute__((ext_vector_type(4)));

// pack 4 f32 -> 4 f16 and store as one 8-byte write
static __device__ __forceinline__ void store_h4(__half* p, f32x4 v)
{
    union { __half2 h2[2]; float2 f2; } u;
    u.h2[0] = __floats2half2_rn(v[0], v[1]);
    u.h2[1] = __floats2half2_rn(v[2], v[3]);
    *reinterpret_cast<float2*>(p) = u.f2;
}

// ---------------------------------------------------------------------------
// Weight prep (must complete before k_cn's node GEMM): Wh[272][128] f16
// (rows: Wp | Wskip | Va_src | Va_trg); ctp[h] = <Wt[h,:], a_tp[h,:]> (blk 0).
// ---------------------------------------------------------------------------
__global__ __launch_bounds__(256) void k_prep(
    const float* __restrict__ Wp, const float* __restrict__ Wskip,
    const float* __restrict__ a_src, const float* __restrict__ a_trg,
    const float* __restrict__ Wt, const float* __restrict__ a_tp,
    _Float16* __restrict__ Wh, float* __restrict__ ctp)
{
    if (blockIdx.x == 0 && threadIdx.x < NH) {
        int h = threadIdx.x;
        float s = 0.f;
        #pragma unroll
        for (int f = 0; f < FO; ++f) s += Wt[h * FO + f] * a_tp[h * FO + f];
        ctp[h] = s;
    }
    const int o = blockIdx.x * 2 + (threadIdx.x >> 7);  // 0..271
    const int k = threadIdx.x & 127;
    float v;
    if (o < 128)      v = Wp[o * FIN + k];
    else if (o < 256) v = Wskip[(o - 128) * FIN + k];
    else if (o < 264) {
        const int h = o - 256;
        float s = 0.f;
        #pragma unroll
        for (int f = 0; f < FO; ++f)
            s += a_src[h * FO + f] * Wp[(h * FO + f) * FIN + k];
        v = s;
    } else {
        const int h = o - 264;
        float s = 0.f;
        #pragma unroll
        for (int f = 0; f < FO; ++f)
            s += a_trg[h * FO + f] * Wp[(h * FO + f) * FIN + k];
        v = s;
    }
    Wh[o * FIN + k] = (_Float16)v;
}

// ---------------------------------------------------------------------------
// Node GEMM with intra-block count overlap. SWAPPED MFMA operands
// (D = Wh_frag . x_frag): A/B lane layouts are identical so register loads
// are unchanged; the transposed D mapping gives each lane 4 CONSECUTIVE
// out-dims for ONE node (col=lane&15=node, row=kb*4+r=out-dim), so every
// tile's accumulator packs into a single 8-byte f16 store (4x fewer store
// instructions, full 32B-segment write utilization — R23's epilogue was
// 2-byte scalar stores at ~0.9 TB/s effective).
//   projA[n][o]   f16 (o<128), skipA[n][o] f16 = skip+bias
//   ssh/sth[n][h] f16 score arrays
// count: trg loads issue first; returning atomics + rank write after epilogue.
// ---------------------------------------------------------------------------
__global__ __launch_bounds__(256) void k_cn(
    const int* __restrict__ trg, int* __restrict__ deg, int* __restrict__ rank,
    const float* __restrict__ x, const _Float16* __restrict__ Wh,
    const float* __restrict__ bias,
    __half* __restrict__ projA, __half* __restrict__ skipA,
    __half* __restrict__ ssh, __half* __restrict__ sth, int E)
{
    const int bid = blockIdx.x;

    // ---- count stage A: issue trg loads ----
    const int e4 = bid * 256 + threadIdx.x;    // edge quad index
    const bool doCnt = (e4 * 4 < E);
    int4 t4;
    if (doCnt) t4 = reinterpret_cast<const int4*>(trg)[e4];

    // ---- node GEMM ----
    const int g0 = bid * 64;
    const int w  = threadIdx.x >> 6;           // wave 0..3 (uniform per wave)
    const int l  = threadIdx.x & 63;
    const int lr = l & 15;
    const int kb = l >> 4;                     // k-block 0..3
    const int t0 = w * 4;                      // first tile of this wave

    // Wh fragments (now the A operand): loaded ONCE, reused across groups
    f16x8 b[4][4];
    const _Float16* wb = Wh + (size_t)lr * FIN + kb * 8;
    #pragma unroll
    for (int i = 0; i < 4; ++i) {
        #pragma unroll
        for (int ks = 0; ks < 4; ++ks)
            b[i][ks] = *reinterpret_cast<const f16x8*>(
                wb + (size_t)(t0 + i) * 16 * FIN + ks * 32);
    }
    f16x8 b16[4];
    if (w == 3) {
        #pragma unroll
        for (int ks = 0; ks < 4; ++ks)
            b16[ks] = *reinterpret_cast<const f16x8*>(
                wb + (size_t)16 * 16 * FIN + ks * 32);
    }

    // bias (contiguous float4 per tile), hoisted — only skip waves use it
    float4 bo[4];
    if (t0 >= 8) {
        #pragma unroll
        for (int i = 0; i < 4; ++i)
            bo[i] = *reinterpret_cast<const float4*>(
                &bias[(t0 + i) * 16 + kb * 4 - 128]);
    }

    const float* xr0 = x + (size_t)(g0 + lr) * FIN + kb * 8;

    if (g0 + 64 <= Nn) {
        // ---- full block: 4 groups, 2-stage pipeline ----
        float4 ucur[8];
        #pragma unroll
        for (int q = 0; q < 8; ++q)
            ucur[q] = *reinterpret_cast<const float4*>(
                xr0 + (q >> 1) * 32 + (q & 1) * 4);

        #pragma unroll
        for (int ng = 0; ng < 4; ++ng) {
            float4 unx[8];
            if (ng < 3) {
                const float* xrn = xr0 + (size_t)(ng + 1) * 16 * FIN;
                #pragma unroll
                for (int q = 0; q < 8; ++q)
                    unx[q] = *reinterpret_cast<const float4*>(
                        xrn + (q >> 1) * 32 + (q & 1) * 4);
            }

            f16x8 a[4];
            #pragma unroll
            for (int ks = 0; ks < 4; ++ks) {
                float4 lo = ucur[ks * 2], hi = ucur[ks * 2 + 1];
                a[ks][0] = (_Float16)lo.x; a[ks][1] = (_Float16)lo.y;
                a[ks][2] = (_Float16)lo.z; a[ks][3] = (_Float16)lo.w;
                a[ks][4] = (_Float16)hi.x; a[ks][5] = (_Float16)hi.y;
                a[ks][6] = (_Float16)hi.z; a[ks][7] = (_Float16)hi.w;
            }

            f32x4 acc[4];
            #pragma unroll
            for (int i = 0; i < 4; ++i) acc[i] = (f32x4){0.f, 0.f, 0.f, 0.f};
            f32x4 acc16 = (f32x4){0.f, 0.f, 0.f, 0.f};

            // SWAPPED operand order: A = Wh tile, B = x rows
            #pragma unroll
            for (int i = 0; i < 4; ++i) {
                #pragma unroll
                for (int ks = 0; ks < 4; ++ks)
                    acc[i] = __builtin_amdgcn_mfma_f32_16x16x32_f16(
                        b[i][ks], a[ks], acc[i], 0, 0, 0);
            }
            if (w == 3) {
                #pragma unroll
                for (int ks = 0; ks < 4; ++ks)
                    acc16 = __builtin_amdgcn_mfma_f32_16x16x32_f16(
                        b16[ks], a[ks], acc16, 0, 0, 0);
            }

            // epilogue: lane owns node n, 4 consecutive out-dims per tile
            const int n = g0 + ng * 16 + lr;
            #pragma unroll
            for (int i = 0; i < 4; ++i) {
                const int ob = (t0 + i) * 16 + kb * 4;
                if (t0 < 8) {
                    store_h4(&projA[(size_t)n * HF + ob], acc[i]);
                } else {
                    f32x4 v = acc[i];
                    v[0] += bo[i].x; v[1] += bo[i].y;
                    v[2] += bo[i].z; v[3] += bo[i].w;
                    store_h4(&skipA[(size_t)n * HF + (ob - 128)], v);
                }
            }
            if (w == 3) {
                __half* sp = (kb < 2) ? (ssh + n * 8 + kb * 4)
                                      : (sth + n * 8 + (kb - 2) * 4);
                store_h4(sp, acc16);
            }

            #pragma unroll
            for (int q = 0; q < 8; ++q) ucur[q] = unx[q];
        }
    } else {
        // ---- partial last block (one 16-node group at 49984) ----
        f16x8 a[4];
        #pragma unroll
        for (int ks = 0; ks < 4; ++ks) {
            float4 u0 = *reinterpret_cast<const float4*>(xr0 + ks * 32);
            float4 u1 = *reinterpret_cast<const float4*>(xr0 + ks * 32 + 4);
            a[ks][0] = (_Float16)u0.x; a[ks][1] = (_Float16)u0.y;
            a[ks][2] = (_Float16)u0.z; a[ks][3] = (_Float16)u0.w;
            a[ks][4] = (_Float16)u1.x; a[ks][5] = (_Float16)u1.y;
            a[ks][6] = (_Float16)u1.z; a[ks][7] = (_Float16)u1.w;
        }

        f32x4 acc[4];
        #pragma unroll
        for (int i = 0; i < 4; ++i) acc[i] = (f32x4){0.f, 0.f, 0.f, 0.f};
        f32x4 acc16 = (f32x4){0.f, 0.f, 0.f, 0.f};

        #pragma unroll
        for (int i = 0; i < 4; ++i) {
            #pragma unroll
            for (int ks = 0; ks < 4; ++ks)
                acc[i] = __builtin_amdgcn_mfma_f32_16x16x32_f16(
                    b[i][ks], a[ks], acc[i], 0, 0, 0);
        }
        if (w == 3) {
            #pragma unroll
            for (int ks = 0; ks < 4; ++ks)
                acc16 = __builtin_amdgcn_mfma_f32_16x16x32_f16(
                    b16[ks], a[ks], acc16, 0, 0, 0);
        }

        const int n = g0 + lr;
        #pragma unroll
        for (int i = 0; i < 4; ++i) {
            const int ob = (t0 + i) * 16 + kb * 4;
            if (t0 < 8) {
                store_h4(&projA[(size_t)n * HF + ob], acc[i]);
            } else {
                f32x4 v = acc[i];
                v[0] += bo[i].x; v[1] += bo[i].y;
                v[2] += bo[i].z; v[3] += bo[i].w;
                store_h4(&skipA[(size_t)n * HF + (ob - 128)], v);
            }
        }
        if (w == 3) {
            __half* sp = (kb < 2) ? (ssh + n * 8 + kb * 4)
                                  : (sth + n * 8 + (kb - 2) * 4);
            store_h4(sp, acc16);
        }
    }

    // ---- count stage B: 4 independent returning atomics + rank write ----
    if (doCnt) {
        int4 r;
        r.x = atomicAdd(&deg[t4.x], 1);
        r.y = atomicAdd(&deg[t4.y], 1);
        r.z = atomicAdd(&deg[t4.z], 1);
        r.w = atomicAdd(&deg[t4.w], 1);
        reinterpret_cast<int4*>(rank)[e4] = r;
    }
}

// ---------------------------------------------------------------------------
// Scan pair. pos stays EXCLUSIVE; row n spans [pos[n], n+1<Nn?pos[n+1]:E).
// ---------------------------------------------------------------------------
__global__ __launch_bounds__(256) void k_scan1(const int* __restrict__ deg,
                                               int* __restrict__ partial)
{
    __shared__ int lds[256];
    int t = threadIdx.x, i = blockIdx.x * 256 + t;
    lds[t] = (i < Nn) ? deg[i] : 0;
    __syncthreads();
    for (int off = 128; off > 0; off >>= 1) {
        if (t < off) lds[t] += lds[t + off];
        __syncthreads();
    }
    if (t == 0) partial[blockIdx.x] = lds[0];
}

__global__ __launch_bounds__(256) void k_scan3(const int* __restrict__ deg,
                                               const int* __restrict__ partial,
                                               int* __restrict__ pos)
{
    __shared__ int lds[256], lds2[256];
    const int t = threadIdx.x;
    const int i = blockIdx.x * 256 + t;
    lds2[t] = (t < NSCAN) ? partial[t] : 0;
    __syncthreads();
    for (int off = 1; off < 256; off <<= 1) {
        int u = (t >= off) ? lds2[t - off] : 0;
        __syncthreads();
        lds2[t] += u;
        __syncthreads();
    }
    const int base = (blockIdx.x == 0) ? 0 : lds2[blockIdx.x - 1];
    int v = (i < Nn) ? deg[i] : 0;
    lds[t] = v;
    __syncthreads();
    for (int off = 1; off < 256; off <<= 1) {
        int u = (t >= off) ? lds[t - off] : 0;
        __syncthreads();
        lds[t] += u;
        __syncthreads();
    }
    if (i < Nn) pos[i] = base + lds[t] - v;
}

// ---------------------------------------------------------------------------
// Fill (atomic-free): slot = pos[trg] + rank; spk = src(16b)|f16(prob)(16b).
// ---------------------------------------------------------------------------
__global__ __launch_bounds__(256) void k_fill(
    const int* __restrict__ src, const int* __restrict__ trg,
    const float* __restrict__ prob, const int* __restrict__ rank,
    const int* __restrict__ pos, unsigned int* __restrict__ spk, int E)
{
    int e4 = blockIdx.x * 256 + threadIdx.x;
    if (e4 * 4 >= E) return;
    int4   s4 = reinterpret_cast<const int4*>(src)[e4];
    int4   t4 = reinterpret_cast<const int4*>(trg)[e4];
    float4 p4 = reinterpret_cast<const float4*>(prob)[e4];
    int4   r4 = reinterpret_cast<const int4*>(rank)[e4];
    int    sv[4] = {s4.x, s4.y, s4.z, s4.w};
    int    tv[4] = {t4.x, t4.y, t4.z, t4.w};
    int    rv[4] = {r4.x, r4.y, r4.z, r4.w};
    float  pv[4] = {p4.x, p4.y, p4.z, p4.w};
    #pragma unroll
    for (int i = 0; i < 4; ++i) {
        int slot = pos[tv[i]] + rv[i];
        spk[slot] = (unsigned int)sv[i] |
            ((unsigned int)__half_as_ushort(__float2half_rn(pv[i])) << 16);
    }
}

// ---------------------------------------------------------------------------
// Fused gather with scalarized edge walk: one wave per node; lanes = 8 heads
// x 8 feature-pairs. spk stream via readfirstlane (scalar pipe); per-edge
// vector work = f16 score gather + 256B projA wave-read + exp + 2 FMA.
// Epilogue reads f16 skipA and writes f32 out exactly once (no RMW).
// ---------------------------------------------------------------------------
__global__ __launch_bounds__(256) void k_gather(
    const unsigned int* __restrict__ spk, const int* __restrict__ pos,
    const __half* __restrict__ ssh, const __half* __restrict__ sth,
    const float* __restrict__ ctp, const __half* __restrict__ skipA,
    const __half2* __restrict__ projA, float* __restrict__ out, int E)
{
    const int lane = threadIdx.x & 63;
    const int h    = lane >> 3;                // head 0..7
    const int f2   = lane & 7;                 // feature pair 0..7

    // wave-uniform node id, forced scalar
    const int n = __builtin_amdgcn_readfirstlane(
        blockIdx.x * 4 + (threadIdx.x >> 6));  // 12500*4 = 50000 exactly

    const int jb = __builtin_amdgcn_readfirstlane(pos[n]);
    const int je = __builtin_amdgcn_readfirstlane((n + 1 < Nn) ? pos[n + 1] : E);

    const float st  = __half2float(sth[n * 8 + h]);
    const float cth = ctp[h];
    const __half* __restrict__ ssl = ssh + h;            // [s*8]
    const __half2* __restrict__ pA = projA + h * 8 + f2; // [s*64]

    float num0 = 0.f, num1 = 0.f, den = 0.f;
    int j = jb;
    for (; j + 3 < je; j += 4) {               // 4 independent chains
        const unsigned int pk0 = __builtin_amdgcn_readfirstlane(spk[j]);
        const unsigned int pk1 = __builtin_amdgcn_readfirstlane(spk[j + 1]);
        const unsigned int pk2 = __builtin_amdgcn_readfirstlane(spk[j + 2]);
        const unsigned int pk3 = __builtin_amdgcn_readfirstlane(spk[j + 3]);
        const int s0 = pk0 & 0xFFFF, s1 = pk1 & 0xFFFF;
        const int s2 = pk2 & 0xFFFF, s3 = pk3 & 0xFFFF;
        const float ss0 = __half2float(ssl[s0 * 8]);
        const float ss1 = __half2float(ssl[s1 * 8]);
        const float ss2 = __half2float(ssl[s2 * 8]);
        const float ss3 = __half2float(ssl[s3 * 8]);
        const __half2 g0 = pA[s0 * 64], g1 = pA[s1 * 64];
        const __half2 g2 = pA[s2 * 64], g3 = pA[s3 * 64];
        const float p0 = __half2float(__ushort_as_half((unsigned short)(pk0 >> 16)));
        const float p1 = __half2float(__ushort_as_half((unsigned short)(pk1 >> 16)));
        const float p2 = __half2float(__ushort_as_half((unsigned short)(pk2 >> 16)));
        const float p3 = __half2float(__ushort_as_half((unsigned short)(pk3 >> 16)));
        float sc0 = ss0 + st + cth * p0;
        float sc1 = ss1 + st + cth * p1;
        float sc2 = ss2 + st + cth * p2;
        float sc3 = ss3 + st + cth * p3;
        sc0 = fmaxf(sc0, 0.2f * sc0);          // leaky_relu(0.2)
        sc1 = fmaxf(sc1, 0.2f * sc1);
        sc2 = fmaxf(sc2, 0.2f * sc2);
        sc3 = fmaxf(sc3, 0.2f * sc3);
        const float ev0 = __expf(sc0), ev1 = __expf(sc1);
        const float ev2 = __expf(sc2), ev3 = __expf(sc3);
        const float2 G0 = __half22float2(g0), G1 = __half22float2(g1);
        const float2 G2 = __half22float2(g2), G3 = __half22float2(g3);
        den  += (ev0 + ev1) + (ev2 + ev3);
        num0 += ev0 * G0.x + ev1 * G1.x + ev2 * G2.x + ev3 * G3.x;
        num1 += ev0 * G0.y + ev1 * G1.y + ev2 * G2.y + ev3 * G3.y;
    }
    for (; j < je; ++j) {
        const unsigned int pk = __builtin_amdgcn_readfirstlane(spk[j]);
        const int s = pk & 0xFFFF;
        const float p = __half2float(__ushort_as_half((unsigned short)(pk >> 16)));
        float sc = __half2float(ssl[s * 8]) + st + cth * p;
        sc = fmaxf(sc, 0.2f * sc);
        const float ev = __expf(sc);
        const float2 G = __half22float2(pA[s * 64]);
        den  += ev;
        num0 += ev * G.x;
        num1 += ev * G.y;
    }

    const float inv = 1.f / (den + 1e-16f);
    const int idx = n * HF + h * FO + f2 * 2;
    const float2 sk = __half22float2(
        *reinterpret_cast<const __half2*>(&skipA[idx]));   // skip + bias (f16)
    float v0 = sk.x + num0 * inv;
    float v1 = sk.y + num1 * inv;
    v0 = v0 > 0.f ? v0 : expm1f(v0);
    v1 = v1 > 0.f ? v1 : expm1f(v1);
    *reinterpret_cast<float2*>(&out[idx]) = make_float2(v0, v1);
}

// ---------------------------------------------------------------------------
extern "C" void kernel_launch(void* const* d_in, const int* in_sizes, int n_in,
                              void* d_out, int out_size, void* d_ws, size_t ws_size,
                              hipStream_t stream)
{
    const float* x     = (const float*)d_in[0];
    const int*   ei    = (const int*)d_in[1];
    const float* prob  = (const float*)d_in[2];
    const float* Wp    = (const float*)d_in[3];
    const float* Wt    = (const float*)d_in[4];
    const float* a_src = (const float*)d_in[5];
    const float* a_trg = (const float*)d_in[6];
    const float* a_tp  = (const float*)d_in[7];
    const float* Wskip = (const float*)d_in[8];
    const float* bias  = (const float*)d_in[9];
    float* out = (float*)d_out;

    const int E = in_sizes[2];        // edge_prob element count = E
    const int* src = ei;              // edge_index row 0
    const int* trg = ei + E;          // edge_index row 1

    // Workspace layout (~34 MB); all blocks 16B-aligned by construction
    char* wsb = (char*)d_ws;
    __half* projA  = (__half*)wsb;                      // Nn*HF f16 (12.8 MB)
    __half* skipA  = projA + (size_t)Nn * HF;           // Nn*HF f16 (12.8 MB)
    __half* ssh    = skipA + (size_t)Nn * HF;           // Nn*8  f16 (0.8 MB)
    __half* sth    = ssh + (size_t)Nn * 8;              // Nn*8  f16 (0.8 MB)
    float* ctp     = (float*)(sth + (size_t)Nn * 8);    // 16 floats
    _Float16* Wh   = (_Float16*)(ctp + 16);             // 272*128   (68 KB)
    unsigned int* spk = (unsigned int*)(Wh + (size_t)NWR * FIN); // E (3.2 MB)
    int*   rank    = (int*)(spk + E);                   // E         (3.2 MB)
    int*   deg     = rank + E;                          // Nn
    int*   pos     = deg + Nn;                          // Nn
    int*   partial = pos + Nn;                          // NSCAN (pad 256)

    hipMemsetAsync(deg, 0, (size_t)Nn * sizeof(int), stream);
    k_prep<<<NWR / 2, 256, 0, stream>>>(Wp, Wskip, a_src, a_trg, Wt, a_tp,
                                        Wh, ctp);
    k_cn<<<NBLK64, 256, 0, stream>>>(trg, deg, rank, x, Wh, bias,
                                     projA, skipA, ssh, sth, E);
    k_scan1<<<NSCAN, 256, 0, stream>>>(deg, partial);
    k_scan3<<<NSCAN, 256, 0, stream>>>(deg, partial, pos);
    k_fill<<<NBLK64, 256, 0, stream>>>(src, trg, prob, rank, pos, spk, E);
    k_gather<<<Nn / 4, 256, 0, stream>>>(spk, pos, ssh, sth, ctp, skipA,
                                         (const __half2*)projA, out, E);
}

// Round 25
// 115.097 us; speedup vs baseline: 1.5629x; 1.0661x over previous
//
#include <hip/hip_runtime.h>
#include <hip/hip_fp16.h>
#include <math.h>

// Problem constants (from reference)
constexpr int Nn  = 50000;   // nodes
constexpr int FIN = 128;     // input features
constexpr int NH  = 8;       // heads
constexpr int FO  = 16;      // features per head
constexpr int HF  = 128;     // NH*FO
constexpr int NWR = 272;     // Wh rows: Wp(128) | Wskip(128) | Va_src(8) | Va_trg(8)
constexpr int NPREP = NWR / 2;                  // 136 Wh-prep blocks (2 rows ea)
constexpr int NBLK64 = (Nn + 63) / 64;          // 782 node blocks (64 nodes ea)
constexpr int NSCAN = (Nn + 255) / 256;         // 196 scan blocks

typedef _Float16 f16x8 __attribute__((ext_vector_type(8)));
typedef float    f32x4 __attribute__((ext_vector_type(4)));

// pack 4 f32 -> 4 f16 and store as one 8-byte write
static __device__ __forceinline__ void store_h4(__half* p, f32x4 v)
{
    union { __half2 h2[2]; float2 f2; } u;
    u.h2[0] = __floats2half2_rn(v[0], v[1]);
    u.h2[1] = __floats2half2_rn(v[2], v[3]);
    *reinterpret_cast<float2*>(p) = u.f2;
}

// ---------------------------------------------------------------------------
// Weight prep + deg zeroing (memset folded in; 196 blocks):
//   all blocks      : deg[bid*256+tid] = 0 (covers Nn)
//   blocks [0,136)  : Wh[272][128] f16 (2 rows/block); ctp in block 0
// ---------------------------------------------------------------------------
__global__ __launch_bounds__(256) void k_prep(
    const float* __restrict__ Wp, const float* __restrict__ Wskip,
    const float* __restrict__ a_src, const float* __restrict__ a_trg,
    const float* __restrict__ Wt, const float* __restrict__ a_tp,
    _Float16* __restrict__ Wh, float* __restrict__ ctp,
    int* __restrict__ deg)
{
    const int bid = blockIdx.x;
    const int i = bid * 256 + threadIdx.x;
    if (i < Nn) deg[i] = 0;

    if (bid >= NPREP) return;
    if (bid == 0 && threadIdx.x < NH) {
        int h = threadIdx.x;
        float s = 0.f;
        #pragma unroll
        for (int f = 0; f < FO; ++f) s += Wt[h * FO + f] * a_tp[h * FO + f];
        ctp[h] = s;
    }
    const int o = bid * 2 + (threadIdx.x >> 7);  // 0..271
    const int k = threadIdx.x & 127;
    float v;
    if (o < 128)      v = Wp[o * FIN + k];
    else if (o < 256) v = Wskip[(o - 128) * FIN + k];
    else if (o < 264) {
        const int h = o - 256;
        float s = 0.f;
        #pragma unroll
        for (int f = 0; f < FO; ++f)
            s += a_src[h * FO + f] * Wp[(h * FO + f) * FIN + k];
        v = s;
    } else {
        const int h = o - 264;
        float s = 0.f;
        #pragma unroll
        for (int f = 0; f < FO; ++f)
            s += a_trg[h * FO + f] * Wp[(h * FO + f) * FIN + k];
        v = s;
    }
    Wh[o * FIN + k] = (_Float16)v;
}

// ---------------------------------------------------------------------------
// Node GEMM with SPREAD count overlap: edge-quad element ng's returning
// atomicAdd issues right after node-group ng's epilogue, so its ~600-900cy
// round trip hides under group ng+1's MFMA+loads (R24's end-of-block atomic
// tail was ~25us unhidden). rank int4-write at the end. Swapped MFMA
// operands (lane owns one node, 4 consecutive out-dims -> 8B stores).
// ---------------------------------------------------------------------------
__global__ __launch_bounds__(256) void k_cn(
    const int* __restrict__ trg, int* __restrict__ deg, int* __restrict__ rank,
    const float* __restrict__ x, const _Float16* __restrict__ Wh,
    const float* __restrict__ bias,
    __half* __restrict__ projA, __half* __restrict__ skipA,
    __half* __restrict__ ssh, __half* __restrict__ sth, int E)
{
    const int bid = blockIdx.x;

    // ---- count stage A: issue trg loads ----
    const int e4 = bid * 256 + threadIdx.x;    // edge quad index
    const bool doCnt = (e4 * 4 < E);
    int4 t4;
    if (doCnt) t4 = reinterpret_cast<const int4*>(trg)[e4];

    // ---- node GEMM ----
    const int g0 = bid * 64;
    const int w  = threadIdx.x >> 6;           // wave 0..3 (uniform per wave)
    const int l  = threadIdx.x & 63;
    const int lr = l & 15;
    const int kb = l >> 4;                     // k-block 0..3
    const int t0 = w * 4;                      // first tile of this wave

    // Wh fragments (A operand): loaded ONCE, reused across groups
    f16x8 b[4][4];
    const _Float16* wb = Wh + (size_t)lr * FIN + kb * 8;
    #pragma unroll
    for (int i = 0; i < 4; ++i) {
        #pragma unroll
        for (int ks = 0; ks < 4; ++ks)
            b[i][ks] = *reinterpret_cast<const f16x8*>(
                wb + (size_t)(t0 + i) * 16 * FIN + ks * 32);
    }
    f16x8 b16[4];
    if (w == 3) {
        #pragma unroll
        for (int ks = 0; ks < 4; ++ks)
            b16[ks] = *reinterpret_cast<const f16x8*>(
                wb + (size_t)16 * 16 * FIN + ks * 32);
    }

    // bias (contiguous float4 per tile), hoisted — only skip waves use it
    float4 bo[4];
    if (t0 >= 8) {
        #pragma unroll
        for (int i = 0; i < 4; ++i)
            bo[i] = *reinterpret_cast<const float4*>(
                &bias[(t0 + i) * 16 + kb * 4 - 128]);
    }

    const float* xr0 = x + (size_t)(g0 + lr) * FIN + kb * 8;

    if (g0 + 64 <= Nn) {
        // ---- full block: 4 groups, 2-stage pipeline, spread atomics ----
        float4 ucur[8];
        #pragma unroll
        for (int q = 0; q < 8; ++q)
            ucur[q] = *reinterpret_cast<const float4*>(
                xr0 + (q >> 1) * 32 + (q & 1) * 4);

        int rres[4];
        #pragma unroll
        for (int ng = 0; ng < 4; ++ng) {
            float4 unx[8];
            if (ng < 3) {
                const float* xrn = xr0 + (size_t)(ng + 1) * 16 * FIN;
                #pragma unroll
                for (int q = 0; q < 8; ++q)
                    unx[q] = *reinterpret_cast<const float4*>(
                        xrn + (q >> 1) * 32 + (q & 1) * 4);
            }

            f16x8 a[4];
            #pragma unroll
            for (int ks = 0; ks < 4; ++ks) {
                float4 lo = ucur[ks * 2], hi = ucur[ks * 2 + 1];
                a[ks][0] = (_Float16)lo.x; a[ks][1] = (_Float16)lo.y;
                a[ks][2] = (_Float16)lo.z; a[ks][3] = (_Float16)lo.w;
                a[ks][4] = (_Float16)hi.x; a[ks][5] = (_Float16)hi.y;
                a[ks][6] = (_Float16)hi.z; a[ks][7] = (_Float16)hi.w;
            }

            f32x4 acc[4];
            #pragma unroll
            for (int i = 0; i < 4; ++i) acc[i] = (f32x4){0.f, 0.f, 0.f, 0.f};
            f32x4 acc16 = (f32x4){0.f, 0.f, 0.f, 0.f};

            #pragma unroll
            for (int i = 0; i < 4; ++i) {
                #pragma unroll
                for (int ks = 0; ks < 4; ++ks)
                    acc[i] = __builtin_amdgcn_mfma_f32_16x16x32_f16(
                        b[i][ks], a[ks], acc[i], 0, 0, 0);
            }
            if (w == 3) {
                #pragma unroll
                for (int ks = 0; ks < 4; ++ks)
                    acc16 = __builtin_amdgcn_mfma_f32_16x16x32_f16(
                        b16[ks], a[ks], acc16, 0, 0, 0);
            }

            // epilogue: lane owns node n, 4 consecutive out-dims per tile
            const int n = g0 + ng * 16 + lr;
            #pragma unroll
            for (int i = 0; i < 4; ++i) {
                const int ob = (t0 + i) * 16 + kb * 4;
                if (t0 < 8) {
                    store_h4(&projA[(size_t)n * HF + ob], acc[i]);
                } else {
                    f32x4 v = acc[i];
                    v[0] += bo[i].x; v[1] += bo[i].y;
                    v[2] += bo[i].z; v[3] += bo[i].w;
                    store_h4(&skipA[(size_t)n * HF + (ob - 128)], v);
                }
            }
            if (w == 3) {
                __half* sp = (kb < 2) ? (ssh + n * 8 + kb * 4)
                                      : (sth + n * 8 + (kb - 2) * 4);
                store_h4(sp, acc16);
            }

            // spread atomic: edge ng of this thread's quad issues NOW; its
            // latency hides under group ng+1's loads + MFMAs.
            if (doCnt) {
                const int tv = (ng == 0) ? t4.x : (ng == 1) ? t4.y
                             : (ng == 2) ? t4.z : t4.w;
                rres[ng] = atomicAdd(&deg[tv], 1);
            }

            #pragma unroll
            for (int q = 0; q < 8; ++q) ucur[q] = unx[q];
        }

        if (doCnt) {
            int4 r;
            r.x = rres[0]; r.y = rres[1]; r.z = rres[2]; r.w = rres[3];
            reinterpret_cast<int4*>(rank)[e4] = r;
        }
    } else {
        // ---- partial last block (one 16-node group at 49984) ----
        f16x8 a[4];
        #pragma unroll
        for (int ks = 0; ks < 4; ++ks) {
            float4 u0 = *reinterpret_cast<const float4*>(xr0 + ks * 32);
            float4 u1 = *reinterpret_cast<const float4*>(xr0 + ks * 32 + 4);
            a[ks][0] = (_Float16)u0.x; a[ks][1] = (_Float16)u0.y;
            a[ks][2] = (_Float16)u0.z; a[ks][3] = (_Float16)u0.w;
            a[ks][4] = (_Float16)u1.x; a[ks][5] = (_Float16)u1.y;
            a[ks][6] = (_Float16)u1.z; a[ks][7] = (_Float16)u1.w;
        }

        f32x4 acc[4];
        #pragma unroll
        for (int i = 0; i < 4; ++i) acc[i] = (f32x4){0.f, 0.f, 0.f, 0.f};
        f32x4 acc16 = (f32x4){0.f, 0.f, 0.f, 0.f};

        #pragma unroll
        for (int i = 0; i < 4; ++i) {
            #pragma unroll
            for (int ks = 0; ks < 4; ++ks)
                acc[i] = __builtin_amdgcn_mfma_f32_16x16x32_f16(
                    b[i][ks], a[ks], acc[i], 0, 0, 0);
        }
        if (w == 3) {
            #pragma unroll
            for (int ks = 0; ks < 4; ++ks)
                acc16 = __builtin_amdgcn_mfma_f32_16x16x32_f16(
                    b16[ks], a[ks], acc16, 0, 0, 0);
        }

        const int n = g0 + lr;
        #pragma unroll
        for (int i = 0; i < 4; ++i) {
            const int ob = (t0 + i) * 16 + kb * 4;
            if (t0 < 8) {
                store_h4(&projA[(size_t)n * HF + ob], acc[i]);
            } else {
                f32x4 v = acc[i];
                v[0] += bo[i].x; v[1] += bo[i].y;
                v[2] += bo[i].z; v[3] += bo[i].w;
                store_h4(&skipA[(size_t)n * HF + (ob - 128)], v);
            }
        }
        if (w == 3) {
            __half* sp = (kb < 2) ? (ssh + n * 8 + kb * 4)
                                  : (sth + n * 8 + (kb - 2) * 4);
            store_h4(sp, acc16);
        }

        if (doCnt) {
            int4 r;
            r.x = atomicAdd(&deg[t4.x], 1);
            r.y = atomicAdd(&deg[t4.y], 1);
            r.z = atomicAdd(&deg[t4.z], 1);
            r.w = atomicAdd(&deg[t4.w], 1);
            reinterpret_cast<int4*>(rank)[e4] = r;
        }
    }
}

// ---------------------------------------------------------------------------
// Scan pair. pos stays EXCLUSIVE; row n spans [pos[n], n+1<Nn?pos[n+1]:E).
// ---------------------------------------------------------------------------
__global__ __launch_bounds__(256) void k_scan1(const int* __restrict__ deg,
                                               int* __restrict__ partial)
{
    __shared__ int lds[256];
    int t = threadIdx.x, i = blockIdx.x * 256 + t;
    lds[t] = (i < Nn) ? deg[i] : 0;
    __syncthreads();
    for (int off = 128; off > 0; off >>= 1) {
        if (t < off) lds[t] += lds[t + off];
        __syncthreads();
    }
    if (t == 0) partial[blockIdx.x] = lds[0];
}

__global__ __launch_bounds__(256) void k_scan3(const int* __restrict__ deg,
                                               const int* __restrict__ partial,
                                               int* __restrict__ pos)
{
    __shared__ int lds[256], lds2[256];
    const int t = threadIdx.x;
    const int i = blockIdx.x * 256 + t;
    lds2[t] = (t < NSCAN) ? partial[t] : 0;
    __syncthreads();
    for (int off = 1; off < 256; off <<= 1) {
        int u = (t >= off) ? lds2[t - off] : 0;
        __syncthreads();
        lds2[t] += u;
        __syncthreads();
    }
    const int base = (blockIdx.x == 0) ? 0 : lds2[blockIdx.x - 1];
    int v = (i < Nn) ? deg[i] : 0;
    lds[t] = v;
    __syncthreads();
    for (int off = 1; off < 256; off <<= 1) {
        int u = (t >= off) ? lds[t - off] : 0;
        __syncthreads();
        lds[t] += u;
        __syncthreads();
    }
    if (i < Nn) pos[i] = base + lds[t] - v;
}

// ---------------------------------------------------------------------------
// Fill (atomic-free): slot = pos[trg] + rank; spk = src(16b)|f16(prob)(16b).
// ---------------------------------------------------------------------------
__global__ __launch_bounds__(256) void k_fill(
    const int* __restrict__ src, const int* __restrict__ trg,
    const float* __restrict__ prob, const int* __restrict__ rank,
    const int* __restrict__ pos, unsigned int* __restrict__ spk, int E)
{
    int e4 = blockIdx.x * 256 + threadIdx.x;
    if (e4 * 4 >= E) return;
    int4   s4 = reinterpret_cast<const int4*>(src)[e4];
    int4   t4 = reinterpret_cast<const int4*>(trg)[e4];
    float4 p4 = reinterpret_cast<const float4*>(prob)[e4];
    int4   r4 = reinterpret_cast<const int4*>(rank)[e4];
    int    sv[4] = {s4.x, s4.y, s4.z, s4.w};
    int    tv[4] = {t4.x, t4.y, t4.z, t4.w};
    int    rv[4] = {r4.x, r4.y, r4.z, r4.w};
    float  pv[4] = {p4.x, p4.y, p4.z, p4.w};
    #pragma unroll
    for (int i = 0; i < 4; ++i) {
        int slot = pos[tv[i]] + rv[i];
        spk[slot] = (unsigned int)sv[i] |
            ((unsigned int)__half_as_ushort(__float2half_rn(pv[i])) << 16);
    }
}

// ---------------------------------------------------------------------------
// Fused gather with scalarized edge walk: one wave per node; lanes = 8 heads
// x 8 feature-pairs. spk stream via readfirstlane (scalar pipe); per-edge
// vector work = f16 score gather + 256B projA wave-read + exp + 2 FMA.
// Epilogue reads f16 skipA and writes f32 out exactly once (no RMW).
// ---------------------------------------------------------------------------
__global__ __launch_bounds__(256) void k_gather(
    const unsigned int* __restrict__ spk, const int* __restrict__ pos,
    const __half* __restrict__ ssh, const __half* __restrict__ sth,
    const float* __restrict__ ctp, const __half* __restrict__ skipA,
    const __half2* __restrict__ projA, float* __restrict__ out, int E)
{
    const int lane = threadIdx.x & 63;
    const int h    = lane >> 3;                // head 0..7
    const int f2   = lane & 7;                 // feature pair 0..7

    // wave-uniform node id, forced scalar
    const int n = __builtin_amdgcn_readfirstlane(
        blockIdx.x * 4 + (threadIdx.x >> 6));  // 12500*4 = 50000 exactly

    const int jb = __builtin_amdgcn_readfirstlane(pos[n]);
    const int je = __builtin_amdgcn_readfirstlane((n + 1 < Nn) ? pos[n + 1] : E);

    const float st  = __half2float(sth[n * 8 + h]);
    const float cth = ctp[h];
    const __half* __restrict__ ssl = ssh + h;            // [s*8]
    const __half2* __restrict__ pA = projA + h * 8 + f2; // [s*64]

    float num0 = 0.f, num1 = 0.f, den = 0.f;
    int j = jb;
    for (; j + 3 < je; j += 4) {               // 4 independent chains
        const unsigned int pk0 = __builtin_amdgcn_readfirstlane(spk[j]);
        const unsigned int pk1 = __builtin_amdgcn_readfirstlane(spk[j + 1]);
        const unsigned int pk2 = __builtin_amdgcn_readfirstlane(spk[j + 2]);
        const unsigned int pk3 = __builtin_amdgcn_readfirstlane(spk[j + 3]);
        const int s0 = pk0 & 0xFFFF, s1 = pk1 & 0xFFFF;
        const int s2 = pk2 & 0xFFFF, s3 = pk3 & 0xFFFF;
        const float ss0 = __half2float(ssl[s0 * 8]);
        const float ss1 = __half2float(ssl[s1 * 8]);
        const float ss2 = __half2float(ssl[s2 * 8]);
        const float ss3 = __half2float(ssl[s3 * 8]);
        const __half2 g0 = pA[s0 * 64], g1 = pA[s1 * 64];
        const __half2 g2 = pA[s2 * 64], g3 = pA[s3 * 64];
        const float p0 = __half2float(__ushort_as_half((unsigned short)(pk0 >> 16)));
        const float p1 = __half2float(__ushort_as_half((unsigned short)(pk1 >> 16)));
        const float p2 = __half2float(__ushort_as_half((unsigned short)(pk2 >> 16)));
        const float p3 = __half2float(__ushort_as_half((unsigned short)(pk3 >> 16)));
        float sc0 = ss0 + st + cth * p0;
        float sc1 = ss1 + st + cth * p1;
        float sc2 = ss2 + st + cth * p2;
        float sc3 = ss3 + st + cth * p3;
        sc0 = fmaxf(sc0, 0.2f * sc0);          // leaky_relu(0.2)
        sc1 = fmaxf(sc1, 0.2f * sc1);
        sc2 = fmaxf(sc2, 0.2f * sc2);
        sc3 = fmaxf(sc3, 0.2f * sc3);
        const float ev0 = __expf(sc0), ev1 = __expf(sc1);
        const float ev2 = __expf(sc2), ev3 = __expf(sc3);
        const float2 G0 = __half22float2(g0), G1 = __half22float2(g1);
        const float2 G2 = __half22float2(g2), G3 = __half22float2(g3);
        den  += (ev0 + ev1) + (ev2 + ev3);
        num0 += ev0 * G0.x + ev1 * G1.x + ev2 * G2.x + ev3 * G3.x;
        num1 += ev0 * G0.y + ev1 * G1.y + ev2 * G2.y + ev3 * G3.y;
    }
    for (; j < je; ++j) {
        const unsigned int pk = __builtin_amdgcn_readfirstlane(spk[j]);
        const int s = pk & 0xFFFF;
        const float p = __half2float(__ushort_as_half((unsigned short)(pk >> 16)));
        float sc = __half2float(ssl[s * 8]) + st + cth * p;
        sc = fmaxf(sc, 0.2f * sc);
        const float ev = __expf(sc);
        const float2 G = __half22float2(pA[s * 64]);
        den  += ev;
        num0 += ev * G.x;
        num1 += ev * G.y;
    }

    const float inv = 1.f / (den + 1e-16f);
    const int idx = n * HF + h * FO + f2 * 2;
    const float2 sk = __half22float2(
        *reinterpret_cast<const __half2*>(&skipA[idx]));   // skip + bias (f16)
    float v0 = sk.x + num0 * inv;
    float v1 = sk.y + num1 * inv;
    v0 = v0 > 0.f ? v0 : expm1f(v0);
    v1 = v1 > 0.f ? v1 : expm1f(v1);
    *reinterpret_cast<float2*>(&out[idx]) = make_float2(v0, v1);
}

// ---------------------------------------------------------------------------
extern "C" void kernel_launch(void* const* d_in, const int* in_sizes, int n_in,
                              void* d_out, int out_size, void* d_ws, size_t ws_size,
                              hipStream_t stream)
{
    const float* x     = (const float*)d_in[0];
    const int*   ei    = (const int*)d_in[1];
    const float* prob  = (const float*)d_in[2];
    const float* Wp    = (const float*)d_in[3];
    const float* Wt    = (const float*)d_in[4];
    const float* a_src = (const float*)d_in[5];
    const float* a_trg = (const float*)d_in[6];
    const float* a_tp  = (const float*)d_in[7];
    const float* Wskip = (const float*)d_in[8];
    const float* bias  = (const float*)d_in[9];
    float* out = (float*)d_out;

    const int E = in_sizes[2];        // edge_prob element count = E
    const int* src = ei;              // edge_index row 0
    const int* trg = ei + E;          // edge_index row 1

    // Workspace layout (~34 MB); all blocks 16B-aligned by construction
    char* wsb = (char*)d_ws;
    __half* projA  = (__half*)wsb;                      // Nn*HF f16 (12.8 MB)
    __half* skipA  = projA + (size_t)Nn * HF;           // Nn*HF f16 (12.8 MB)
    __half* ssh    = skipA + (size_t)Nn * HF;           // Nn*8  f16 (0.8 MB)
    __half* sth    = ssh + (size_t)Nn * 8;              // Nn*8  f16 (0.8 MB)
    float* ctp     = (float*)(sth + (size_t)Nn * 8);    // 16 floats
    _Float16* Wh   = (_Float16*)(ctp + 16);             // 272*128   (68 KB)
    unsigned int* spk = (unsigned int*)(Wh + (size_t)NWR * FIN); // E (3.2 MB)
    int*   rank    = (int*)(spk + E);                   // E         (3.2 MB)
    int*   deg     = rank + E;                          // Nn
    int*   pos     = deg + Nn;                          // Nn
    int*   partial = pos + Nn;                          // NSCAN (pad 256)

    k_prep<<<NSCAN, 256, 0, stream>>>(Wp, Wskip, a_src, a_trg, Wt, a_tp,
                                      Wh, ctp, deg);
    k_cn<<<NBLK64, 256, 0, stream>>>(trg, deg, rank, x, Wh, bias,
                                     projA, skipA, ssh, sth, E);
    k_scan1<<<NSCAN, 256, 0, stream>>>(deg, partial);
    k_scan3<<<NSCAN, 256, 0, stream>>>(deg, partial, pos);
    k_fill<<<NBLK64, 256, 0, stream>>>(src, trg, prob, rank, pos, spk, E);
    k_gather<<<Nn / 4, 256, 0, stream>>>(spk, pos, ssh, sth, ctp, skipA,
                                         (const __half2*)projA, out, E);
}

// Round 26
// 113.651 us; speedup vs baseline: 1.5828x; 1.0127x over previous
//
#include <hip/hip_runtime.h>
#include <hip/hip_fp16.h>
#include <math.h>

// Problem constants (from reference)
constexpr int Nn  = 50000;   // nodes
constexpr int FIN = 128;     // input features
constexpr int NH  = 8;       // heads
constexpr int FO  = 16;      // features per head
constexpr int HF  = 128;     // NH*FO
constexpr int NWR = 272;     // Wh rows: Wp(128) | Wskip(128) | Va_src(8) | Va_trg(8)
constexpr int NPREP = NWR / 2;                  // 136 Wh-prep blocks (2 rows ea)
constexpr int NBLK64 = (Nn + 63) / 64;          // 782 node blocks (64 nodes ea)
constexpr int NSCAN = (Nn + 255) / 256;         // 196 scan blocks

typedef _Float16 f16x8 __attribute__((ext_vector_type(8)));
typedef float    f32x4 __attribute__((ext_vector_type(4)));

// pack 4 f32 -> 4 f16 and store as one 8-byte write
static __device__ __forceinline__ void store_h4(__half* p, f32x4 v)
{
    union { __half2 h2[2]; float2 f2; } u;
    u.h2[0] = __floats2half2_rn(v[0], v[1]);
    u.h2[1] = __floats2half2_rn(v[2], v[3]);
    *reinterpret_cast<float2*>(p) = u.f2;
}

// process 4 edges (packed spk words) into one node's accumulators
static __device__ __forceinline__ void edge4(
    unsigned int pk0, unsigned int pk1, unsigned int pk2, unsigned int pk3,
    float st, float cth,
    const __half* __restrict__ ssl, const __half2* __restrict__ pA,
    float& num0, float& num1, float& den)
{
    const int s0 = pk0 & 0xFFFF, s1 = pk1 & 0xFFFF;
    const int s2 = pk2 & 0xFFFF, s3 = pk3 & 0xFFFF;
    const float ss0 = __half2float(ssl[s0 * 8]);
    const float ss1 = __half2float(ssl[s1 * 8]);
    const float ss2 = __half2float(ssl[s2 * 8]);
    const float ss3 = __half2float(ssl[s3 * 8]);
    const __half2 g0 = pA[s0 * 64], g1 = pA[s1 * 64];
    const __half2 g2 = pA[s2 * 64], g3 = pA[s3 * 64];
    const float p0 = __half2float(__ushort_as_half((unsigned short)(pk0 >> 16)));
    const float p1 = __half2float(__ushort_as_half((unsigned short)(pk1 >> 16)));
    const float p2 = __half2float(__ushort_as_half((unsigned short)(pk2 >> 16)));
    const float p3 = __half2float(__ushort_as_half((unsigned short)(pk3 >> 16)));
    float sc0 = ss0 + st + cth * p0;
    float sc1 = ss1 + st + cth * p1;
    float sc2 = ss2 + st + cth * p2;
    float sc3 = ss3 + st + cth * p3;
    sc0 = fmaxf(sc0, 0.2f * sc0);              // leaky_relu(0.2)
    sc1 = fmaxf(sc1, 0.2f * sc1);
    sc2 = fmaxf(sc2, 0.2f * sc2);
    sc3 = fmaxf(sc3, 0.2f * sc3);
    const float ev0 = __expf(sc0), ev1 = __expf(sc1);
    const float ev2 = __expf(sc2), ev3 = __expf(sc3);
    const float2 G0 = __half22float2(g0), G1 = __half22float2(g1);
    const float2 G2 = __half22float2(g2), G3 = __half22float2(g3);
    den  += (ev0 + ev1) + (ev2 + ev3);
    num0 += ev0 * G0.x + ev1 * G1.x + ev2 * G2.x + ev3 * G3.x;
    num1 += ev0 * G0.y + ev1 * G1.y + ev2 * G2.y + ev3 * G3.y;
}

// process one edge
static __device__ __forceinline__ void edge1(
    unsigned int pk, float st, float cth,
    const __half* __restrict__ ssl, const __half2* __restrict__ pA,
    float& num0, float& num1, float& den)
{
    const int s = pk & 0xFFFF;
    const float p = __half2float(__ushort_as_half((unsigned short)(pk >> 16)));
    float sc = __half2float(ssl[s * 8]) + st + cth * p;
    sc = fmaxf(sc, 0.2f * sc);
    const float ev = __expf(sc);
    const float2 G = __half22float2(pA[s * 64]);
    den  += ev;
    num0 += ev * G.x;
    num1 += ev * G.y;
}

// ---------------------------------------------------------------------------
// Weight prep + deg zeroing (memset folded in; 196 blocks):
//   all blocks      : deg[bid*256+tid] = 0 (covers Nn)
//   blocks [0,136)  : Wh[272][128] f16 (2 rows/block); ctp in block 0
// ---------------------------------------------------------------------------
__global__ __launch_bounds__(256) void k_prep(
    const float* __restrict__ Wp, const float* __restrict__ Wskip,
    const float* __restrict__ a_src, const float* __restrict__ a_trg,
    const float* __restrict__ Wt, const float* __restrict__ a_tp,
    _Float16* __restrict__ Wh, float* __restrict__ ctp,
    int* __restrict__ deg)
{
    const int bid = blockIdx.x;
    const int i = bid * 256 + threadIdx.x;
    if (i < Nn) deg[i] = 0;

    if (bid >= NPREP) return;
    if (bid == 0 && threadIdx.x < NH) {
        int h = threadIdx.x;
        float s = 0.f;
        #pragma unroll
        for (int f = 0; f < FO; ++f) s += Wt[h * FO + f] * a_tp[h * FO + f];
        ctp[h] = s;
    }
    const int o = bid * 2 + (threadIdx.x >> 7);  // 0..271
    const int k = threadIdx.x & 127;
    float v;
    if (o < 128)      v = Wp[o * FIN + k];
    else if (o < 256) v = Wskip[(o - 128) * FIN + k];
    else if (o < 264) {
        const int h = o - 256;
        float s = 0.f;
        #pragma unroll
        for (int f = 0; f < FO; ++f)
            s += a_src[h * FO + f] * Wp[(h * FO + f) * FIN + k];
        v = s;
    } else {
        const int h = o - 264;
        float s = 0.f;
        #pragma unroll
        for (int f = 0; f < FO; ++f)
            s += a_trg[h * FO + f] * Wp[(h * FO + f) * FIN + k];
        v = s;
    }
    Wh[o * FIN + k] = (_Float16)v;
}

// ---------------------------------------------------------------------------
// Node GEMM with SPREAD count overlap (R25 winner): edge-quad element ng's
// returning atomicAdd issues right after node-group ng's epilogue so its
// round trip hides under group ng+1's MFMA+loads. Swapped MFMA operands
// (lane owns one node, 4 consecutive out-dims -> 8B stores).
// ---------------------------------------------------------------------------
__global__ __launch_bounds__(256) void k_cn(
    const int* __restrict__ trg, int* __restrict__ deg, int* __restrict__ rank,
    const float* __restrict__ x, const _Float16* __restrict__ Wh,
    const float* __restrict__ bias,
    __half* __restrict__ projA, __half* __restrict__ skipA,
    __half* __restrict__ ssh, __half* __restrict__ sth, int E)
{
    const int bid = blockIdx.x;

    // ---- count stage A: issue trg loads ----
    const int e4 = bid * 256 + threadIdx.x;    // edge quad index
    const bool doCnt = (e4 * 4 < E);
    int4 t4;
    if (doCnt) t4 = reinterpret_cast<const int4*>(trg)[e4];

    // ---- node GEMM ----
    const int g0 = bid * 64;
    const int w  = threadIdx.x >> 6;           // wave 0..3 (uniform per wave)
    const int l  = threadIdx.x & 63;
    const int lr = l & 15;
    const int kb = l >> 4;                     // k-block 0..3
    const int t0 = w * 4;                      // first tile of this wave

    // Wh fragments (A operand): loaded ONCE, reused across groups
    f16x8 b[4][4];
    const _Float16* wb = Wh + (size_t)lr * FIN + kb * 8;
    #pragma unroll
    for (int i = 0; i < 4; ++i) {
        #pragma unroll
        for (int ks = 0; ks < 4; ++ks)
            b[i][ks] = *reinterpret_cast<const f16x8*>(
                wb + (size_t)(t0 + i) * 16 * FIN + ks * 32);
    }
    f16x8 b16[4];
    if (w == 3) {
        #pragma unroll
        for (int ks = 0; ks < 4; ++ks)
            b16[ks] = *reinterpret_cast<const f16x8*>(
                wb + (size_t)16 * 16 * FIN + ks * 32);
    }

    // bias (contiguous float4 per tile), hoisted — only skip waves use it
    float4 bo[4];
    if (t0 >= 8) {
        #pragma unroll
        for (int i = 0; i < 4; ++i)
            bo[i] = *reinterpret_cast<const float4*>(
                &bias[(t0 + i) * 16 + kb * 4 - 128]);
    }

    const float* xr0 = x + (size_t)(g0 + lr) * FIN + kb * 8;

    if (g0 + 64 <= Nn) {
        // ---- full block: 4 groups, 2-stage pipeline, spread atomics ----
        float4 ucur[8];
        #pragma unroll
        for (int q = 0; q < 8; ++q)
            ucur[q] = *reinterpret_cast<const float4*>(
                xr0 + (q >> 1) * 32 + (q & 1) * 4);

        int rres[4];
        #pragma unroll
        for (int ng = 0; ng < 4; ++ng) {
            float4 unx[8];
            if (ng < 3) {
                const float* xrn = xr0 + (size_t)(ng + 1) * 16 * FIN;
                #pragma unroll
                for (int q = 0; q < 8; ++q)
                    unx[q] = *reinterpret_cast<const float4*>(
                        xrn + (q >> 1) * 32 + (q & 1) * 4);
            }

            f16x8 a[4];
            #pragma unroll
            for (int ks = 0; ks < 4; ++ks) {
                float4 lo = ucur[ks * 2], hi = ucur[ks * 2 + 1];
                a[ks][0] = (_Float16)lo.x; a[ks][1] = (_Float16)lo.y;
                a[ks][2] = (_Float16)lo.z; a[ks][3] = (_Float16)lo.w;
                a[ks][4] = (_Float16)hi.x; a[ks][5] = (_Float16)hi.y;
                a[ks][6] = (_Float16)hi.z; a[ks][7] = (_Float16)hi.w;
            }

            f32x4 acc[4];
            #pragma unroll
            for (int i = 0; i < 4; ++i) acc[i] = (f32x4){0.f, 0.f, 0.f, 0.f};
            f32x4 acc16 = (f32x4){0.f, 0.f, 0.f, 0.f};

            #pragma unroll
            for (int i = 0; i < 4; ++i) {
                #pragma unroll
                for (int ks = 0; ks < 4; ++ks)
                    acc[i] = __builtin_amdgcn_mfma_f32_16x16x32_f16(
                        b[i][ks], a[ks], acc[i], 0, 0, 0);
            }
            if (w == 3) {
                #pragma unroll
                for (int ks = 0; ks < 4; ++ks)
                    acc16 = __builtin_amdgcn_mfma_f32_16x16x32_f16(
                        b16[ks], a[ks], acc16, 0, 0, 0);
            }

            // epilogue: lane owns node n, 4 consecutive out-dims per tile
            const int n = g0 + ng * 16 + lr;
            #pragma unroll
            for (int i = 0; i < 4; ++i) {
                const int ob = (t0 + i) * 16 + kb * 4;
                if (t0 < 8) {
                    store_h4(&projA[(size_t)n * HF + ob], acc[i]);
                } else {
                    f32x4 v = acc[i];
                    v[0] += bo[i].x; v[1] += bo[i].y;
                    v[2] += bo[i].z; v[3] += bo[i].w;
                    store_h4(&skipA[(size_t)n * HF + (ob - 128)], v);
                }
            }
            if (w == 3) {
                __half* sp = (kb < 2) ? (ssh + n * 8 + kb * 4)
                                      : (sth + n * 8 + (kb - 2) * 4);
                store_h4(sp, acc16);
            }

            // spread atomic: edge ng of this thread's quad issues NOW
            if (doCnt) {
                const int tv = (ng == 0) ? t4.x : (ng == 1) ? t4.y
                             : (ng == 2) ? t4.z : t4.w;
                rres[ng] = atomicAdd(&deg[tv], 1);
            }

            #pragma unroll
            for (int q = 0; q < 8; ++q) ucur[q] = unx[q];
        }

        if (doCnt) {
            int4 r;
            r.x = rres[0]; r.y = rres[1]; r.z = rres[2]; r.w = rres[3];
            reinterpret_cast<int4*>(rank)[e4] = r;
        }
    } else {
        // ---- partial last block (one 16-node group at 49984) ----
        f16x8 a[4];
        #pragma unroll
        for (int ks = 0; ks < 4; ++ks) {
            float4 u0 = *reinterpret_cast<const float4*>(xr0 + ks * 32);
            float4 u1 = *reinterpret_cast<const float4*>(xr0 + ks * 32 + 4);
            a[ks][0] = (_Float16)u0.x; a[ks][1] = (_Float16)u0.y;
            a[ks][2] = (_Float16)u0.z; a[ks][3] = (_Float16)u0.w;
            a[ks][4] = (_Float16)u1.x; a[ks][5] = (_Float16)u1.y;
            a[ks][6] = (_Float16)u1.z; a[ks][7] = (_Float16)u1.w;
        }

        f32x4 acc[4];
        #pragma unroll
        for (int i = 0; i < 4; ++i) acc[i] = (f32x4){0.f, 0.f, 0.f, 0.f};
        f32x4 acc16 = (f32x4){0.f, 0.f, 0.f, 0.f};

        #pragma unroll
        for (int i = 0; i < 4; ++i) {
            #pragma unroll
            for (int ks = 0; ks < 4; ++ks)
                acc[i] = __builtin_amdgcn_mfma_f32_16x16x32_f16(
                    b[i][ks], a[ks], acc[i], 0, 0, 0);
        }
        if (w == 3) {
            #pragma unroll
            for (int ks = 0; ks < 4; ++ks)
                acc16 = __builtin_amdgcn_mfma_f32_16x16x32_f16(
                    b16[ks], a[ks], acc16, 0, 0, 0);
        }

        const int n = g0 + lr;
        #pragma unroll
        for (int i = 0; i < 4; ++i) {
            const int ob = (t0 + i) * 16 + kb * 4;
            if (t0 < 8) {
                store_h4(&projA[(size_t)n * HF + ob], acc[i]);
            } else {
                f32x4 v = acc[i];
                v[0] += bo[i].x; v[1] += bo[i].y;
                v[2] += bo[i].z; v[3] += bo[i].w;
                store_h4(&skipA[(size_t)n * HF + (ob - 128)], v);
            }
        }
        if (w == 3) {
            __half* sp = (kb < 2) ? (ssh + n * 8 + kb * 4)
                                  : (sth + n * 8 + (kb - 2) * 4);
            store_h4(sp, acc16);
        }

        if (doCnt) {
            int4 r;
            r.x = atomicAdd(&deg[t4.x], 1);
            r.y = atomicAdd(&deg[t4.y], 1);
            r.z = atomicAdd(&deg[t4.z], 1);
            r.w = atomicAdd(&deg[t4.w], 1);
            reinterpret_cast<int4*>(rank)[e4] = r;
        }
    }
}

// ---------------------------------------------------------------------------
// Scan pair. pos stays EXCLUSIVE; row n spans [pos[n], n+1<Nn?pos[n+1]:E).
// ---------------------------------------------------------------------------
__global__ __launch_bounds__(256) void k_scan1(const int* __restrict__ deg,
                                               int* __restrict__ partial)
{
    __shared__ int lds[256];
    int t = threadIdx.x, i = blockIdx.x * 256 + t;
    lds[t] = (i < Nn) ? deg[i] : 0;
    __syncthreads();
    for (int off = 128; off > 0; off >>= 1) {
        if (t < off) lds[t] += lds[t + off];
        __syncthreads();
    }
    if (t == 0) partial[blockIdx.x] = lds[0];
}

__global__ __launch_bounds__(256) void k_scan3(const int* __restrict__ deg,
                                               const int* __restrict__ partial,
                                               int* __restrict__ pos)
{
    __shared__ int lds[256], lds2[256];
    const int t = threadIdx.x;
    const int i = blockIdx.x * 256 + t;
    lds2[t] = (t < NSCAN) ? partial[t] : 0;
    __syncthreads();
    for (int off = 1; off < 256; off <<= 1) {
        int u = (t >= off) ? lds2[t - off] : 0;
        __syncthreads();
        lds2[t] += u;
        __syncthreads();
    }
    const int base = (blockIdx.x == 0) ? 0 : lds2[blockIdx.x - 1];
    int v = (i < Nn) ? deg[i] : 0;
    lds[t] = v;
    __syncthreads();
    for (int off = 1; off < 256; off <<= 1) {
        int u = (t >= off) ? lds[t - off] : 0;
        __syncthreads();
        lds[t] += u;
        __syncthreads();
    }
    if (i < Nn) pos[i] = base + lds[t] - v;
}

// ---------------------------------------------------------------------------
// Fill (atomic-free): slot = pos[trg] + rank; spk = src(16b)|f16(prob)(16b).
// ---------------------------------------------------------------------------
__global__ __launch_bounds__(256) void k_fill(
    const int* __restrict__ src, const int* __restrict__ trg,
    const float* __restrict__ prob, const int* __restrict__ rank,
    const int* __restrict__ pos, unsigned int* __restrict__ spk, int E)
{
    int e4 = blockIdx.x * 256 + threadIdx.x;
    if (e4 * 4 >= E) return;
    int4   s4 = reinterpret_cast<const int4*>(src)[e4];
    int4   t4 = reinterpret_cast<const int4*>(trg)[e4];
    float4 p4 = reinterpret_cast<const float4*>(prob)[e4];
    int4   r4 = reinterpret_cast<const int4*>(rank)[e4];
    int    sv[4] = {s4.x, s4.y, s4.z, s4.w};
    int    tv[4] = {t4.x, t4.y, t4.z, t4.w};
    int    rv[4] = {r4.x, r4.y, r4.z, r4.w};
    float  pv[4] = {p4.x, p4.y, p4.z, p4.w};
    #pragma unroll
    for (int i = 0; i < 4; ++i) {
        int slot = pos[tv[i]] + rv[i];
        spk[slot] = (unsigned int)sv[i] |
            ((unsigned int)__half_as_ushort(__float2half_rn(pv[i])) << 16);
    }
}

// ---------------------------------------------------------------------------
// Fused gather, TWO NODES PER WAVE: main loop interleaves 4 edges of node A
// with 4 edges of node B — 8 independent gather chains in flight (2x the
// MLP of one-node waves; resident-wave count still saturates 32/CU).
// Scalarized edge walk via readfirstlane; per-edge vector work = f16 score
// gather + 256B projA wave-read + exp + 2 FMA. Lanes = 8 heads x 8 f-pairs.
// ---------------------------------------------------------------------------
__global__ __launch_bounds__(256) void k_gather(
    const unsigned int* __restrict__ spk, const int* __restrict__ pos,
    const __half* __restrict__ ssh, const __half* __restrict__ sth,
    const float* __restrict__ ctp, const __half* __restrict__ skipA,
    const __half2* __restrict__ projA, float* __restrict__ out, int E)
{
    const int lane = threadIdx.x & 63;
    const int h    = lane >> 3;                // head 0..7
    const int f2   = lane & 7;                 // feature pair 0..7

    // wave-uniform node pair, forced scalar
    const int pair = __builtin_amdgcn_readfirstlane(
        blockIdx.x * 4 + (threadIdx.x >> 6));  // 6250*4 = 25000 pairs
    const int nA = pair * 2;                   // 0..49998
    const int nB = nA + 1;

    const int jbA = __builtin_amdgcn_readfirstlane(pos[nA]);
    const int jbB = __builtin_amdgcn_readfirstlane(pos[nB]);
    const int jeA = jbB;                       // pos[nA+1] == pos[nB]
    const int jeB = __builtin_amdgcn_readfirstlane(
        (nB + 1 < Nn) ? pos[nB + 1] : E);

    const float cth = ctp[h];
    const float stA = __half2float(sth[nA * 8 + h]);
    const float stB = __half2float(sth[nB * 8 + h]);
    const __half* __restrict__ ssl = ssh + h;            // [s*8]
    const __half2* __restrict__ pA = projA + h * 8 + f2; // [s*64]

    float a0 = 0.f, a1 = 0.f, da = 0.f;
    float b0 = 0.f, b1 = 0.f, db = 0.f;
    int jA = jbA, jB = jbB;

    // interleaved main loop: 8 chains (4 per node)
    while (jA + 3 < jeA && jB + 3 < jeB) {
        const unsigned int kA0 = __builtin_amdgcn_readfirstlane(spk[jA]);
        const unsigned int kA1 = __builtin_amdgcn_readfirstlane(spk[jA + 1]);
        const unsigned int kA2 = __builtin_amdgcn_readfirstlane(spk[jA + 2]);
        const unsigned int kA3 = __builtin_amdgcn_readfirstlane(spk[jA + 3]);
        const unsigned int kB0 = __builtin_amdgcn_readfirstlane(spk[jB]);
        const unsigned int kB1 = __builtin_amdgcn_readfirstlane(spk[jB + 1]);
        const unsigned int kB2 = __builtin_amdgcn_readfirstlane(spk[jB + 2]);
        const unsigned int kB3 = __builtin_amdgcn_readfirstlane(spk[jB + 3]);
        edge4(kA0, kA1, kA2, kA3, stA, cth, ssl, pA, a0, a1, da);
        edge4(kB0, kB1, kB2, kB3, stB, cth, ssl, pA, b0, b1, db);
        jA += 4; jB += 4;
    }
    // drain A
    for (; jA + 3 < jeA; jA += 4) {
        const unsigned int k0 = __builtin_amdgcn_readfirstlane(spk[jA]);
        const unsigned int k1 = __builtin_amdgcn_readfirstlane(spk[jA + 1]);
        const unsigned int k2 = __builtin_amdgcn_readfirstlane(spk[jA + 2]);
        const unsigned int k3 = __builtin_amdgcn_readfirstlane(spk[jA + 3]);
        edge4(k0, k1, k2, k3, stA, cth, ssl, pA, a0, a1, da);
    }
    for (; jA < jeA; ++jA)
        edge1(__builtin_amdgcn_readfirstlane(spk[jA]), stA, cth, ssl, pA,
              a0, a1, da);
    // drain B
    for (; jB + 3 < jeB; jB += 4) {
        const unsigned int k0 = __builtin_amdgcn_readfirstlane(spk[jB]);
        const unsigned int k1 = __builtin_amdgcn_readfirstlane(spk[jB + 1]);
        const unsigned int k2 = __builtin_amdgcn_readfirstlane(spk[jB + 2]);
        const unsigned int k3 = __builtin_amdgcn_readfirstlane(spk[jB + 3]);
        edge4(k0, k1, k2, k3, stB, cth, ssl, pA, b0, b1, db);
    }
    for (; jB < jeB; ++jB)
        edge1(__builtin_amdgcn_readfirstlane(spk[jB]), stB, cth, ssl, pA,
              b0, b1, db);

    // epilogue for both nodes
    {
        const float inv = 1.f / (da + 1e-16f);
        const int idx = nA * HF + h * FO + f2 * 2;
        const float2 sk = __half22float2(
            *reinterpret_cast<const __half2*>(&skipA[idx]));
        float v0 = sk.x + a0 * inv;
        float v1 = sk.y + a1 * inv;
        v0 = v0 > 0.f ? v0 : expm1f(v0);
        v1 = v1 > 0.f ? v1 : expm1f(v1);
        *reinterpret_cast<float2*>(&out[idx]) = make_float2(v0, v1);
    }
    {
        const float inv = 1.f / (db + 1e-16f);
        const int idx = nB * HF + h * FO + f2 * 2;
        const float2 sk = __half22float2(
            *reinterpret_cast<const __half2*>(&skipA[idx]));
        float v0 = sk.x + b0 * inv;
        float v1 = sk.y + b1 * inv;
        v0 = v0 > 0.f ? v0 : expm1f(v0);
        v1 = v1 > 0.f ? v1 : expm1f(v1);
        *reinterpret_cast<float2*>(&out[idx]) = make_float2(v0, v1);
    }
}

// ---------------------------------------------------------------------------
extern "C" void kernel_launch(void* const* d_in, const int* in_sizes, int n_in,
                              void* d_out, int out_size, void* d_ws, size_t ws_size,
                              hipStream_t stream)
{
    const float* x     = (const float*)d_in[0];
    const int*   ei    = (const int*)d_in[1];
    const float* prob  = (const float*)d_in[2];
    const float* Wp    = (const float*)d_in[3];
    const float* Wt    = (const float*)d_in[4];
    const float* a_src = (const float*)d_in[5];
    const float* a_trg = (const float*)d_in[6];
    const float* a_tp  = (const float*)d_in[7];
    const float* Wskip = (const float*)d_in[8];
    const float* bias  = (const float*)d_in[9];
    float* out = (float*)d_out;

    const int E = in_sizes[2];        // edge_prob element count = E
    const int* src = ei;              // edge_index row 0
    const int* trg = ei + E;          // edge_index row 1

    // Workspace layout (~34 MB); all blocks 16B-aligned by construction
    char* wsb = (char*)d_ws;
    __half* projA  = (__half*)wsb;                      // Nn*HF f16 (12.8 MB)
    __half* skipA  = projA + (size_t)Nn * HF;           // Nn*HF f16 (12.8 MB)
    __half* ssh    = skipA + (size_t)Nn * HF;           // Nn*8  f16 (0.8 MB)
    __half* sth    = ssh + (size_t)Nn * 8;              // Nn*8  f16 (0.8 MB)
    float* ctp     = (float*)(sth + (size_t)Nn * 8);    // 16 floats
    _Float16* Wh   = (_Float16*)(ctp + 16);             // 272*128   (68 KB)
    unsigned int* spk = (unsigned int*)(Wh + (size_t)NWR * FIN); // E (3.2 MB)
    int*   rank    = (int*)(spk + E);                   // E         (3.2 MB)
    int*   deg     = rank + E;                          // Nn
    int*   pos     = deg + Nn;                          // Nn
    int*   partial = pos + Nn;                          // NSCAN (pad 256)

    k_prep<<<NSCAN, 256, 0, stream>>>(Wp, Wskip, a_src, a_trg, Wt, a_tp,
                                      Wh, ctp, deg);
    k_cn<<<NBLK64, 256, 0, stream>>>(trg, deg, rank, x, Wh, bias,
                                     projA, skipA, ssh, sth, E);
    k_scan1<<<NSCAN, 256, 0, stream>>>(deg, partial);
    k_scan3<<<NSCAN, 256, 0, stream>>>(deg, partial, pos);
    k_fill<<<NBLK64, 256, 0, stream>>>(src, trg, prob, rank, pos, spk, E);
    k_gather<<<Nn / 8, 256, 0, stream>>>(spk, pos, ssh, sth, ctp, skipA,
                                         (const __half2*)projA, out, E);
}

// Round 27
// 112.678 us; speedup vs baseline: 1.5965x; 1.0086x over previous
//
#include <hip/hip_runtime.h>
#include <hip/hip_fp16.h>
#include <math.h>

// Problem constants (from reference)
constexpr int Nn  = 50000;   // nodes
constexpr int FIN = 128;     // input features
constexpr int NH  = 8;       // heads
constexpr int FO  = 16;      // features per head
constexpr int HF  = 128;     // NH*FO
constexpr int NWR = 272;     // Wh rows: Wp(128) | Wskip(128) | Va_src(8) | Va_trg(8)
constexpr int NPREP = NWR / 2;                  // 136 Wh-prep blocks (2 rows ea)
constexpr int NBLK32 = (Nn + 31) / 32;          // 1563 node blocks (32 nodes ea)
constexpr int NBLK64 = (Nn + 63) / 64;          // 782 fill blocks
constexpr int NSCAN = (Nn + 255) / 256;         // 196 scan blocks

typedef _Float16 f16x8 __attribute__((ext_vector_type(8)));
typedef float    f32x4 __attribute__((ext_vector_type(4)));

// pack 4 f32 -> 4 f16 and store as one 8-byte write
static __device__ __forceinline__ void store_h4(__half* p, f32x4 v)
{
    union { __half2 h2[2]; float2 f2; } u;
    u.h2[0] = __floats2half2_rn(v[0], v[1]);
    u.h2[1] = __floats2half2_rn(v[2], v[3]);
    *reinterpret_cast<float2*>(p) = u.f2;
}

// process 4 edges (packed spk words) into one node's accumulators
static __device__ __forceinline__ void edge4(
    unsigned int pk0, unsigned int pk1, unsigned int pk2, unsigned int pk3,
    float st, float cth,
    const __half* __restrict__ ssl, const __half2* __restrict__ pA,
    float& num0, float& num1, float& den)
{
    const int s0 = pk0 & 0xFFFF, s1 = pk1 & 0xFFFF;
    const int s2 = pk2 & 0xFFFF, s3 = pk3 & 0xFFFF;
    const float ss0 = __half2float(ssl[s0 * 8]);
    const float ss1 = __half2float(ssl[s1 * 8]);
    const float ss2 = __half2float(ssl[s2 * 8]);
    const float ss3 = __half2float(ssl[s3 * 8]);
    const __half2 g0 = pA[s0 * 64], g1 = pA[s1 * 64];
    const __half2 g2 = pA[s2 * 64], g3 = pA[s3 * 64];
    const float p0 = __half2float(__ushort_as_half((unsigned short)(pk0 >> 16)));
    const float p1 = __half2float(__ushort_as_half((unsigned short)(pk1 >> 16)));
    const float p2 = __half2float(__ushort_as_half((unsigned short)(pk2 >> 16)));
    const float p3 = __half2float(__ushort_as_half((unsigned short)(pk3 >> 16)));
    float sc0 = ss0 + st + cth * p0;
    float sc1 = ss1 + st + cth * p1;
    float sc2 = ss2 + st + cth * p2;
    float sc3 = ss3 + st + cth * p3;
    sc0 = fmaxf(sc0, 0.2f * sc0);              // leaky_relu(0.2)
    sc1 = fmaxf(sc1, 0.2f * sc1);
    sc2 = fmaxf(sc2, 0.2f * sc2);
    sc3 = fmaxf(sc3, 0.2f * sc3);
    const float ev0 = __expf(sc0), ev1 = __expf(sc1);
    const float ev2 = __expf(sc2), ev3 = __expf(sc3);
    const float2 G0 = __half22float2(g0), G1 = __half22float2(g1);
    const float2 G2 = __half22float2(g2), G3 = __half22float2(g3);
    den  += (ev0 + ev1) + (ev2 + ev3);
    num0 += ev0 * G0.x + ev1 * G1.x + ev2 * G2.x + ev3 * G3.x;
    num1 += ev0 * G0.y + ev1 * G1.y + ev2 * G2.y + ev3 * G3.y;
}

// process one edge
static __device__ __forceinline__ void edge1(
    unsigned int pk, float st, float cth,
    const __half* __restrict__ ssl, const __half2* __restrict__ pA,
    float& num0, float& num1, float& den)
{
    const int s = pk & 0xFFFF;
    const float p = __half2float(__ushort_as_half((unsigned short)(pk >> 16)));
    float sc = __half2float(ssl[s * 8]) + st + cth * p;
    sc = fmaxf(sc, 0.2f * sc);
    const float ev = __expf(sc);
    const float2 G = __half22float2(pA[s * 64]);
    den  += ev;
    num0 += ev * G.x;
    num1 += ev * G.y;
}

// ---------------------------------------------------------------------------
// Weight prep + deg zeroing (memset folded in; 196 blocks):
//   all blocks      : deg[bid*256+tid] = 0 (covers Nn)
//   blocks [0,136)  : Wh[272][128] f16 (2 rows/block); ctp in block 0
// ---------------------------------------------------------------------------
__global__ __launch_bounds__(256) void k_prep(
    const float* __restrict__ Wp, const float* __restrict__ Wskip,
    const float* __restrict__ a_src, const float* __restrict__ a_trg,
    const float* __restrict__ Wt, const float* __restrict__ a_tp,
    _Float16* __restrict__ Wh, float* __restrict__ ctp,
    int* __restrict__ deg)
{
    const int bid = blockIdx.x;
    const int i = bid * 256 + threadIdx.x;
    if (i < Nn) deg[i] = 0;

    if (bid >= NPREP) return;
    if (bid == 0 && threadIdx.x < NH) {
        int h = threadIdx.x;
        float s = 0.f;
        #pragma unroll
        for (int f = 0; f < FO; ++f) s += Wt[h * FO + f] * a_tp[h * FO + f];
        ctp[h] = s;
    }
    const int o = bid * 2 + (threadIdx.x >> 7);  // 0..271
    const int k = threadIdx.x & 127;
    float v;
    if (o < 128)      v = Wp[o * FIN + k];
    else if (o < 256) v = Wskip[(o - 128) * FIN + k];
    else if (o < 264) {
        const int h = o - 256;
        float s = 0.f;
        #pragma unroll
        for (int f = 0; f < FO; ++f)
            s += a_src[h * FO + f] * Wp[(h * FO + f) * FIN + k];
        v = s;
    } else {
        const int h = o - 264;
        float s = 0.f;
        #pragma unroll
        for (int f = 0; f < FO; ++f)
            s += a_trg[h * FO + f] * Wp[(h * FO + f) * FIN + k];
        v = s;
    }
    Wh[o * FIN + k] = (_Float16)v;
}

// ---------------------------------------------------------------------------
// Node GEMM, 32 nodes/block (1563 blocks -> ~4 waves/SIMD, filling the VGPR
// occupancy cap; R26's 782-block grid left the machine at 3/SIMD). Count
// chunk = 2 edges/thread (int2), the two spread returning atomics issue
// after group 0 / group 1 epilogues so their round trips hide under the
// other group's MFMA+loads. Swapped MFMA operands (lane owns one node,
// 4 consecutive out-dims -> 8B stores).
// ---------------------------------------------------------------------------
__global__ __launch_bounds__(256) void k_cn(
    const int* __restrict__ trg, int* __restrict__ deg, int* __restrict__ rank,
    const float* __restrict__ x, const _Float16* __restrict__ Wh,
    const float* __restrict__ bias,
    __half* __restrict__ projA, __half* __restrict__ skipA,
    __half* __restrict__ ssh, __half* __restrict__ sth, int E)
{
    const int bid = blockIdx.x;

    // ---- count stage A: issue trg loads (2 edges/thread) ----
    const int e2 = bid * 256 + threadIdx.x;    // edge pair index
    const bool doCnt = (e2 * 2 < E);
    int2 t2;
    if (doCnt) t2 = reinterpret_cast<const int2*>(trg)[e2];

    // ---- node GEMM ----
    const int g0 = bid * 32;
    const int w  = threadIdx.x >> 6;           // wave 0..3 (uniform per wave)
    const int l  = threadIdx.x & 63;
    const int lr = l & 15;
    const int kb = l >> 4;                     // k-block 0..3
    const int t0 = w * 4;                      // first tile of this wave

    // Wh fragments (A operand): loaded ONCE, reused across groups
    f16x8 b[4][4];
    const _Float16* wb = Wh + (size_t)lr * FIN + kb * 8;
    #pragma unroll
    for (int i = 0; i < 4; ++i) {
        #pragma unroll
        for (int ks = 0; ks < 4; ++ks)
            b[i][ks] = *reinterpret_cast<const f16x8*>(
                wb + (size_t)(t0 + i) * 16 * FIN + ks * 32);
    }
    f16x8 b16[4];
    if (w == 3) {
        #pragma unroll
        for (int ks = 0; ks < 4; ++ks)
            b16[ks] = *reinterpret_cast<const f16x8*>(
                wb + (size_t)16 * 16 * FIN + ks * 32);
    }

    // bias (contiguous float4 per tile), hoisted — only skip waves use it
    float4 bo[4];
    if (t0 >= 8) {
        #pragma unroll
        for (int i = 0; i < 4; ++i)
            bo[i] = *reinterpret_cast<const float4*>(
                &bias[(t0 + i) * 16 + kb * 4 - 128]);
    }

    const float* xr0 = x + (size_t)(g0 + lr) * FIN + kb * 8;

    if (g0 + 32 <= Nn) {
        // ---- full block: 2 groups, 2-stage pipeline, spread atomics ----
        float4 ucur[8];
        #pragma unroll
        for (int q = 0; q < 8; ++q)
            ucur[q] = *reinterpret_cast<const float4*>(
                xr0 + (q >> 1) * 32 + (q & 1) * 4);

        int rres[2];
        #pragma unroll
        for (int ng = 0; ng < 2; ++ng) {
            float4 unx[8];
            if (ng < 1) {
                const float* xrn = xr0 + (size_t)16 * FIN;
                #pragma unroll
                for (int q = 0; q < 8; ++q)
                    unx[q] = *reinterpret_cast<const float4*>(
                        xrn + (q >> 1) * 32 + (q & 1) * 4);
            }

            f16x8 a[4];
            #pragma unroll
            for (int ks = 0; ks < 4; ++ks) {
                float4 lo = ucur[ks * 2], hi = ucur[ks * 2 + 1];
                a[ks][0] = (_Float16)lo.x; a[ks][1] = (_Float16)lo.y;
                a[ks][2] = (_Float16)lo.z; a[ks][3] = (_Float16)lo.w;
                a[ks][4] = (_Float16)hi.x; a[ks][5] = (_Float16)hi.y;
                a[ks][6] = (_Float16)hi.z; a[ks][7] = (_Float16)hi.w;
            }

            f32x4 acc[4];
            #pragma unroll
            for (int i = 0; i < 4; ++i) acc[i] = (f32x4){0.f, 0.f, 0.f, 0.f};
            f32x4 acc16 = (f32x4){0.f, 0.f, 0.f, 0.f};

            #pragma unroll
            for (int i = 0; i < 4; ++i) {
                #pragma unroll
                for (int ks = 0; ks < 4; ++ks)
                    acc[i] = __builtin_amdgcn_mfma_f32_16x16x32_f16(
                        b[i][ks], a[ks], acc[i], 0, 0, 0);
            }
            if (w == 3) {
                #pragma unroll
                for (int ks = 0; ks < 4; ++ks)
                    acc16 = __builtin_amdgcn_mfma_f32_16x16x32_f16(
                        b16[ks], a[ks], acc16, 0, 0, 0);
            }

            // epilogue: lane owns node n, 4 consecutive out-dims per tile
            const int n = g0 + ng * 16 + lr;
            #pragma unroll
            for (int i = 0; i < 4; ++i) {
                const int ob = (t0 + i) * 16 + kb * 4;
                if (t0 < 8) {
                    store_h4(&projA[(size_t)n * HF + ob], acc[i]);
                } else {
                    f32x4 v = acc[i];
                    v[0] += bo[i].x; v[1] += bo[i].y;
                    v[2] += bo[i].z; v[3] += bo[i].w;
                    store_h4(&skipA[(size_t)n * HF + (ob - 128)], v);
                }
            }
            if (w == 3) {
                __half* sp = (kb < 2) ? (ssh + n * 8 + kb * 4)
                                      : (sth + n * 8 + (kb - 2) * 4);
                store_h4(sp, acc16);
            }

            // spread atomic: edge ng of this thread's pair issues NOW
            if (doCnt) {
                const int tv = (ng == 0) ? t2.x : t2.y;
                rres[ng] = atomicAdd(&deg[tv], 1);
            }

            #pragma unroll
            for (int q = 0; q < 8; ++q) ucur[q] = unx[q];
        }

        if (doCnt) {
            int2 r;
            r.x = rres[0]; r.y = rres[1];
            reinterpret_cast<int2*>(rank)[e2] = r;
        }
    } else {
        // ---- partial last block (one 16-node group at 49984) ----
        f16x8 a[4];
        #pragma unroll
        for (int ks = 0; ks < 4; ++ks) {
            float4 u0 = *reinterpret_cast<const float4*>(xr0 + ks * 32);
            float4 u1 = *reinterpret_cast<const float4*>(xr0 + ks * 32 + 4);
            a[ks][0] = (_Float16)u0.x; a[ks][1] = (_Float16)u0.y;
            a[ks][2] = (_Float16)u0.z; a[ks][3] = (_Float16)u0.w;
            a[ks][4] = (_Float16)u1.x; a[ks][5] = (_Float16)u1.y;
            a[ks][6] = (_Float16)u1.z; a[ks][7] = (_Float16)u1.w;
        }

        f32x4 acc[4];
        #pragma unroll
        for (int i = 0; i < 4; ++i) acc[i] = (f32x4){0.f, 0.f, 0.f, 0.f};
        f32x4 acc16 = (f32x4){0.f, 0.f, 0.f, 0.f};

        #pragma unroll
        for (int i = 0; i < 4; ++i) {
            #pragma unroll
            for (int ks = 0; ks < 4; ++ks)
                acc[i] = __builtin_amdgcn_mfma_f32_16x16x32_f16(
                    b[i][ks], a[ks], acc[i], 0, 0, 0);
        }
        if (w == 3) {
            #pragma unroll
            for (int ks = 0; ks < 4; ++ks)
                acc16 = __builtin_amdgcn_mfma_f32_16x16x32_f16(
                    b16[ks], a[ks], acc16, 0, 0, 0);
        }

        const int n = g0 + lr;
        #pragma unroll
        for (int i = 0; i < 4; ++i) {
            const int ob = (t0 + i) * 16 + kb * 4;
            if (t0 < 8) {
                store_h4(&projA[(size_t)n * HF + ob], acc[i]);
            } else {
                f32x4 v = acc[i];
                v[0] += bo[i].x; v[1] += bo[i].y;
                v[2] += bo[i].z; v[3] += bo[i].w;
                store_h4(&skipA[(size_t)n * HF + (ob - 128)], v);
            }
        }
        if (w == 3) {
            __half* sp = (kb < 2) ? (ssh + n * 8 + kb * 4)
                                  : (sth + n * 8 + (kb - 2) * 4);
            store_h4(sp, acc16);
        }

        if (doCnt) {
            int2 r;
            r.x = atomicAdd(&deg[t2.x], 1);
            r.y = atomicAdd(&deg[t2.y], 1);
            reinterpret_cast<int2*>(rank)[e2] = r;
        }
    }
}

// ---------------------------------------------------------------------------
// Scan pair. pos stays EXCLUSIVE; row n spans [pos[n], n+1<Nn?pos[n+1]:E).
// ---------------------------------------------------------------------------
__global__ __launch_bounds__(256) void k_scan1(const int* __restrict__ deg,
                                               int* __restrict__ partial)
{
    __shared__ int lds[256];
    int t = threadIdx.x, i = blockIdx.x * 256 + t;
    lds[t] = (i < Nn) ? deg[i] : 0;
    __syncthreads();
    for (int off = 128; off > 0; off >>= 1) {
        if (t < off) lds[t] += lds[t + off];
        __syncthreads();
    }
    if (t == 0) partial[blockIdx.x] = lds[0];
}

__global__ __launch_bounds__(256) void k_scan3(const int* __restrict__ deg,
                                               const int* __restrict__ partial,
                                               int* __restrict__ pos)
{
    __shared__ int lds[256], lds2[256];
    const int t = threadIdx.x;
    const int i = blockIdx.x * 256 + t;
    lds2[t] = (t < NSCAN) ? partial[t] : 0;
    __syncthreads();
    for (int off = 1; off < 256; off <<= 1) {
        int u = (t >= off) ? lds2[t - off] : 0;
        __syncthreads();
        lds2[t] += u;
        __syncthreads();
    }
    const int base = (blockIdx.x == 0) ? 0 : lds2[blockIdx.x - 1];
    int v = (i < Nn) ? deg[i] : 0;
    lds[t] = v;
    __syncthreads();
    for (int off = 1; off < 256; off <<= 1) {
        int u = (t >= off) ? lds[t - off] : 0;
        __syncthreads();
        lds[t] += u;
        __syncthreads();
    }
    if (i < Nn) pos[i] = base + lds[t] - v;
}

// ---------------------------------------------------------------------------
// Fill (atomic-free): slot = pos[trg] + rank; spk = src(16b)|f16(prob)(16b).
// ---------------------------------------------------------------------------
__global__ __launch_bounds__(256) void k_fill(
    const int* __restrict__ src, const int* __restrict__ trg,
    const float* __restrict__ prob, const int* __restrict__ rank,
    const int* __restrict__ pos, unsigned int* __restrict__ spk, int E)
{
    int e4 = blockIdx.x * 256 + threadIdx.x;
    if (e4 * 4 >= E) return;
    int4   s4 = reinterpret_cast<const int4*>(src)[e4];
    int4   t4 = reinterpret_cast<const int4*>(trg)[e4];
    float4 p4 = reinterpret_cast<const float4*>(prob)[e4];
    int4   r4 = reinterpret_cast<const int4*>(rank)[e4];
    int    sv[4] = {s4.x, s4.y, s4.z, s4.w};
    int    tv[4] = {t4.x, t4.y, t4.z, t4.w};
    int    rv[4] = {r4.x, r4.y, r4.z, r4.w};
    float  pv[4] = {p4.x, p4.y, p4.z, p4.w};
    #pragma unroll
    for (int i = 0; i < 4; ++i) {
        int slot = pos[tv[i]] + rv[i];
        spk[slot] = (unsigned int)sv[i] |
            ((unsigned int)__half_as_ushort(__float2half_rn(pv[i])) << 16);
    }
}

// ---------------------------------------------------------------------------
// Fused gather, TWO NODES PER WAVE (R26 winner): main loop interleaves 4
// edges of node A with 4 edges of node B — 8 independent gather chains.
// Scalarized edge walk via readfirstlane; per-edge vector work = f16 score
// gather + 256B projA wave-read + exp + 2 FMA. Lanes = 8 heads x 8 f-pairs.
// ---------------------------------------------------------------------------
__global__ __launch_bounds__(256) void k_gather(
    const unsigned int* __restrict__ spk, const int* __restrict__ pos,
    const __half* __restrict__ ssh, const __half* __restrict__ sth,
    const float* __restrict__ ctp, const __half* __restrict__ skipA,
    const __half2* __restrict__ projA, float* __restrict__ out, int E)
{
    const int lane = threadIdx.x & 63;
    const int h    = lane >> 3;                // head 0..7
    const int f2   = lane & 7;                 // feature pair 0..7

    // wave-uniform node pair, forced scalar
    const int pair = __builtin_amdgcn_readfirstlane(
        blockIdx.x * 4 + (threadIdx.x >> 6));  // 6250*4 = 25000 pairs
    const int nA = pair * 2;                   // 0..49998
    const int nB = nA + 1;

    const int jbA = __builtin_amdgcn_readfirstlane(pos[nA]);
    const int jbB = __builtin_amdgcn_readfirstlane(pos[nB]);
    const int jeA = jbB;                       // pos[nA+1] == pos[nB]
    const int jeB = __builtin_amdgcn_readfirstlane(
        (nB + 1 < Nn) ? pos[nB + 1] : E);

    const float cth = ctp[h];
    const float stA = __half2float(sth[nA * 8 + h]);
    const float stB = __half2float(sth[nB * 8 + h]);
    const __half* __restrict__ ssl = ssh + h;            // [s*8]
    const __half2* __restrict__ pA = projA + h * 8 + f2; // [s*64]

    float a0 = 0.f, a1 = 0.f, da = 0.f;
    float b0 = 0.f, b1 = 0.f, db = 0.f;
    int jA = jbA, jB = jbB;

    // interleaved main loop: 8 chains (4 per node)
    while (jA + 3 < jeA && jB + 3 < jeB) {
        const unsigned int kA0 = __builtin_amdgcn_readfirstlane(spk[jA]);
        const unsigned int kA1 = __builtin_amdgcn_readfirstlane(spk[jA + 1]);
        const unsigned int kA2 = __builtin_amdgcn_readfirstlane(spk[jA + 2]);
        const unsigned int kA3 = __builtin_amdgcn_readfirstlane(spk[jA + 3]);
        const unsigned int kB0 = __builtin_amdgcn_readfirstlane(spk[jB]);
        const unsigned int kB1 = __builtin_amdgcn_readfirstlane(spk[jB + 1]);
        const unsigned int kB2 = __builtin_amdgcn_readfirstlane(spk[jB + 2]);
        const unsigned int kB3 = __builtin_amdgcn_readfirstlane(spk[jB + 3]);
        edge4(kA0, kA1, kA2, kA3, stA, cth, ssl, pA, a0, a1, da);
        edge4(kB0, kB1, kB2, kB3, stB, cth, ssl, pA, b0, b1, db);
        jA += 4; jB += 4;
    }
    // drain A
    for (; jA + 3 < jeA; jA += 4) {
        const unsigned int k0 = __builtin_amdgcn_readfirstlane(spk[jA]);
        const unsigned int k1 = __builtin_amdgcn_readfirstlane(spk[jA + 1]);
        const unsigned int k2 = __builtin_amdgcn_readfirstlane(spk[jA + 2]);
        const unsigned int k3 = __builtin_amdgcn_readfirstlane(spk[jA + 3]);
        edge4(k0, k1, k2, k3, stA, cth, ssl, pA, a0, a1, da);
    }
    for (; jA < jeA; ++jA)
        edge1(__builtin_amdgcn_readfirstlane(spk[jA]), stA, cth, ssl, pA,
              a0, a1, da);
    // drain B
    for (; jB + 3 < jeB; jB += 4) {
        const unsigned int k0 = __builtin_amdgcn_readfirstlane(spk[jB]);
        const unsigned int k1 = __builtin_amdgcn_readfirstlane(spk[jB + 1]);
        const unsigned int k2 = __builtin_amdgcn_readfirstlane(spk[jB + 2]);
        const unsigned int k3 = __builtin_amdgcn_readfirstlane(spk[jB + 3]);
        edge4(k0, k1, k2, k3, stB, cth, ssl, pA, b0, b1, db);
    }
    for (; jB < jeB; ++jB)
        edge1(__builtin_amdgcn_readfirstlane(spk[jB]), stB, cth, ssl, pA,
              b0, b1, db);

    // epilogue for both nodes
    {
        const float inv = 1.f / (da + 1e-16f);
        const int idx = nA * HF + h * FO + f2 * 2;
        const float2 sk = __half22float2(
            *reinterpret_cast<const __half2*>(&skipA[idx]));
        float v0 = sk.x + a0 * inv;
        float v1 = sk.y + a1 * inv;
        v0 = v0 > 0.f ? v0 : expm1f(v0);
        v1 = v1 > 0.f ? v1 : expm1f(v1);
        *reinterpret_cast<float2*>(&out[idx]) = make_float2(v0, v1);
    }
    {
        const float inv = 1.f / (db + 1e-16f);
        const int idx = nB * HF + h * FO + f2 * 2;
        const float2 sk = __half22float2(
            *reinterpret_cast<const __half2*>(&skipA[idx]));
        float v0 = sk.x + b0 * inv;
        float v1 = sk.y + b1 * inv;
        v0 = v0 > 0.f ? v0 : expm1f(v0);
        v1 = v1 > 0.f ? v1 : expm1f(v1);
        *reinterpret_cast<float2*>(&out[idx]) = make_float2(v0, v1);
    }
}

// ---------------------------------------------------------------------------
extern "C" void kernel_launch(void* const* d_in, const int* in_sizes, int n_in,
                              void* d_out, int out_size, void* d_ws, size_t ws_size,
                              hipStream_t stream)
{
    const float* x     = (const float*)d_in[0];
    const int*   ei    = (const int*)d_in[1];
    const float* prob  = (const float*)d_in[2];
    const float* Wp    = (const float*)d_in[3];
    const float* Wt    = (const float*)d_in[4];
    const float* a_src = (const float*)d_in[5];
    const float* a_trg = (const float*)d_in[6];
    const float* a_tp  = (const float*)d_in[7];
    const float* Wskip = (const float*)d_in[8];
    const float* bias  = (const float*)d_in[9];
    float* out = (float*)d_out;

    const int E = in_sizes[2];        // edge_prob element count = E
    const int* src = ei;              // edge_index row 0
    const int* trg = ei + E;          // edge_index row 1

    // Workspace layout (~34 MB); all blocks 16B-aligned by construction
    char* wsb = (char*)d_ws;
    __half* projA  = (__half*)wsb;                      // Nn*HF f16 (12.8 MB)
    __half* skipA  = projA + (size_t)Nn * HF;           // Nn*HF f16 (12.8 MB)
    __half* ssh    = skipA + (size_t)Nn * HF;           // Nn*8  f16 (0.8 MB)
    __half* sth    = ssh + (size_t)Nn * 8;              // Nn*8  f16 (0.8 MB)
    float* ctp     = (float*)(sth + (size_t)Nn * 8);    // 16 floats
    _Float16* Wh   = (_Float16*)(ctp + 16);             // 272*128   (68 KB)
    unsigned int* spk = (unsigned int*)(Wh + (size_t)NWR * FIN); // E (3.2 MB)
    int*   rank    = (int*)(spk + E);                   // E         (3.2 MB)
    int*   deg     = rank + E;                          // Nn
    int*   pos     = deg + Nn;                          // Nn
    int*   partial = pos + Nn;                          // NSCAN (pad 256)

    k_prep<<<NSCAN, 256, 0, stream>>>(Wp, Wskip, a_src, a_trg, Wt, a_tp,
                                      Wh, ctp, deg);
    k_cn<<<NBLK32, 256, 0, stream>>>(trg, deg, rank, x, Wh, bias,
                                     projA, skipA, ssh, sth, E);
    k_scan1<<<NSCAN, 256, 0, stream>>>(deg, partial);
    k_scan3<<<NSCAN, 256, 0, stream>>>(deg, partial, pos);
    k_fill<<<NBLK64, 256, 0, stream>>>(src, trg, prob, rank, pos, spk, E);
    k_gather<<<Nn / 8, 256, 0, stream>>>(spk, pos, ssh, sth, ctp, skipA,
                                         (const __half2*)projA, out, E);
}